// Round 6
// baseline (1146.985 us; speedup 1.0000x reference)
//
#include <hip/hip_runtime.h>
#include <math.h>

#define CDIM 384
#define SDIM 4096
#define BDIM 4
#define DINC 768
#define NST  16
#define NCHUNK 64
#define LCHUNK 64
#define PSTRIDE 6291456   // floats per conv partial [B,C,S]

typedef unsigned short ushort_t;
typedef unsigned int uint_t;
typedef __attribute__((ext_vector_type(4))) float f32x4;
typedef __attribute__((ext_vector_type(8))) short bf16x8;

__device__ __forceinline__ ushort_t f2bf(float f) {
    union { float f; uint_t u; } v; v.f = f;
    uint_t r = v.u + 0x7FFFu + ((v.u >> 16) & 1u);   // round-to-nearest-even
    return (ushort_t)(r >> 16);
}
__device__ __forceinline__ float bf2f(ushort_t u) {
    union { uint_t i; float f; } v; v.i = ((uint_t)u) << 16; return v.f;
}
__device__ __forceinline__ uint_t pk2(float a, float b) {
    return (uint_t)f2bf(a) | ((uint_t)f2bf(b) << 16);
}

// ---------------------------------------------------------------------------
// fp32 -> bf16 flat convert (n4 = n/4).
// ---------------------------------------------------------------------------
__global__ __launch_bounds__(256)
void cvt_bf16_kernel(const float* __restrict__ src, ushort_t* __restrict__ dst, int n4) {
    const int i = blockIdx.x * 256 + threadIdx.x;
    if (i >= n4) return;
    float4 v = ((const float4*)src)[i];
    uint2 o; o.x = pk2(v.x, v.y); o.y = pk2(v.z, v.w);
    ((uint2*)dst)[i] = o;
}

// ---------------------------------------------------------------------------
// Weight convert 3x3x3: W[co][ci][27] fp32 -> Wb[tap][co][ci] bf16.
// ---------------------------------------------------------------------------
__global__ __launch_bounds__(256)
void wconv_kernel(const float* __restrict__ W, ushort_t* __restrict__ Wb) {
    const int idx = blockIdx.x * 256 + threadIdx.x;      // co*384 + ci
    const float* wp = W + (size_t)idx * 27;
#pragma unroll
    for (int tap = 0; tap < 27; ++tap)
        Wb[(size_t)tap * (CDIM * CDIM) + idx] = f2bf(wp[tap]);
}

// ---------------------------------------------------------------------------
// Pad + transpose to channels-last bf16: src[b][c][16^3] -> Xp[b][18][18][18][384]
// ---------------------------------------------------------------------------
__global__ __launch_bounds__(384)
void pad_kernel(const float* __restrict__ src, ushort_t* __restrict__ Xp) {
    const int blk = blockIdx.x;                          // b(4) d(16) h(16)
    const int b = blk >> 8, d = (blk >> 4) & 15, h = blk & 15;
    const int ci = threadIdx.x;
    const float* sp = src + (size_t)(b * CDIM + ci) * SDIM + d * 256 + h * 16;
    ushort_t* dp = Xp + ((((size_t)(b * 18 + d + 1) * 18) + (h + 1)) * 18 + 1) * CDIM + ci;
#pragma unroll
    for (int w = 0; w < 16; ++w)
        dp[(size_t)w * CDIM] = f2bf(sp[w]);
}

// ---------------------------------------------------------------------------
// Fused: v = relu((P0+P1 - m)*r) -> pad/transpose to channels-last bf16 Xp.
// ---------------------------------------------------------------------------
__global__ __launch_bounds__(384)
void pad_fuse2_kernel(const float* __restrict__ P0, const float* __restrict__ P1,
                      const float* __restrict__ stats, ushort_t* __restrict__ Xp) {
    const int blk = blockIdx.x;
    const int b = blk >> 8, d = (blk >> 4) & 15, h = blk & 15;
    const int ci = threadIdx.x;
    const size_t o = (size_t)(b * CDIM + ci) * SDIM + d * 256 + h * 16;
    const float m = stats[(b * CDIM + ci) * 2], r = stats[(b * CDIM + ci) * 2 + 1];
    ushort_t* dp = Xp + ((((size_t)(b * 18 + d + 1) * 18) + (h + 1)) * 18 + 1) * CDIM + ci;
#pragma unroll
    for (int w = 0; w < 16; ++w) {
        const float v = P0[o + w] + P1[o + w];
        dp[(size_t)w * CDIM] = f2bf(fmaxf((v - m) * r, 0.f));
    }
}

// ---------------------------------------------------------------------------
// Fused: S = relu((P0+P1-m2)*r2) + relu((C3-m3)*r3) -> pad channels-last bf16.
// ---------------------------------------------------------------------------
__global__ __launch_bounds__(384)
void pad_fuse3_kernel(const float* __restrict__ P0, const float* __restrict__ P1,
                      const float* __restrict__ st2, const float* __restrict__ C3,
                      const float* __restrict__ st3, ushort_t* __restrict__ Xp) {
    const int blk = blockIdx.x;
    const int b = blk >> 8, d = (blk >> 4) & 15, h = blk & 15;
    const int ci = threadIdx.x;
    const size_t o = (size_t)(b * CDIM + ci) * SDIM + d * 256 + h * 16;
    const float m2 = st2[(b * CDIM + ci) * 2], r2 = st2[(b * CDIM + ci) * 2 + 1];
    const float m3 = st3[(b * CDIM + ci) * 2], r3 = st3[(b * CDIM + ci) * 2 + 1];
    ushort_t* dp = Xp + ((((size_t)(b * 18 + d + 1) * 18) + (h + 1)) * 18 + 1) * CDIM + ci;
#pragma unroll
    for (int w = 0; w < 16; ++w) {
        const float x1 = fmaxf((P0[o + w] + P1[o + w] - m2) * r2, 0.f);
        const float x2 = fmaxf((C3[o + w] - m3) * r3, 0.f);
        dp[(size_t)w * CDIM] = f2bf(x1 + x2);
    }
}

// ---------------------------------------------------------------------------
// 3x3x3 implicit-GEMM conv via MFMA bf16, v2: block 128co x 256sp (one full
// d-plane), 4 waves (2co x 2sp), wave tile 64co x 128sp (acc 4x8) -> 25% less
// LDS fragment traffic per FLOP than 64x64 and 2x barrier amortization.
// z-split 2 over taps (z=0: 0..13, z=1: 14..26 -> partial Y + z*PSTRIDE).
// Single-barrier reg-staged double-buffer, incremental offset walking.
// LDS: A 128x40 x2buf + B 256x40 x2buf = 61440 B -> 2 blocks/CU.
// ---------------------------------------------------------------------------
__global__ __launch_bounds__(256)
void conv3_kernel(const ushort_t* __restrict__ Xp, const ushort_t* __restrict__ Wb,
                  float* __restrict__ Y) {
    const int b  = blockIdx.x >> 4;
    const int d  = blockIdx.x & 15;
    const int co0 = blockIdx.y * 128;
    const int z = blockIdx.z;
    const int t = threadIdx.x;
    const int lane = t & 63;
    const int wid = t >> 6;
    const int wy = wid >> 1, wx = wid & 1;               // co-half / sp-half

    const int tap0 = z ? 14 : 0;
    const int iters = (z ? 13 : 14) * 12;
    const int kd0 = z ? 1 : 0, kh0 = z ? 1 : 0, kw0 = z ? 2 : 0;
    Y += (size_t)z * PSTRIDE;

    __shared__ ushort_t As[2][128 * 40];
    __shared__ ushort_t Bs[2][256 * 40];

    f32x4 acc[4][8];
#pragma unroll
    for (int i = 0; i < 4; ++i)
#pragma unroll
        for (int j = 0; j < 8; ++j) acc[i][j] = (f32x4){0.f, 0.f, 0.f, 0.f};

    // staging: thread t owns uint4-q = t&3, rows (t>>2)+64k (A: k<2, B: k<4)
    const int srow = t >> 2, q = t & 3;
    const int sA = srow * 40 + q * 8;                    // LDS elem addr
    // per-thread fixed parts
    const int aBase0 = (co0 + srow) * CDIM + q * 8;
    const int aBase1 = (co0 + srow + 64) * CDIM + q * 8;
    int voff[4];
#pragma unroll
    for (int k = 0; k < 4; ++k) {
        const int r = srow + 64 * k;
        voff[k] = ((r >> 4) * 18 + (r & 15)) * CDIM + q * 8;
    }
    // uniform walking offsets
    int aoff = tap0 * (CDIM * CDIM);
    int goff = (((b * 18 + d + kd0) * 18 + kh0) * 18 + kw0) * CDIM;
    int c12 = 0, ckw = kw0, ckh = kh0;

    // fragment read bases
    const int lm = lane & 15, lk = (lane >> 4) * 8;
    const int rA0 = (wy * 64 + lm) * 40 + lk;
    const int rB0 = (wx * 128 + lm) * 40 + lk;

    uint4 ra[2], rb[4];

    auto loadg = [&]() {
        ra[0] = *reinterpret_cast<const uint4*>(Wb + aoff + aBase0);
        ra[1] = *reinterpret_cast<const uint4*>(Wb + aoff + aBase1);
#pragma unroll
        for (int k = 0; k < 4; ++k)
            rb[k] = *reinterpret_cast<const uint4*>(Xp + goff + voff[k]);
        aoff += 32; goff += 32;
        if (++c12 == 12) {                               // tap wrap
            c12 = 0;
            aoff += CDIM * CDIM - 384;
            if (++ckw == 3) {
                ckw = 0;
                if (++ckh == 3) { ckh = 0; goff += 109440; }
                else goff += 5760;
            }
        }
    };
    auto lwrite = [&](int buf) {
        *reinterpret_cast<uint4*>(&As[buf][sA])        = ra[0];
        *reinterpret_cast<uint4*>(&As[buf][sA + 2560]) = ra[1];
#pragma unroll
        for (int k = 0; k < 4; ++k)
            *reinterpret_cast<uint4*>(&Bs[buf][sA + k * 2560]) = rb[k];
    };

    loadg();
    lwrite(0);
    __syncthreads();

    int buf = 0;
    for (int idx = 0; idx < iters; ++idx) {
        const bool more = (idx + 1) < iters;
        if (more) loadg();                               // issue early
        bf16x8 af[4], bfr[8];
#pragma unroll
        for (int mi = 0; mi < 4; ++mi)
            af[mi] = *reinterpret_cast<const bf16x8*>(&As[buf][rA0 + mi * 640]);
#pragma unroll
        for (int ni = 0; ni < 8; ++ni)
            bfr[ni] = *reinterpret_cast<const bf16x8*>(&Bs[buf][rB0 + ni * 640]);
#pragma unroll
        for (int mi = 0; mi < 4; ++mi)
#pragma unroll
            for (int ni = 0; ni < 8; ++ni)
                acc[mi][ni] = __builtin_amdgcn_mfma_f32_16x16x32_bf16(
                    af[mi], bfr[ni], acc[mi][ni], 0, 0, 0);
        if (more) lwrite(buf ^ 1);                       // write late
        __syncthreads();
        buf ^= 1;
    }

    // epilogue: C/D layout col(lane&15)=sp, row=(lane>>4)*4+j=co
    const int coB = co0 + wy * 64 + (lane >> 4) * 4;
#pragma unroll
    for (int mi = 0; mi < 4; ++mi) {
#pragma unroll
        for (int ni = 0; ni < 8; ++ni) {
            const int r = wx * 128 + ni * 16 + lm;       // sp within plane
            float* yp = Y + ((size_t)b * CDIM + (coB + mi * 16)) * SDIM + d * 256 + r;
#pragma unroll
            for (int j = 0; j < 4; ++j)
                yp[(size_t)j * SDIM] = acc[mi][ni][j];
        }
    }
}

// ---------------------------------------------------------------------------
// 1x1x1 conv via MFMA bf16 (proven round-4/5 kernel, NTAP=1 path).
// Block 128co x 128sp, 4 waves 2x2, BK=32, dbuf, issue-early/write-late.
// ---------------------------------------------------------------------------
__global__ __launch_bounds__(256)
void conv1x1_kernel(const ushort_t* __restrict__ Xp, const ushort_t* __restrict__ Wb,
                    float* __restrict__ Y) {
    const int nt = blockIdx.x;
    const int b  = nt >> 5;
    const int d  = (nt >> 1) & 15;
    const int h0 = (nt & 1) * 8;
    const int co0 = blockIdx.y * 128;
    const int t = threadIdx.x;
    const int lane = t & 63;
    const int wid = t >> 6;
    const int wy = wid >> 1, wx = wid & 1;

    __shared__ ushort_t As[2][128 * 40];
    __shared__ ushort_t Bs[2][128 * 40];

    f32x4 acc[4][4];
#pragma unroll
    for (int i = 0; i < 4; ++i)
#pragma unroll
        for (int j = 0; j < 4; ++j) acc[i][j] = (f32x4){0.f, 0.f, 0.f, 0.f};

    const int arow = t >> 1, half = t & 1;
    const int hl = arow >> 4, w = arow & 15;
    const int wA = arow * 40 + half * 16;

    const int lm = lane & 15, lk = (lane >> 4) * 8;
    const int rA0 = (wy * 64 + lm) * 40 + lk;
    const int rB0 = (wx * 64 + lm) * 40 + lk;

    const ushort_t* ap = Wb + (size_t)(co0 + arow) * CDIM + half * 16;
    const ushort_t* bp = Xp + ((((size_t)(b * 18 + d + 1) * 18) + (h0 + hl + 1)) * 18
                               + (w + 1)) * CDIM + half * 16;
    uint4 ra0, ra1, rb0, rb1;
    auto loadg = [&]() {
        const uint4* pa = reinterpret_cast<const uint4*>(ap);
        ra0 = pa[0]; ra1 = pa[1];
        const uint4* pb = reinterpret_cast<const uint4*>(bp);
        rb0 = pb[0]; rb1 = pb[1];
        ap += 32; bp += 32;
    };
    auto lwrite = [&](int buf) {
        *reinterpret_cast<uint4*>(&As[buf][wA])     = ra0;
        *reinterpret_cast<uint4*>(&As[buf][wA + 8]) = ra1;
        *reinterpret_cast<uint4*>(&Bs[buf][wA])     = rb0;
        *reinterpret_cast<uint4*>(&Bs[buf][wA + 8]) = rb1;
    };

    loadg();
    lwrite(0);
    __syncthreads();

    int buf = 0;
    for (int idx = 0; idx < 12; ++idx) {
        const bool more = (idx + 1) < 12;
        if (more) loadg();
        bf16x8 af[4], bfr[4];
#pragma unroll
        for (int mi = 0; mi < 4; ++mi)
            af[mi] = *reinterpret_cast<const bf16x8*>(&As[buf][rA0 + mi * 640]);
#pragma unroll
        for (int ni = 0; ni < 4; ++ni)
            bfr[ni] = *reinterpret_cast<const bf16x8*>(&Bs[buf][rB0 + ni * 640]);
#pragma unroll
        for (int mi = 0; mi < 4; ++mi)
#pragma unroll
            for (int ni = 0; ni < 4; ++ni)
                acc[mi][ni] = __builtin_amdgcn_mfma_f32_16x16x32_bf16(
                    af[mi], bfr[ni], acc[mi][ni], 0, 0, 0);
        if (more) lwrite(buf ^ 1);
        __syncthreads();
        buf ^= 1;
    }

    const int coB = co0 + wy * 64 + (lane >> 4) * 4;
    const int nB  = wx * 64 + lm;
#pragma unroll
    for (int mi = 0; mi < 4; ++mi) {
#pragma unroll
        for (int ni = 0; ni < 4; ++ni) {
            const int nl = nB + ni * 16;
            const int s = d * 256 + (h0 + (nl >> 4)) * 16 + (nl & 15);
            float* yp = Y + ((size_t)b * CDIM + (coB + mi * 16)) * SDIM + s;
#pragma unroll
            for (int j = 0; j < 4; ++j)
                yp[(size_t)j * SDIM] = acc[mi][ni][j];
        }
    }
}

// ---------------------------------------------------------------------------
// bf16 MFMA GEMM, NT: C[M,N] = A[M,K] x B[N,K]^T. A bf16 (AT=ushort_t) or
// fp32 converted-on-stage (AT=float). Tile 128x128xBK32, 4 waves.
// EPI 0: fp32 store (ldc); 1: xz split -> bf16 C/C2 (N=1536);
// EPI 2: transposed fp32 float4 store C[b][n][l].
// ---------------------------------------------------------------------------
template<typename AT, int EPI>
__global__ __launch_bounds__(256)
void gemm_mfma_kernel(const AT* __restrict__ A, const ushort_t* __restrict__ Bw,
                      void* __restrict__ Cv, void* __restrict__ C2v,
                      int M, int N, int K, int ldc) {
    const int n0 = blockIdx.x * 128;
    const int m0 = blockIdx.y * 128;
    const int t = threadIdx.x;
    const int lane = t & 63;
    const int wid = t >> 6;
    const int wy = wid >> 1, wx = wid & 1;

    __shared__ ushort_t As[2][128 * 40];
    __shared__ ushort_t Bs[2][128 * 40];

    f32x4 acc[4][4];
#pragma unroll
    for (int i = 0; i < 4; ++i)
#pragma unroll
        for (int j = 0; j < 4; ++j) acc[i][j] = (f32x4){0.f, 0.f, 0.f, 0.f};

    const int arow = t >> 1, half = t & 1;
    const int wA = arow * 40 + half * 16;
    const int lm = lane & 15, lk = (lane >> 4) * 8;
    const int rA0 = (wy * 64 + lm) * 40 + lk;
    const int rB0 = (wx * 64 + lm) * 40 + lk;

    uint4 ra0, ra1, rb0, rb1;

    auto loadg = [&](int kk) {
        const int kb = kk * 32 + half * 16;
        if constexpr (sizeof(AT) == 2) {                 // bf16 A
            const uint4* pa = reinterpret_cast<const uint4*>(
                (const ushort_t*)A + (size_t)(m0 + arow) * K + kb);
            ra0 = pa[0]; ra1 = pa[1];
        } else {                                         // fp32 A, convert
            const float4* pa = reinterpret_cast<const float4*>(
                (const float*)A + (size_t)(m0 + arow) * K + kb);
            float4 f0 = pa[0], f1 = pa[1], f2 = pa[2], f3 = pa[3];
            ra0.x = pk2(f0.x, f0.y); ra0.y = pk2(f0.z, f0.w);
            ra0.z = pk2(f1.x, f1.y); ra0.w = pk2(f1.z, f1.w);
            ra1.x = pk2(f2.x, f2.y); ra1.y = pk2(f2.z, f2.w);
            ra1.z = pk2(f3.x, f3.y); ra1.w = pk2(f3.z, f3.w);
        }
        if (n0 + arow < N) {
            const uint4* pb = reinterpret_cast<const uint4*>(
                Bw + (size_t)(n0 + arow) * K + kb);
            rb0 = pb[0]; rb1 = pb[1];
        } else {
            rb0 = make_uint4(0, 0, 0, 0); rb1 = rb0;
        }
    };
    auto lwrite = [&](int buf) {
        *reinterpret_cast<uint4*>(&As[buf][wA])     = ra0;
        *reinterpret_cast<uint4*>(&As[buf][wA + 8]) = ra1;
        *reinterpret_cast<uint4*>(&Bs[buf][wA])     = rb0;
        *reinterpret_cast<uint4*>(&Bs[buf][wA + 8]) = rb1;
    };

    const int KI = K >> 5;
    loadg(0);
    lwrite(0);
    __syncthreads();

    int buf = 0;
    for (int kk = 0; kk < KI; ++kk) {
        const bool more = (kk + 1) < KI;
        if (more) loadg(kk + 1);
        bf16x8 af[4], bfr[4];
#pragma unroll
        for (int mi = 0; mi < 4; ++mi)
            af[mi] = *reinterpret_cast<const bf16x8*>(&As[buf][rA0 + mi * 640]);
#pragma unroll
        for (int ni = 0; ni < 4; ++ni)
            bfr[ni] = *reinterpret_cast<const bf16x8*>(&Bs[buf][rB0 + ni * 640]);
#pragma unroll
        for (int mi = 0; mi < 4; ++mi)
#pragma unroll
            for (int ni = 0; ni < 4; ++ni)
                acc[mi][ni] = __builtin_amdgcn_mfma_f32_16x16x32_bf16(
                    af[mi], bfr[ni], acc[mi][ni], 0, 0, 0);
        if (more) lwrite(buf ^ 1);
        __syncthreads();
        buf ^= 1;
    }

    const int mB = m0 + wy * 64 + (lane >> 4) * 4;
    const int nB = n0 + wx * 64 + lm;
#pragma unroll
    for (int mi = 0; mi < 4; ++mi) {
#pragma unroll
        for (int ni = 0; ni < 4; ++ni) {
            const int n = nB + ni * 16;
            if (EPI == 2) {                              // transposed float4
                const int mrow = mB + mi * 16;
                const int bb = mrow >> 12, l = mrow & 4095;
                float4 st = {acc[mi][ni][0], acc[mi][ni][1],
                             acc[mi][ni][2], acc[mi][ni][3]};
                *reinterpret_cast<float4*>(
                    (float*)Cv + ((size_t)(bb * CDIM + n)) * SDIM + l) = st;
            } else {
#pragma unroll
                for (int j = 0; j < 4; ++j) {
                    const int m = mB + mi * 16 + j;
                    const float v = acc[mi][ni][j];
                    if (EPI == 0) {
                        if (n < N) ((float*)Cv)[(size_t)m * ldc + n] = v;
                    } else {                             // xz split, bf16 out
                        if (n < DINC) ((ushort_t*)Cv)[(size_t)m * DINC + n] = f2bf(v);
                        else ((ushort_t*)C2v)[(size_t)m * DINC + (n - DINC)] = f2bf(v);
                    }
                }
            }
        }
    }
}

// ---------------------------------------------------------------------------
// InstanceNorm stats, single input: one block per (b,c).
// ---------------------------------------------------------------------------
__global__ __launch_bounds__(256)
void inorm_stats_kernel(const float* __restrict__ X, float* __restrict__ stats) {
    const int bc = blockIdx.x;
    const float* xp = X + (size_t)bc * SDIM;
    float s = 0.f, ss = 0.f;
    for (int i = threadIdx.x * 4; i < SDIM; i += 1024) {
        float4 v = *(const float4*)(xp + i);
        s += v.x + v.y + v.z + v.w;
        ss += v.x * v.x + v.y * v.y + v.z * v.z + v.w * v.w;
    }
#pragma unroll
    for (int off = 32; off > 0; off >>= 1) {
        s += __shfl_down(s, off);
        ss += __shfl_down(ss, off);
    }
    __shared__ float rs[4], rss[4];
    const int wid = threadIdx.x >> 6;
    if ((threadIdx.x & 63) == 0) { rs[wid] = s; rss[wid] = ss; }
    __syncthreads();
    if (threadIdx.x == 0) {
        float S = rs[0] + rs[1] + rs[2] + rs[3];
        float SS = rss[0] + rss[1] + rss[2] + rss[3];
        float m = S * (1.f / SDIM);
        float var = SS * (1.f / SDIM) - m * m;
        stats[bc * 2] = m;
        stats[bc * 2 + 1] = rsqrtf(var + 1e-5f);
    }
}

// ---------------------------------------------------------------------------
// InstanceNorm stats over the SUM of two partials.
// ---------------------------------------------------------------------------
__global__ __launch_bounds__(256)
void inorm_stats2_kernel(const float* __restrict__ P0, const float* __restrict__ P1,
                         float* __restrict__ stats) {
    const int bc = blockIdx.x;
    const float* p0 = P0 + (size_t)bc * SDIM;
    const float* p1 = P1 + (size_t)bc * SDIM;
    float s = 0.f, ss = 0.f;
    for (int i = threadIdx.x * 4; i < SDIM; i += 1024) {
        float4 a = *(const float4*)(p0 + i);
        float4 c = *(const float4*)(p1 + i);
        const float vx = a.x + c.x, vy = a.y + c.y, vz = a.z + c.z, vw = a.w + c.w;
        s += vx + vy + vz + vw;
        ss += vx * vx + vy * vy + vz * vz + vw * vw;
    }
#pragma unroll
    for (int off = 32; off > 0; off >>= 1) {
        s += __shfl_down(s, off);
        ss += __shfl_down(ss, off);
    }
    __shared__ float rs[4], rss[4];
    const int wid = threadIdx.x >> 6;
    if ((threadIdx.x & 63) == 0) { rs[wid] = s; rss[wid] = ss; }
    __syncthreads();
    if (threadIdx.x == 0) {
        float S = rs[0] + rs[1] + rs[2] + rs[3];
        float SS = rss[0] + rss[1] + rss[2] + rss[3];
        float m = S * (1.f / SDIM);
        float var = SS * (1.f / SDIM) - m * m;
        stats[bc * 2] = m;
        stats[bc * 2 + 1] = rsqrtf(var + 1e-5f);
    }
}

// ---------------------------------------------------------------------------
// Fused LayerNorm: xg = relu((C4-m)*r) + x inline, LN over C, transpose
// -> tn [b][l][c] bf16.
// ---------------------------------------------------------------------------
__global__ __launch_bounds__(256)
void layernorm_kernel(const float* __restrict__ C4, const float* __restrict__ stats,
                      const float* __restrict__ X, const float* __restrict__ gam,
                      const float* __restrict__ bet, ushort_t* __restrict__ Tn) {
    const int token = blockIdx.x * 4 + (threadIdx.x >> 6);
    const int lane = threadIdx.x & 63;
    const int b = token >> 12, l = token & 4095;
    const size_t base = (size_t)b * CDIM * SDIM + l;
    float v[6];
    float s = 0.f, ss = 0.f;
#pragma unroll
    for (int i = 0; i < 6; ++i) {
        const int c = lane + i * 64;
        const size_t o = base + (size_t)c * SDIM;
        const float m = stats[(b * CDIM + c) * 2], r = stats[(b * CDIM + c) * 2 + 1];
        v[i] = fmaxf((C4[o] - m) * r, 0.f) + X[o];
        s += v[i]; ss += v[i] * v[i];
    }
#pragma unroll
    for (int off = 32; off > 0; off >>= 1) {
        s += __shfl_down(s, off);
        ss += __shfl_down(ss, off);
    }
    s = __shfl(s, 0); ss = __shfl(ss, 0);
    const float m = s * (1.f / CDIM);
    const float r = rsqrtf(ss * (1.f / CDIM) - m * m + 1e-5f);
    ushort_t* tp = Tn + (size_t)token * CDIM;
#pragma unroll
    for (int i = 0; i < 6; ++i) {
        const int c = lane + i * 64;
        tp[c] = f2bf((v[i] - m) * r * gam[c] + bet[c]);
    }
}

// ---------------------------------------------------------------------------
// Tiled fp32 GEMM for dt_proj (K=24), NT, bias+softplus, bf16 store.
// ---------------------------------------------------------------------------
__global__ __launch_bounds__(256)
void gemm_dtproj_kernel(const float* __restrict__ A, const float* __restrict__ B,
                        ushort_t* __restrict__ C, const float* __restrict__ bias,
                        int M, int N, int K, int lda, int ldb, int ldc) {
    __shared__ __align__(16) float As[16][132];
    __shared__ __align__(16) float Bs[16][68];
    const int t = threadIdx.x;
    const int m0 = blockIdx.y * 128;
    const int n0 = blockIdx.x * 64;

    float acc[8][4];
#pragma unroll
    for (int i = 0; i < 8; ++i)
#pragma unroll
        for (int j = 0; j < 4; ++j) acc[i][j] = 0.f;

    const int mr = (t & 15) * 8;
    const int nr = (t >> 4) * 4;

    for (int k0 = 0; k0 < K; k0 += 16) {
#pragma unroll
        for (int idx = 0; idx < 8; ++idx) {
            const int e = idx * 256 + t;
            const int k = e & 15, m = e >> 4;
            float v = 0.f;
            if (k0 + k < K) v = A[(size_t)(m0 + m) * lda + (k0 + k)];
            As[k][m] = v;
        }
#pragma unroll
        for (int idx = 0; idx < 4; ++idx) {
            const int e = idx * 256 + t;
            const int k = e & 15, n = e >> 4;
            float v = 0.f;
            if ((n0 + n) < N && (k0 + k) < K) v = B[(size_t)(n0 + n) * ldb + (k0 + k)];
            Bs[k][n] = v;
        }
        __syncthreads();
#pragma unroll
        for (int k = 0; k < 16; ++k) {
            float4 a0 = *(const float4*)&As[k][mr];
            float4 a1 = *(const float4*)&As[k][mr + 4];
            float4 b0 = *(const float4*)&Bs[k][nr];
            const float av[8] = {a0.x, a0.y, a0.z, a0.w, a1.x, a1.y, a1.z, a1.w};
            const float bv[4] = {b0.x, b0.y, b0.z, b0.w};
#pragma unroll
            for (int i = 0; i < 8; ++i)
#pragma unroll
                for (int j = 0; j < 4; ++j)
                    acc[i][j] = fmaf(av[i], bv[j], acc[i][j]);
        }
        __syncthreads();
    }

#pragma unroll
    for (int i = 0; i < 8; ++i) {
        const int m = m0 + mr + i;
#pragma unroll
        for (int j = 0; j < 4; ++j) {
            const int n = n0 + nr + j;
            if (n >= N) continue;
            float v = acc[i][j] + bias[n];
            v = (v > 20.f) ? v : log1pf(__expf(v));
            C[(size_t)m * ldc + n] = f2bf(v);
        }
    }
}

// ---------------------------------------------------------------------------
// Causal depthwise conv1d (K=4) + bias + SiLU, bf16 in/out.
// ---------------------------------------------------------------------------
__global__ __launch_bounds__(256)
void dwconv_silu_kernel(const ushort_t* __restrict__ Xin, const float* __restrict__ W,
                        const float* __restrict__ bias, ushort_t* __restrict__ U) {
    const int dch = blockIdx.x * 256 + threadIdx.x;
    const int l = blockIdx.y, b = blockIdx.z;
    const float4 w4 = ((const float4*)W)[dch];
    const float wk[4] = {w4.x, w4.y, w4.z, w4.w};
    const ushort_t* xp = Xin + ((size_t)b * 4096 + l) * DINC + dch;
    float acc = bias[dch];
#pragma unroll
    for (int k = 0; k < 4; ++k) {
        const int ll = l - 3 + k;
        if (ll >= 0) acc = fmaf(bf2f(xp[(k - 3) * DINC]), wk[k], acc);
    }
    U[((size_t)b * 4096 + l) * DINC + dch] = f2bf(acc / (1.f + __expf(-acc)));
}

// ---------------------------------------------------------------------------
// Chunked parallel selective scan (3 phases). dt/u/z/y are bf16; B,C (DBL),
// chunk states fp32.
// ---------------------------------------------------------------------------
__global__ __launch_bounds__(256)
void scan_phase1_kernel(const ushort_t* __restrict__ DT, const ushort_t* __restrict__ U,
                        const float* __restrict__ DBL, const float* __restrict__ A_log,
                        float* __restrict__ HOUT, float* __restrict__ SDT) {
    const int b = blockIdx.z, chunk = blockIdx.y;
    const int dch = blockIdx.x * 256 + threadIdx.x;
    float Arow[16];
#pragma unroll
    for (int n = 0; n < NST; ++n) Arow[n] = -__expf(A_log[dch * NST + n]);

    __shared__ float bcs[LCHUNK][16];
    const size_t tokbase = (size_t)b * 4096 + chunk * LCHUNK;
#pragma unroll
    for (int idx = 0; idx < 4; ++idx) {
        const int e = idx * 256 + threadIdx.x;
        bcs[e >> 4][e & 15] = DBL[(tokbase + (e >> 4)) * 56 + 24 + (e & 15)];
    }
    __syncthreads();

    size_t off = tokbase * DINC + dch;
    float h[16];
#pragma unroll
    for (int n = 0; n < NST; ++n) h[n] = 0.f;
    float sdt = 0.f;
    float cdt = bf2f(DT[off]), cu = bf2f(U[off]);
    for (int t = 0; t < LCHUNK; ++t) {
        float ndt = 0.f, nu = 0.f;
        if (t < LCHUNK - 1) { ndt = bf2f(DT[off + DINC]); nu = bf2f(U[off + DINC]); }
        sdt += cdt;
        const float du = cdt * cu;
#pragma unroll
        for (int n = 0; n < NST; ++n)
            h[n] = __expf(cdt * Arow[n]) * h[n] + du * bcs[t][n];
        off += DINC;
        cdt = ndt; cu = nu;
    }
    float* hp = HOUT + (((size_t)(b * DINC + dch) * NCHUNK + chunk) << 4);
#pragma unroll
    for (int n = 0; n < NST; ++n) hp[n] = h[n];
    SDT[(size_t)(b * DINC + dch) * NCHUNK + chunk] = sdt;
}

__global__ __launch_bounds__(256)
void scan_phase2_kernel(float* __restrict__ HOUT, const float* __restrict__ SDT,
                        const float* __restrict__ A_log) {
    const int t = blockIdx.x * 256 + threadIdx.x;        // 49152
    const int b = t / (DINC * NST);
    const int rem = t - b * (DINC * NST);
    const int d = rem >> 4, n = rem & 15;
    const float An = -__expf(A_log[d * NST + n]);
    float* hp = HOUT + (((size_t)(b * DINC + d) * NCHUNK) << 4) + n;
    const float* sp = SDT + (size_t)(b * DINC + d) * NCHUNK;
    float H = 0.f;
    for (int c = 0; c < NCHUNK; ++c) {
        const float tmp = hp[c * 16];
        const float dA = __expf(An * sp[c]);
        hp[c * 16] = H;
        H = dA * H + tmp;
    }
}

__global__ __launch_bounds__(256)
void scan_phase3_kernel(ushort_t* __restrict__ DT, const ushort_t* __restrict__ U,
                        const float* __restrict__ DBL, const ushort_t* __restrict__ Z,
                        const float* __restrict__ A_log, const float* __restrict__ D_skip,
                        const float* __restrict__ HOUT) {
    const int b = blockIdx.z, chunk = blockIdx.y;
    const int dch = blockIdx.x * 256 + threadIdx.x;
    float Arow[16];
#pragma unroll
    for (int n = 0; n < NST; ++n) Arow[n] = -__expf(A_log[dch * NST + n]);
    const float Dsk = D_skip[dch];

    __shared__ float bcs[LCHUNK][32];
    const size_t tokbase = (size_t)b * 4096 + chunk * LCHUNK;
#pragma unroll
    for (int idx = 0; idx < 8; ++idx) {
        const int e = idx * 256 + threadIdx.x;
        bcs[e >> 5][e & 31] = DBL[(tokbase + (e >> 5)) * 56 + 24 + (e & 31)];
    }
    __syncthreads();

    float h[16];
    const float* hp = HOUT + (((size_t)(b * DINC + dch) * NCHUNK + chunk) << 4);
#pragma unroll
    for (int n = 0; n < NST; ++n) h[n] = hp[n];

    size_t off = tokbase * DINC + dch;
    float cdt = bf2f(DT[off]), cu = bf2f(U[off]), cz = bf2f(Z[off]);
    for (int t = 0; t < LCHUNK; ++t) {
        float ndt = 0.f, nu = 0.f, nz = 0.f;
        if (t < LCHUNK - 1) {
            ndt = bf2f(DT[off + DINC]); nu = bf2f(U[off + DINC]); nz = bf2f(Z[off + DINC]);
        }
        const float du = cdt * cu;
        float y = 0.f;
#pragma unroll
        for (int n = 0; n < NST; ++n) {
            h[n] = __expf(cdt * Arow[n]) * h[n] + du * bcs[t][n];
            y = fmaf(h[n], bcs[t][16 + n], y);
        }
        y += cu * Dsk;
        const float sz = cz / (1.f + __expf(-cz));
        DT[off] = f2bf(y * sz);
        off += DINC;
        cdt = ndt; cu = nu; cz = nz;
    }
}

// ---------------------------------------------------------------------------
extern "C" void kernel_launch(void* const* d_in, const int* in_sizes, int n_in,
                              void* d_out, int out_size, void* d_ws, size_t ws_size,
                              hipStream_t stream) {
    (void)in_sizes; (void)n_in; (void)out_size; (void)ws_size;
    const float* x         = (const float*)d_in[0];
    const float* w1        = (const float*)d_in[1];
    const float* w2        = (const float*)d_in[3];
    const float* w3        = (const float*)d_in[5];
    const float* w4        = (const float*)d_in[7];
    const float* ln_g      = (const float*)d_in[9];
    const float* ln_b      = (const float*)d_in[10];
    const float* in_proj_w = (const float*)d_in[11];
    const float* conv1d_w  = (const float*)d_in[12];
    const float* conv1d_b  = (const float*)d_in[13];
    const float* x_proj_w  = (const float*)d_in[14];
    const float* dt_proj_w = (const float*)d_in[15];
    const float* dt_proj_b = (const float*)d_in[16];
    const float* A_log     = (const float*)d_in[17];
    const float* D_skip    = (const float*)d_in[18];
    const float* out_proj_w= (const float*)d_in[19];
    float* out = (float*)d_out;

    // Workspace regions (floats): R0..R4. Lifetimes disjoint where aliased.
    float* ws = (float*)d_ws;
    float* R0 = ws;                    //  6291456
    float* R1 = ws + 6291456;          //  6291456
    float* R2 = ws + 12582912;         // 12582912
    float* R3 = ws + 25165824;         // 12582912
    float* R4 = ws + 37748736;         // 12582912

    // GSC-phase aliases
    float*    P0    = R0;                            // conv partial z=0
    float*    P1    = R1;                            // conv partial z=1 (= P0+PSTRIDE)
    ushort_t* Wb27  = (ushort_t*)R2;                 // 3981312 bf16
    ushort_t* Xp    = (ushort_t*)(R2 + 2097152);     // 8957952 bf16
    ushort_t* w3b   = (ushort_t*)(R2 + 6576128);     // 147456 bf16
    ushort_t* w4b   = (ushort_t*)(R2 + 6649856);     // 147456 bf16
    float*    SA    = R4;                            // stats A (3072 fl)
    float*    SB    = R4 + 4096;                     // stats B (3072 fl)
    // Mamba-phase aliases
    ushort_t* tnb   = (ushort_t*)R0;                 // 16384*384 bf16
    float*    DBL   = R0 + 3145728;                  // 16384*56 fp32
    ushort_t* ipwb  = (ushort_t*)R1;                 // 1536*384 bf16
    ushort_t* opwb  = (ushort_t*)(R1 + 294912);      // 384*768 bf16
    ushort_t* xpwb  = (ushort_t*)(R1 + 442368);      // 56*768 bf16
    float*    HOUT  = R1 + 463872;                   // 3145728
    float*    SDT   = R1 + 3609600;                  // 196608
    ushort_t* XIN   = (ushort_t*)R2;                 // 16384*768 bf16 (over conv stuff)
    ushort_t* Zb    = (ushort_t*)R3;                 // 16384*768 bf16
    ushort_t* Ub    = (ushort_t*)R4;                 // 16384*768 bf16
    ushort_t* DTb   = (ushort_t*)R2;                 // dt/y bf16 over XIN

    const size_t XP_BYTES = (size_t)4 * 18 * 18 * 18 * CDIM * 2;
    const dim3 cgrid27(64, 3, 2);                    // (b*16+d, co/128, z)
    const dim3 cgrid1(128, 3);

    // ---- GSC block ----
    hipMemsetAsync(Xp, 0, XP_BYTES, stream);             // zero pad borders
    pad_kernel<<<1024, 384, 0, stream>>>(x, Xp);         // x channels-last
    wconv_kernel<<<576, 256, 0, stream>>>(w1, Wb27);
    cvt_bf16_kernel<<<144, 256, 0, stream>>>(w3, w3b, 36864);
    cvt_bf16_kernel<<<144, 256, 0, stream>>>(w4, w4b, 36864);
    conv3_kernel<<<cgrid27, 256, 0, stream>>>(Xp, Wb27, P0);             // c1
    conv1x1_kernel<<<cgrid1, 256, 0, stream>>>(Xp, w3b, R3);             // c3
    inorm_stats2_kernel<<<1536, 256, 0, stream>>>(P0, P1, SA);
    pad_fuse2_kernel<<<1024, 384, 0, stream>>>(P0, P1, SA, Xp);          // x1a
    wconv_kernel<<<576, 256, 0, stream>>>(w2, Wb27);
    conv3_kernel<<<cgrid27, 256, 0, stream>>>(Xp, Wb27, P0);             // c2
    inorm_stats2_kernel<<<1536, 256, 0, stream>>>(P0, P1, SA);           // c2 stats
    inorm_stats_kernel<<<1536, 256, 0, stream>>>(R3, SB);                // c3 stats
    pad_fuse3_kernel<<<1024, 384, 0, stream>>>(P0, P1, SA, R3, SB, Xp);  // S
    conv1x1_kernel<<<cgrid1, 256, 0, stream>>>(Xp, w4b, R3);             // c4
    inorm_stats_kernel<<<1536, 256, 0, stream>>>(R3, SA);                // c4 stats
    // ---- fused relu(IN(c4)) + x residual + LayerNorm -> tn bf16 [b][l][c]
    layernorm_kernel<<<4096, 256, 0, stream>>>(R3, SA, x, ln_g, ln_b, tnb);
    // ---- weight converts (R1 free now)
    cvt_bf16_kernel<<<576, 256, 0, stream>>>(in_proj_w, ipwb, 147456);
    cvt_bf16_kernel<<<288, 256, 0, stream>>>(out_proj_w, opwb, 73728);
    cvt_bf16_kernel<<<42, 256, 0, stream>>>(x_proj_w, xpwb, 10752);
    // ---- in_proj (bf16 MFMA): tn x W^T -> split XIN | Zb (bf16)
    gemm_mfma_kernel<ushort_t, 1><<<dim3(12, 128), 256, 0, stream>>>(
        tnb, ipwb, XIN, Zb, 16384, 1536, CDIM, 0);
    // ---- causal depthwise conv + SiLU -> Ub (bf16)
    dwconv_silu_kernel<<<dim3(3, 4096, 4), 256, 0, stream>>>(XIN, conv1d_w, conv1d_b, Ub);
    // ---- x_proj (bf16 MFMA, N=56 masked): u x W^T -> DBL (fp32)
    gemm_mfma_kernel<ushort_t, 0><<<dim3(1, 128), 256, 0, stream>>>(
        Ub, xpwb, DBL, nullptr, 16384, 56, DINC, 56);
    // ---- dt_proj (fp32 VALU, K=24) + bias + softplus -> DTb (bf16, over XIN)
    gemm_dtproj_kernel<<<dim3(12, 128), 256, 0, stream>>>(
        DBL, dt_proj_w, DTb, dt_proj_b, 16384, DINC, 24, 56, 24, DINC);
    // ---- chunked parallel selective scan (y bf16 over DTb)
    scan_phase1_kernel<<<dim3(3, NCHUNK, 4), 256, 0, stream>>>(
        DTb, Ub, DBL, A_log, HOUT, SDT);
    scan_phase2_kernel<<<192, 256, 0, stream>>>(HOUT, SDT, A_log);
    scan_phase3_kernel<<<dim3(3, NCHUNK, 4), 256, 0, stream>>>(
        DTb, Ub, DBL, Zb, A_log, D_skip, HOUT);
    // ---- out_proj (bf16 MFMA) -> d_out transposed fp32
    gemm_mfma_kernel<ushort_t, 2><<<dim3(3, 128), 256, 0, stream>>>(
        DTb, opwb, out, nullptr, 16384, CDIM, DINC, 0);
}

// Round 7
// 965.427 us; speedup vs baseline: 1.1881x; 1.1881x over previous
//
#include <hip/hip_runtime.h>
#include <math.h>

#define CDIM 384
#define SDIM 4096
#define BDIM 4
#define DINC 768
#define NST  16
#define NCHUNK 64
#define LCHUNK 64
#define PSTRIDE 6291456   // floats per conv partial [B,C,S]

typedef unsigned short ushort_t;
typedef unsigned int uint_t;
typedef __attribute__((ext_vector_type(4))) float f32x4;
typedef __attribute__((ext_vector_type(8))) short bf16x8;

__device__ __forceinline__ ushort_t f2bf(float f) {
    union { float f; uint_t u; } v; v.f = f;
    uint_t r = v.u + 0x7FFFu + ((v.u >> 16) & 1u);   // round-to-nearest-even
    return (ushort_t)(r >> 16);
}
__device__ __forceinline__ float bf2f(ushort_t u) {
    union { uint_t i; float f; } v; v.i = ((uint_t)u) << 16; return v.f;
}
__device__ __forceinline__ uint_t pk2(float a, float b) {
    return (uint_t)f2bf(a) | ((uint_t)f2bf(b) << 16);
}

// ---------------------------------------------------------------------------
// fp32 -> bf16 flat convert (n4 = n/4).
// ---------------------------------------------------------------------------
__global__ __launch_bounds__(256)
void cvt_bf16_kernel(const float* __restrict__ src, ushort_t* __restrict__ dst, int n4) {
    const int i = blockIdx.x * 256 + threadIdx.x;
    if (i >= n4) return;
    float4 v = ((const float4*)src)[i];
    uint2 o; o.x = pk2(v.x, v.y); o.y = pk2(v.z, v.w);
    ((uint2*)dst)[i] = o;
}

// ---------------------------------------------------------------------------
// Weight convert 3x3x3: W[co][ci][27] fp32 -> Wb[tap][co][ci] bf16.
// ---------------------------------------------------------------------------
__global__ __launch_bounds__(256)
void wconv_kernel(const float* __restrict__ W, ushort_t* __restrict__ Wb) {
    const int idx = blockIdx.x * 256 + threadIdx.x;      // co*384 + ci
    const float* wp = W + (size_t)idx * 27;
#pragma unroll
    for (int tap = 0; tap < 27; ++tap)
        Wb[(size_t)tap * (CDIM * CDIM) + idx] = f2bf(wp[tap]);
}

// ---------------------------------------------------------------------------
// Pad + transpose to channels-last bf16: src[b][c][16^3] -> Xp[b][18][18][18][384]
// ---------------------------------------------------------------------------
__global__ __launch_bounds__(384)
void pad_kernel(const float* __restrict__ src, ushort_t* __restrict__ Xp) {
    const int blk = blockIdx.x;                          // b(4) d(16) h(16)
    const int b = blk >> 8, d = (blk >> 4) & 15, h = blk & 15;
    const int ci = threadIdx.x;
    const float* sp = src + (size_t)(b * CDIM + ci) * SDIM + d * 256 + h * 16;
    ushort_t* dp = Xp + ((((size_t)(b * 18 + d + 1) * 18) + (h + 1)) * 18 + 1) * CDIM + ci;
#pragma unroll
    for (int w = 0; w < 16; ++w)
        dp[(size_t)w * CDIM] = f2bf(sp[w]);
}

// ---------------------------------------------------------------------------
// Fused: v = relu((P0+P1+P2 - m)*r) -> pad/transpose channels-last bf16 Xp.
// ---------------------------------------------------------------------------
__global__ __launch_bounds__(384)
void pad_fuseA_kernel(const float* __restrict__ P0, const float* __restrict__ P1,
                      const float* __restrict__ P2, const float* __restrict__ stats,
                      ushort_t* __restrict__ Xp) {
    const int blk = blockIdx.x;
    const int b = blk >> 8, d = (blk >> 4) & 15, h = blk & 15;
    const int ci = threadIdx.x;
    const size_t o = (size_t)(b * CDIM + ci) * SDIM + d * 256 + h * 16;
    const float m = stats[(b * CDIM + ci) * 2], r = stats[(b * CDIM + ci) * 2 + 1];
    ushort_t* dp = Xp + ((((size_t)(b * 18 + d + 1) * 18) + (h + 1)) * 18 + 1) * CDIM + ci;
#pragma unroll
    for (int w = 0; w < 16; ++w) {
        const float v = P0[o + w] + P1[o + w] + P2[o + w];
        dp[(size_t)w * CDIM] = f2bf(fmaxf((v - m) * r, 0.f));
    }
}

// ---------------------------------------------------------------------------
// Fused: S = relu((P0+P1+P2-m2)*r2) + relu((C3-m3)*r3) -> pad channels-last.
// ---------------------------------------------------------------------------
__global__ __launch_bounds__(384)
void pad_fuseB_kernel(const float* __restrict__ P0, const float* __restrict__ P1,
                      const float* __restrict__ P2, const float* __restrict__ st2,
                      const float* __restrict__ C3, const float* __restrict__ st3,
                      ushort_t* __restrict__ Xp) {
    const int blk = blockIdx.x;
    const int b = blk >> 8, d = (blk >> 4) & 15, h = blk & 15;
    const int ci = threadIdx.x;
    const size_t o = (size_t)(b * CDIM + ci) * SDIM + d * 256 + h * 16;
    const float m2 = st2[(b * CDIM + ci) * 2], r2 = st2[(b * CDIM + ci) * 2 + 1];
    const float m3 = st3[(b * CDIM + ci) * 2], r3 = st3[(b * CDIM + ci) * 2 + 1];
    ushort_t* dp = Xp + ((((size_t)(b * 18 + d + 1) * 18) + (h + 1)) * 18 + 1) * CDIM + ci;
#pragma unroll
    for (int w = 0; w < 16; ++w) {
        const float x1 = fmaxf((P0[o + w] + P1[o + w] + P2[o + w] - m2) * r2, 0.f);
        const float x2 = fmaxf((C3[o + w] - m3) * r3, 0.f);
        dp[(size_t)w * CDIM] = f2bf(x1 + x2);
    }
}

// ---------------------------------------------------------------------------
// 3x3x3 implicit-GEMM conv via MFMA bf16 (round-5 proven 128x128 structure),
// kd-aligned 3-way K-split: z covers taps 9z..9z+8 (kd=z fixed, so the B
// pointer never kd-wraps). Partials: z<2 -> Y01 + z*PSTRIDE, z=2 -> Y2.
// Block 128co x 128sp, 4 waves 2x2, BK=32, dbuf LDS 40KB, VGPR ~60 ->
// 4 blocks/CU; grid 1152 = 4.5 blocks/CU for latency overlap.
// ---------------------------------------------------------------------------
__global__ __launch_bounds__(256)
void conv3z_kernel(const ushort_t* __restrict__ Xp, const ushort_t* __restrict__ Wb,
                   float* __restrict__ Y01, float* __restrict__ Y2) {
    const int nt = blockIdx.x;
    const int b  = nt >> 5;
    const int d  = (nt >> 1) & 15;
    const int h0 = (nt & 1) * 8;
    const int co0 = blockIdx.y * 128;
    const int z = blockIdx.z;
    const int t = threadIdx.x;
    const int lane = t & 63;
    const int wid = t >> 6;
    const int wy = wid >> 1, wx = wid & 1;

    float* Y = (z == 2) ? Y2 : (Y01 + (size_t)z * PSTRIDE);
    const int iters = 9 * 12;                            // 9 taps x 12 ci-chunks

    __shared__ ushort_t As[2][128 * 40];
    __shared__ ushort_t Bs[2][128 * 40];

    f32x4 acc[4][4];
#pragma unroll
    for (int i = 0; i < 4; ++i)
#pragma unroll
        for (int j = 0; j < 4; ++j) acc[i][j] = (f32x4){0.f, 0.f, 0.f, 0.f};

    const int arow = t >> 1, half = t & 1;
    const int hl = arow >> 4, w = arow & 15;
    const int wA = arow * 40 + half * 16;

    const int lm = lane & 15, lk = (lane >> 4) * 8;
    const int rA0 = (wy * 64 + lm) * 40 + lk;
    const int rB0 = (wx * 64 + lm) * 40 + lk;

    // incremental pointers: +32/iter; A +147072 on tap wrap (12 chunks);
    // B: kw wraps are seamless (12*32 == CDIM); kh wrap += 5760.
    const ushort_t* ap = Wb + (size_t)(9 * z) * (CDIM * CDIM)
                       + (size_t)(co0 + arow) * CDIM + half * 16;
    const ushort_t* bp = Xp + ((((size_t)(b * 18 + d + z) * 18) + (h0 + hl)) * 18
                               + w) * CDIM + half * 16;
    int c12 = 0, ckw = 0;

    uint4 ra0, ra1, rb0, rb1;

    auto loadg = [&]() {
        const uint4* pa = reinterpret_cast<const uint4*>(ap);
        ra0 = pa[0]; ra1 = pa[1];
        const uint4* pb = reinterpret_cast<const uint4*>(bp);
        rb0 = pb[0]; rb1 = pb[1];
        ap += 32; bp += 32;
        if (++c12 == 12) {                               // tap wrap
            c12 = 0;
            ap += CDIM * CDIM - 384;
            if (++ckw == 3) { ckw = 0; bp += 5760; }     // kh step (kd fixed)
        }
    };
    auto lwrite = [&](int buf) {
        *reinterpret_cast<uint4*>(&As[buf][wA])     = ra0;
        *reinterpret_cast<uint4*>(&As[buf][wA + 8]) = ra1;
        *reinterpret_cast<uint4*>(&Bs[buf][wA])     = rb0;
        *reinterpret_cast<uint4*>(&Bs[buf][wA + 8]) = rb1;
    };

    loadg();
    lwrite(0);
    __syncthreads();

    int buf = 0;
    for (int idx = 0; idx < iters; ++idx) {
        const bool more = (idx + 1) < iters;
        if (more) loadg();                               // issue early
        bf16x8 af[4], bfr[4];
#pragma unroll
        for (int mi = 0; mi < 4; ++mi)
            af[mi] = *reinterpret_cast<const bf16x8*>(&As[buf][rA0 + mi * 640]);
#pragma unroll
        for (int ni = 0; ni < 4; ++ni)
            bfr[ni] = *reinterpret_cast<const bf16x8*>(&Bs[buf][rB0 + ni * 640]);
#pragma unroll
        for (int mi = 0; mi < 4; ++mi)
#pragma unroll
            for (int ni = 0; ni < 4; ++ni)
                acc[mi][ni] = __builtin_amdgcn_mfma_f32_16x16x32_bf16(
                    af[mi], bfr[ni], acc[mi][ni], 0, 0, 0);
        if (more) lwrite(buf ^ 1);                       // write late
        __syncthreads();
        buf ^= 1;
    }

    // epilogue: C/D layout col(lane&15)=sp, row=(lane>>4)*4+j=co
    const int coB = co0 + wy * 64 + (lane >> 4) * 4;
    const int nB  = wx * 64 + lm;
#pragma unroll
    for (int mi = 0; mi < 4; ++mi) {
#pragma unroll
        for (int ni = 0; ni < 4; ++ni) {
            const int nl = nB + ni * 16;
            const int s = d * 256 + (h0 + (nl >> 4)) * 16 + (nl & 15);
            float* yp = Y + ((size_t)b * CDIM + (coB + mi * 16)) * SDIM + s;
#pragma unroll
            for (int j = 0; j < 4; ++j)
                yp[(size_t)j * SDIM] = acc[mi][ni][j];
        }
    }
}

// ---------------------------------------------------------------------------
// 1x1x1 conv via MFMA bf16 (proven). Block 128co x 128sp, 4 waves, BK=32.
// ---------------------------------------------------------------------------
__global__ __launch_bounds__(256)
void conv1x1_kernel(const ushort_t* __restrict__ Xp, const ushort_t* __restrict__ Wb,
                    float* __restrict__ Y) {
    const int nt = blockIdx.x;
    const int b  = nt >> 5;
    const int d  = (nt >> 1) & 15;
    const int h0 = (nt & 1) * 8;
    const int co0 = blockIdx.y * 128;
    const int t = threadIdx.x;
    const int lane = t & 63;
    const int wid = t >> 6;
    const int wy = wid >> 1, wx = wid & 1;

    __shared__ ushort_t As[2][128 * 40];
    __shared__ ushort_t Bs[2][128 * 40];

    f32x4 acc[4][4];
#pragma unroll
    for (int i = 0; i < 4; ++i)
#pragma unroll
        for (int j = 0; j < 4; ++j) acc[i][j] = (f32x4){0.f, 0.f, 0.f, 0.f};

    const int arow = t >> 1, half = t & 1;
    const int hl = arow >> 4, w = arow & 15;
    const int wA = arow * 40 + half * 16;

    const int lm = lane & 15, lk = (lane >> 4) * 8;
    const int rA0 = (wy * 64 + lm) * 40 + lk;
    const int rB0 = (wx * 64 + lm) * 40 + lk;

    const ushort_t* ap = Wb + (size_t)(co0 + arow) * CDIM + half * 16;
    const ushort_t* bp = Xp + ((((size_t)(b * 18 + d + 1) * 18) + (h0 + hl + 1)) * 18
                               + (w + 1)) * CDIM + half * 16;
    uint4 ra0, ra1, rb0, rb1;
    auto loadg = [&]() {
        const uint4* pa = reinterpret_cast<const uint4*>(ap);
        ra0 = pa[0]; ra1 = pa[1];
        const uint4* pb = reinterpret_cast<const uint4*>(bp);
        rb0 = pb[0]; rb1 = pb[1];
        ap += 32; bp += 32;
    };
    auto lwrite = [&](int buf) {
        *reinterpret_cast<uint4*>(&As[buf][wA])     = ra0;
        *reinterpret_cast<uint4*>(&As[buf][wA + 8]) = ra1;
        *reinterpret_cast<uint4*>(&Bs[buf][wA])     = rb0;
        *reinterpret_cast<uint4*>(&Bs[buf][wA + 8]) = rb1;
    };

    loadg();
    lwrite(0);
    __syncthreads();

    int buf = 0;
    for (int idx = 0; idx < 12; ++idx) {
        const bool more = (idx + 1) < 12;
        if (more) loadg();
        bf16x8 af[4], bfr[4];
#pragma unroll
        for (int mi = 0; mi < 4; ++mi)
            af[mi] = *reinterpret_cast<const bf16x8*>(&As[buf][rA0 + mi * 640]);
#pragma unroll
        for (int ni = 0; ni < 4; ++ni)
            bfr[ni] = *reinterpret_cast<const bf16x8*>(&Bs[buf][rB0 + ni * 640]);
#pragma unroll
        for (int mi = 0; mi < 4; ++mi)
#pragma unroll
            for (int ni = 0; ni < 4; ++ni)
                acc[mi][ni] = __builtin_amdgcn_mfma_f32_16x16x32_bf16(
                    af[mi], bfr[ni], acc[mi][ni], 0, 0, 0);
        if (more) lwrite(buf ^ 1);
        __syncthreads();
        buf ^= 1;
    }

    const int coB = co0 + wy * 64 + (lane >> 4) * 4;
    const int nB  = wx * 64 + lm;
#pragma unroll
    for (int mi = 0; mi < 4; ++mi) {
#pragma unroll
        for (int ni = 0; ni < 4; ++ni) {
            const int nl = nB + ni * 16;
            const int s = d * 256 + (h0 + (nl >> 4)) * 16 + (nl & 15);
            float* yp = Y + ((size_t)b * CDIM + (coB + mi * 16)) * SDIM + s;
#pragma unroll
            for (int j = 0; j < 4; ++j)
                yp[(size_t)j * SDIM] = acc[mi][ni][j];
        }
    }
}

// ---------------------------------------------------------------------------
// bf16 MFMA GEMM, NT: C[M,N] = A[M,K] x B[N,K]^T. A bf16 (AT=ushort_t) or
// fp32 converted-on-stage (AT=float). Tile 128x128xBK32, 4 waves.
// EPI 0: fp32 store (ldc); 1: xz split -> bf16 C/C2 (N=1536);
// EPI 2: transposed fp32 float4 store C[b][n][l].
// ---------------------------------------------------------------------------
template<typename AT, int EPI>
__global__ __launch_bounds__(256)
void gemm_mfma_kernel(const AT* __restrict__ A, const ushort_t* __restrict__ Bw,
                      void* __restrict__ Cv, void* __restrict__ C2v,
                      int M, int N, int K, int ldc) {
    const int n0 = blockIdx.x * 128;
    const int m0 = blockIdx.y * 128;
    const int t = threadIdx.x;
    const int lane = t & 63;
    const int wid = t >> 6;
    const int wy = wid >> 1, wx = wid & 1;

    __shared__ ushort_t As[2][128 * 40];
    __shared__ ushort_t Bs[2][128 * 40];

    f32x4 acc[4][4];
#pragma unroll
    for (int i = 0; i < 4; ++i)
#pragma unroll
        for (int j = 0; j < 4; ++j) acc[i][j] = (f32x4){0.f, 0.f, 0.f, 0.f};

    const int arow = t >> 1, half = t & 1;
    const int wA = arow * 40 + half * 16;
    const int lm = lane & 15, lk = (lane >> 4) * 8;
    const int rA0 = (wy * 64 + lm) * 40 + lk;
    const int rB0 = (wx * 64 + lm) * 40 + lk;

    uint4 ra0, ra1, rb0, rb1;

    auto loadg = [&](int kk) {
        const int kb = kk * 32 + half * 16;
        if constexpr (sizeof(AT) == 2) {                 // bf16 A
            const uint4* pa = reinterpret_cast<const uint4*>(
                (const ushort_t*)A + (size_t)(m0 + arow) * K + kb);
            ra0 = pa[0]; ra1 = pa[1];
        } else {                                         // fp32 A, convert
            const float4* pa = reinterpret_cast<const float4*>(
                (const float*)A + (size_t)(m0 + arow) * K + kb);
            float4 f0 = pa[0], f1 = pa[1], f2 = pa[2], f3 = pa[3];
            ra0.x = pk2(f0.x, f0.y); ra0.y = pk2(f0.z, f0.w);
            ra0.z = pk2(f1.x, f1.y); ra0.w = pk2(f1.z, f1.w);
            ra1.x = pk2(f2.x, f2.y); ra1.y = pk2(f2.z, f2.w);
            ra1.z = pk2(f3.x, f3.y); ra1.w = pk2(f3.z, f3.w);
        }
        if (n0 + arow < N) {
            const uint4* pb = reinterpret_cast<const uint4*>(
                Bw + (size_t)(n0 + arow) * K + kb);
            rb0 = pb[0]; rb1 = pb[1];
        } else {
            rb0 = make_uint4(0, 0, 0, 0); rb1 = rb0;
        }
    };
    auto lwrite = [&](int buf) {
        *reinterpret_cast<uint4*>(&As[buf][wA])     = ra0;
        *reinterpret_cast<uint4*>(&As[buf][wA + 8]) = ra1;
        *reinterpret_cast<uint4*>(&Bs[buf][wA])     = rb0;
        *reinterpret_cast<uint4*>(&Bs[buf][wA + 8]) = rb1;
    };

    const int KI = K >> 5;
    loadg(0);
    lwrite(0);
    __syncthreads();

    int buf = 0;
    for (int kk = 0; kk < KI; ++kk) {
        const bool more = (kk + 1) < KI;
        if (more) loadg(kk + 1);
        bf16x8 af[4], bfr[4];
#pragma unroll
        for (int mi = 0; mi < 4; ++mi)
            af[mi] = *reinterpret_cast<const bf16x8*>(&As[buf][rA0 + mi * 640]);
#pragma unroll
        for (int ni = 0; ni < 4; ++ni)
            bfr[ni] = *reinterpret_cast<const bf16x8*>(&Bs[buf][rB0 + ni * 640]);
#pragma unroll
        for (int mi = 0; mi < 4; ++mi)
#pragma unroll
            for (int ni = 0; ni < 4; ++ni)
                acc[mi][ni] = __builtin_amdgcn_mfma_f32_16x16x32_bf16(
                    af[mi], bfr[ni], acc[mi][ni], 0, 0, 0);
        if (more) lwrite(buf ^ 1);
        __syncthreads();
        buf ^= 1;
    }

    const int mB = m0 + wy * 64 + (lane >> 4) * 4;
    const int nB = n0 + wx * 64 + lm;
#pragma unroll
    for (int mi = 0; mi < 4; ++mi) {
#pragma unroll
        for (int ni = 0; ni < 4; ++ni) {
            const int n = nB + ni * 16;
            if (EPI == 2) {                              // transposed float4
                const int mrow = mB + mi * 16;
                const int bb = mrow >> 12, l = mrow & 4095;
                float4 st = {acc[mi][ni][0], acc[mi][ni][1],
                             acc[mi][ni][2], acc[mi][ni][3]};
                *reinterpret_cast<float4*>(
                    (float*)Cv + ((size_t)(bb * CDIM + n)) * SDIM + l) = st;
            } else {
#pragma unroll
                for (int j = 0; j < 4; ++j) {
                    const int m = mB + mi * 16 + j;
                    const float v = acc[mi][ni][j];
                    if (EPI == 0) {
                        if (n < N) ((float*)Cv)[(size_t)m * ldc + n] = v;
                    } else {                             // xz split, bf16 out
                        if (n < DINC) ((ushort_t*)Cv)[(size_t)m * DINC + n] = f2bf(v);
                        else ((ushort_t*)C2v)[(size_t)m * DINC + (n - DINC)] = f2bf(v);
                    }
                }
            }
        }
    }
}

// ---------------------------------------------------------------------------
// InstanceNorm stats, single input: one block per (b,c).
// ---------------------------------------------------------------------------
__global__ __launch_bounds__(256)
void inorm_stats_kernel(const float* __restrict__ X, float* __restrict__ stats) {
    const int bc = blockIdx.x;
    const float* xp = X + (size_t)bc * SDIM;
    float s = 0.f, ss = 0.f;
    for (int i = threadIdx.x * 4; i < SDIM; i += 1024) {
        float4 v = *(const float4*)(xp + i);
        s += v.x + v.y + v.z + v.w;
        ss += v.x * v.x + v.y * v.y + v.z * v.z + v.w * v.w;
    }
#pragma unroll
    for (int off = 32; off > 0; off >>= 1) {
        s += __shfl_down(s, off);
        ss += __shfl_down(ss, off);
    }
    __shared__ float rs[4], rss[4];
    const int wid = threadIdx.x >> 6;
    if ((threadIdx.x & 63) == 0) { rs[wid] = s; rss[wid] = ss; }
    __syncthreads();
    if (threadIdx.x == 0) {
        float S = rs[0] + rs[1] + rs[2] + rs[3];
        float SS = rss[0] + rss[1] + rss[2] + rss[3];
        float m = S * (1.f / SDIM);
        float var = SS * (1.f / SDIM) - m * m;
        stats[bc * 2] = m;
        stats[bc * 2 + 1] = rsqrtf(var + 1e-5f);
    }
}

// ---------------------------------------------------------------------------
// InstanceNorm stats over the SUM of three partials.
// ---------------------------------------------------------------------------
__global__ __launch_bounds__(256)
void inorm_stats3_kernel(const float* __restrict__ P0, const float* __restrict__ P1,
                         const float* __restrict__ P2, float* __restrict__ stats) {
    const int bc = blockIdx.x;
    const float* p0 = P0 + (size_t)bc * SDIM;
    const float* p1 = P1 + (size_t)bc * SDIM;
    const float* p2 = P2 + (size_t)bc * SDIM;
    float s = 0.f, ss = 0.f;
    for (int i = threadIdx.x * 4; i < SDIM; i += 1024) {
        float4 a = *(const float4*)(p0 + i);
        float4 c = *(const float4*)(p1 + i);
        float4 e = *(const float4*)(p2 + i);
        const float vx = a.x + c.x + e.x, vy = a.y + c.y + e.y;
        const float vz = a.z + c.z + e.z, vw = a.w + c.w + e.w;
        s += vx + vy + vz + vw;
        ss += vx * vx + vy * vy + vz * vz + vw * vw;
    }
#pragma unroll
    for (int off = 32; off > 0; off >>= 1) {
        s += __shfl_down(s, off);
        ss += __shfl_down(ss, off);
    }
    __shared__ float rs[4], rss[4];
    const int wid = threadIdx.x >> 6;
    if ((threadIdx.x & 63) == 0) { rs[wid] = s; rss[wid] = ss; }
    __syncthreads();
    if (threadIdx.x == 0) {
        float S = rs[0] + rs[1] + rs[2] + rs[3];
        float SS = rss[0] + rss[1] + rss[2] + rss[3];
        float m = S * (1.f / SDIM);
        float var = SS * (1.f / SDIM) - m * m;
        stats[bc * 2] = m;
        stats[bc * 2 + 1] = rsqrtf(var + 1e-5f);
    }
}

// ---------------------------------------------------------------------------
// Fused LayerNorm: xg = relu((C4-m)*r) + x inline, LN over C, transpose
// -> tn [b][l][c] bf16.
// ---------------------------------------------------------------------------
__global__ __launch_bounds__(256)
void layernorm_kernel(const float* __restrict__ C4, const float* __restrict__ stats,
                      const float* __restrict__ X, const float* __restrict__ gam,
                      const float* __restrict__ bet, ushort_t* __restrict__ Tn) {
    const int token = blockIdx.x * 4 + (threadIdx.x >> 6);
    const int lane = threadIdx.x & 63;
    const int b = token >> 12, l = token & 4095;
    const size_t base = (size_t)b * CDIM * SDIM + l;
    float v[6];
    float s = 0.f, ss = 0.f;
#pragma unroll
    for (int i = 0; i < 6; ++i) {
        const int c = lane + i * 64;
        const size_t o = base + (size_t)c * SDIM;
        const float m = stats[(b * CDIM + c) * 2], r = stats[(b * CDIM + c) * 2 + 1];
        v[i] = fmaxf((C4[o] - m) * r, 0.f) + X[o];
        s += v[i]; ss += v[i] * v[i];
    }
#pragma unroll
    for (int off = 32; off > 0; off >>= 1) {
        s += __shfl_down(s, off);
        ss += __shfl_down(ss, off);
    }
    s = __shfl(s, 0); ss = __shfl(ss, 0);
    const float m = s * (1.f / CDIM);
    const float r = rsqrtf(ss * (1.f / CDIM) - m * m + 1e-5f);
    ushort_t* tp = Tn + (size_t)token * CDIM;
#pragma unroll
    for (int i = 0; i < 6; ++i) {
        const int c = lane + i * 64;
        tp[c] = f2bf((v[i] - m) * r * gam[c] + bet[c]);
    }
}

// ---------------------------------------------------------------------------
// Tiled fp32 GEMM for dt_proj (K=24), NT, bias+softplus, bf16 store.
// ---------------------------------------------------------------------------
__global__ __launch_bounds__(256)
void gemm_dtproj_kernel(const float* __restrict__ A, const float* __restrict__ B,
                        ushort_t* __restrict__ C, const float* __restrict__ bias,
                        int M, int N, int K, int lda, int ldb, int ldc) {
    __shared__ __align__(16) float As[16][132];
    __shared__ __align__(16) float Bs[16][68];
    const int t = threadIdx.x;
    const int m0 = blockIdx.y * 128;
    const int n0 = blockIdx.x * 64;

    float acc[8][4];
#pragma unroll
    for (int i = 0; i < 8; ++i)
#pragma unroll
        for (int j = 0; j < 4; ++j) acc[i][j] = 0.f;

    const int mr = (t & 15) * 8;
    const int nr = (t >> 4) * 4;

    for (int k0 = 0; k0 < K; k0 += 16) {
#pragma unroll
        for (int idx = 0; idx < 8; ++idx) {
            const int e = idx * 256 + t;
            const int k = e & 15, m = e >> 4;
            float v = 0.f;
            if (k0 + k < K) v = A[(size_t)(m0 + m) * lda + (k0 + k)];
            As[k][m] = v;
        }
#pragma unroll
        for (int idx = 0; idx < 4; ++idx) {
            const int e = idx * 256 + t;
            const int k = e & 15, n = e >> 4;
            float v = 0.f;
            if ((n0 + n) < N && (k0 + k) < K) v = B[(size_t)(n0 + n) * ldb + (k0 + k)];
            Bs[k][n] = v;
        }
        __syncthreads();
#pragma unroll
        for (int k = 0; k < 16; ++k) {
            float4 a0 = *(const float4*)&As[k][mr];
            float4 a1 = *(const float4*)&As[k][mr + 4];
            float4 b0 = *(const float4*)&Bs[k][nr];
            const float av[8] = {a0.x, a0.y, a0.z, a0.w, a1.x, a1.y, a1.z, a1.w};
            const float bv[4] = {b0.x, b0.y, b0.z, b0.w};
#pragma unroll
            for (int i = 0; i < 8; ++i)
#pragma unroll
                for (int j = 0; j < 4; ++j)
                    acc[i][j] = fmaf(av[i], bv[j], acc[i][j]);
        }
        __syncthreads();
    }

#pragma unroll
    for (int i = 0; i < 8; ++i) {
        const int m = m0 + mr + i;
#pragma unroll
        for (int j = 0; j < 4; ++j) {
            const int n = n0 + nr + j;
            if (n >= N) continue;
            float v = acc[i][j] + bias[n];
            v = (v > 20.f) ? v : log1pf(__expf(v));
            C[(size_t)m * ldc + n] = f2bf(v);
        }
    }
}

// ---------------------------------------------------------------------------
// Causal depthwise conv1d (K=4) + bias + SiLU, bf16 in/out.
// ---------------------------------------------------------------------------
__global__ __launch_bounds__(256)
void dwconv_silu_kernel(const ushort_t* __restrict__ Xin, const float* __restrict__ W,
                        const float* __restrict__ bias, ushort_t* __restrict__ U) {
    const int dch = blockIdx.x * 256 + threadIdx.x;
    const int l = blockIdx.y, b = blockIdx.z;
    const float4 w4 = ((const float4*)W)[dch];
    const float wk[4] = {w4.x, w4.y, w4.z, w4.w};
    const ushort_t* xp = Xin + ((size_t)b * 4096 + l) * DINC + dch;
    float acc = bias[dch];
#pragma unroll
    for (int k = 0; k < 4; ++k) {
        const int ll = l - 3 + k;
        if (ll >= 0) acc = fmaf(bf2f(xp[(k - 3) * DINC]), wk[k], acc);
    }
    U[((size_t)b * 4096 + l) * DINC + dch] = f2bf(acc / (1.f + __expf(-acc)));
}

// ---------------------------------------------------------------------------
// Chunked parallel selective scan (3 phases). dt/u/z/y bf16; B,C fp32.
// ---------------------------------------------------------------------------
__global__ __launch_bounds__(256)
void scan_phase1_kernel(const ushort_t* __restrict__ DT, const ushort_t* __restrict__ U,
                        const float* __restrict__ DBL, const float* __restrict__ A_log,
                        float* __restrict__ HOUT, float* __restrict__ SDT) {
    const int b = blockIdx.z, chunk = blockIdx.y;
    const int dch = blockIdx.x * 256 + threadIdx.x;
    float Arow[16];
#pragma unroll
    for (int n = 0; n < NST; ++n) Arow[n] = -__expf(A_log[dch * NST + n]);

    __shared__ float bcs[LCHUNK][16];
    const size_t tokbase = (size_t)b * 4096 + chunk * LCHUNK;
#pragma unroll
    for (int idx = 0; idx < 4; ++idx) {
        const int e = idx * 256 + threadIdx.x;
        bcs[e >> 4][e & 15] = DBL[(tokbase + (e >> 4)) * 56 + 24 + (e & 15)];
    }
    __syncthreads();

    size_t off = tokbase * DINC + dch;
    float h[16];
#pragma unroll
    for (int n = 0; n < NST; ++n) h[n] = 0.f;
    float sdt = 0.f;
    float cdt = bf2f(DT[off]), cu = bf2f(U[off]);
    for (int t = 0; t < LCHUNK; ++t) {
        float ndt = 0.f, nu = 0.f;
        if (t < LCHUNK - 1) { ndt = bf2f(DT[off + DINC]); nu = bf2f(U[off + DINC]); }
        sdt += cdt;
        const float du = cdt * cu;
#pragma unroll
        for (int n = 0; n < NST; ++n)
            h[n] = __expf(cdt * Arow[n]) * h[n] + du * bcs[t][n];
        off += DINC;
        cdt = ndt; cu = nu;
    }
    float* hp = HOUT + (((size_t)(b * DINC + dch) * NCHUNK + chunk) << 4);
#pragma unroll
    for (int n = 0; n < NST; ++n) hp[n] = h[n];
    SDT[(size_t)(b * DINC + dch) * NCHUNK + chunk] = sdt;
}

__global__ __launch_bounds__(256)
void scan_phase2_kernel(float* __restrict__ HOUT, const float* __restrict__ SDT,
                        const float* __restrict__ A_log) {
    const int t = blockIdx.x * 256 + threadIdx.x;        // 49152
    const int b = t / (DINC * NST);
    const int rem = t - b * (DINC * NST);
    const int d = rem >> 4, n = rem & 15;
    const float An = -__expf(A_log[d * NST + n]);
    float* hp = HOUT + (((size_t)(b * DINC + d) * NCHUNK) << 4) + n;
    const float* sp = SDT + (size_t)(b * DINC + d) * NCHUNK;
    float H = 0.f;
    for (int c = 0; c < NCHUNK; ++c) {
        const float tmp = hp[c * 16];
        const float dA = __expf(An * sp[c]);
        hp[c * 16] = H;
        H = dA * H + tmp;
    }
}

__global__ __launch_bounds__(256)
void scan_phase3_kernel(ushort_t* __restrict__ DT, const ushort_t* __restrict__ U,
                        const float* __restrict__ DBL, const ushort_t* __restrict__ Z,
                        const float* __restrict__ A_log, const float* __restrict__ D_skip,
                        const float* __restrict__ HOUT) {
    const int b = blockIdx.z, chunk = blockIdx.y;
    const int dch = blockIdx.x * 256 + threadIdx.x;
    float Arow[16];
#pragma unroll
    for (int n = 0; n < NST; ++n) Arow[n] = -__expf(A_log[dch * NST + n]);
    const float Dsk = D_skip[dch];

    __shared__ float bcs[LCHUNK][32];
    const size_t tokbase = (size_t)b * 4096 + chunk * LCHUNK;
#pragma unroll
    for (int idx = 0; idx < 8; ++idx) {
        const int e = idx * 256 + threadIdx.x;
        bcs[e >> 5][e & 31] = DBL[(tokbase + (e >> 5)) * 56 + 24 + (e & 31)];
    }
    __syncthreads();

    float h[16];
    const float* hp = HOUT + (((size_t)(b * DINC + dch) * NCHUNK + chunk) << 4);
#pragma unroll
    for (int n = 0; n < NST; ++n) h[n] = hp[n];

    size_t off = tokbase * DINC + dch;
    float cdt = bf2f(DT[off]), cu = bf2f(U[off]), cz = bf2f(Z[off]);
    for (int t = 0; t < LCHUNK; ++t) {
        float ndt = 0.f, nu = 0.f, nz = 0.f;
        if (t < LCHUNK - 1) {
            ndt = bf2f(DT[off + DINC]); nu = bf2f(U[off + DINC]); nz = bf2f(Z[off + DINC]);
        }
        const float du = cdt * cu;
        float y = 0.f;
#pragma unroll
        for (int n = 0; n < NST; ++n) {
            h[n] = __expf(cdt * Arow[n]) * h[n] + du * bcs[t][n];
            y = fmaf(h[n], bcs[t][16 + n], y);
        }
        y += cu * Dsk;
        const float sz = cz / (1.f + __expf(-cz));
        DT[off] = f2bf(y * sz);
        off += DINC;
        cdt = ndt; cu = nu; cz = nz;
    }
}

// ---------------------------------------------------------------------------
extern "C" void kernel_launch(void* const* d_in, const int* in_sizes, int n_in,
                              void* d_out, int out_size, void* d_ws, size_t ws_size,
                              hipStream_t stream) {
    (void)in_sizes; (void)n_in; (void)out_size; (void)ws_size;
    const float* x         = (const float*)d_in[0];
    const float* w1        = (const float*)d_in[1];
    const float* w2        = (const float*)d_in[3];
    const float* w3        = (const float*)d_in[5];
    const float* w4        = (const float*)d_in[7];
    const float* ln_g      = (const float*)d_in[9];
    const float* ln_b      = (const float*)d_in[10];
    const float* in_proj_w = (const float*)d_in[11];
    const float* conv1d_w  = (const float*)d_in[12];
    const float* conv1d_b  = (const float*)d_in[13];
    const float* x_proj_w  = (const float*)d_in[14];
    const float* dt_proj_w = (const float*)d_in[15];
    const float* dt_proj_b = (const float*)d_in[16];
    const float* A_log     = (const float*)d_in[17];
    const float* D_skip    = (const float*)d_in[18];
    const float* out_proj_w= (const float*)d_in[19];
    float* out = (float*)d_out;

    // Workspace regions (floats): R0..R4. Lifetimes disjoint where aliased.
    float* ws = (float*)d_ws;
    float* R0 = ws;                    //  6291456
    float* R1 = ws + 6291456;          //  6291456
    float* R2 = ws + 12582912;         // 12582912
    float* R3 = ws + 25165824;         // 12582912
    float* R4 = ws + 37748736;         // 12582912

    // GSC-phase aliases
    float*    P0    = R0;                            // conv partial z=0
    // P1 = R0 + PSTRIDE = R1 (contiguous)            // conv partial z=1
    float*    P1    = R1;
    float*    P2    = R4 + 8192;                     // conv partial z=2
    ushort_t* Wb27  = (ushort_t*)R2;                 // 3981312 bf16
    ushort_t* Xp    = (ushort_t*)(R2 + 2097152);     // 8957952 bf16
    ushort_t* w3b   = (ushort_t*)(R2 + 6576128);     // 147456 bf16
    ushort_t* w4b   = (ushort_t*)(R2 + 6649856);     // 147456 bf16
    float*    SA    = R4;                            // stats A (3072 fl)
    float*    SB    = R4 + 4096;                     // stats B (3072 fl)
    // Mamba-phase aliases
    ushort_t* tnb   = (ushort_t*)R0;                 // 16384*384 bf16
    float*    DBL   = R0 + 3145728;                  // 16384*56 fp32
    ushort_t* ipwb  = (ushort_t*)R1;                 // 1536*384 bf16
    ushort_t* opwb  = (ushort_t*)(R1 + 294912);      // 384*768 bf16
    ushort_t* xpwb  = (ushort_t*)(R1 + 442368);      // 56*768 bf16
    float*    HOUT  = R1 + 463872;                   // 3145728
    float*    SDT   = R1 + 3609600;                  // 196608
    ushort_t* XIN   = (ushort_t*)R2;                 // 16384*768 bf16 (over conv)
    ushort_t* Zb    = (ushort_t*)R3;                 // 16384*768 bf16
    ushort_t* Ub    = (ushort_t*)R4;                 // 16384*768 bf16
    ushort_t* DTb   = (ushort_t*)R2;                 // dt/y bf16 over XIN

    const size_t XP_BYTES = (size_t)4 * 18 * 18 * 18 * CDIM * 2;
    const dim3 cgrid27(128, 3, 3);                   // (b,d,h-half; co/128; z)
    const dim3 cgrid1(128, 3);

    // ---- GSC block ----
    hipMemsetAsync(Xp, 0, XP_BYTES, stream);             // zero pad borders
    pad_kernel<<<1024, 384, 0, stream>>>(x, Xp);         // x channels-last
    wconv_kernel<<<576, 256, 0, stream>>>(w1, Wb27);
    cvt_bf16_kernel<<<144, 256, 0, stream>>>(w3, w3b, 36864);
    cvt_bf16_kernel<<<144, 256, 0, stream>>>(w4, w4b, 36864);
    conv3z_kernel<<<cgrid27, 256, 0, stream>>>(Xp, Wb27, P0, P2);        // c1
    conv1x1_kernel<<<cgrid1, 256, 0, stream>>>(Xp, w3b, R3);             // c3
    inorm_stats3_kernel<<<1536, 256, 0, stream>>>(P0, P1, P2, SA);
    pad_fuseA_kernel<<<1024, 384, 0, stream>>>(P0, P1, P2, SA, Xp);      // x1a
    wconv_kernel<<<576, 256, 0, stream>>>(w2, Wb27);
    conv3z_kernel<<<cgrid27, 256, 0, stream>>>(Xp, Wb27, P0, P2);        // c2
    inorm_stats3_kernel<<<1536, 256, 0, stream>>>(P0, P1, P2, SA);       // c2 stats
    inorm_stats_kernel<<<1536, 256, 0, stream>>>(R3, SB);                // c3 stats
    pad_fuseB_kernel<<<1024, 384, 0, stream>>>(P0, P1, P2, SA, R3, SB, Xp); // S
    conv1x1_kernel<<<cgrid1, 256, 0, stream>>>(Xp, w4b, R3);             // c4
    inorm_stats_kernel<<<1536, 256, 0, stream>>>(R3, SA);                // c4 stats
    // ---- fused relu(IN(c4)) + x residual + LayerNorm -> tn bf16 [b][l][c]
    layernorm_kernel<<<4096, 256, 0, stream>>>(R3, SA, x, ln_g, ln_b, tnb);
    // ---- weight converts (R1 free now)
    cvt_bf16_kernel<<<576, 256, 0, stream>>>(in_proj_w, ipwb, 147456);
    cvt_bf16_kernel<<<288, 256, 0, stream>>>(out_proj_w, opwb, 73728);
    cvt_bf16_kernel<<<42, 256, 0, stream>>>(x_proj_w, xpwb, 10752);
    // ---- in_proj (bf16 MFMA): tn x W^T -> split XIN | Zb (bf16)
    gemm_mfma_kernel<ushort_t, 1><<<dim3(12, 128), 256, 0, stream>>>(
        tnb, ipwb, XIN, Zb, 16384, 1536, CDIM, 0);
    // ---- causal depthwise conv + SiLU -> Ub (bf16)
    dwconv_silu_kernel<<<dim3(3, 4096, 4), 256, 0, stream>>>(XIN, conv1d_w, conv1d_b, Ub);
    // ---- x_proj (bf16 MFMA, N=56 masked): u x W^T -> DBL (fp32)
    gemm_mfma_kernel<ushort_t, 0><<<dim3(1, 128), 256, 0, stream>>>(
        Ub, xpwb, DBL, nullptr, 16384, 56, DINC, 56);
    // ---- dt_proj (fp32 VALU, K=24) + bias + softplus -> DTb (bf16, over XIN)
    gemm_dtproj_kernel<<<dim3(12, 128), 256, 0, stream>>>(
        DBL, dt_proj_w, DTb, dt_proj_b, 16384, DINC, 24, 56, 24, DINC);
    // ---- chunked parallel selective scan (y bf16 over DTb)
    scan_phase1_kernel<<<dim3(3, NCHUNK, 4), 256, 0, stream>>>(
        DTb, Ub, DBL, A_log, HOUT, SDT);
    scan_phase2_kernel<<<192, 256, 0, stream>>>(HOUT, SDT, A_log);
    scan_phase3_kernel<<<dim3(3, NCHUNK, 4), 256, 0, stream>>>(
        DTb, Ub, DBL, Zb, A_log, D_skip, HOUT);
    // ---- out_proj (bf16 MFMA) -> d_out transposed fp32
    gemm_mfma_kernel<ushort_t, 2><<<dim3(3, 128), 256, 0, stream>>>(
        DTb, opwb, out, nullptr, 16384, CDIM, DINC, 0);
}

// Round 8
// 892.067 us; speedup vs baseline: 1.2858x; 1.0822x over previous
//
#include <hip/hip_runtime.h>
#include <math.h>

#define CDIM 384
#define SDIM 4096
#define BDIM 4
#define DINC 768
#define NST  16
#define NCHUNK 64
#define LCHUNK 64
#define PSTRIDE 6291456   // floats per conv partial [B,C,S]

typedef unsigned short ushort_t;
typedef unsigned int uint_t;
typedef __attribute__((ext_vector_type(4))) float f32x4;
typedef __attribute__((ext_vector_type(8))) short bf16x8;

__device__ __forceinline__ ushort_t f2bf(float f) {
    union { float f; uint_t u; } v; v.f = f;
    uint_t r = v.u + 0x7FFFu + ((v.u >> 16) & 1u);   // round-to-nearest-even
    return (ushort_t)(r >> 16);
}
__device__ __forceinline__ float bf2f(ushort_t u) {
    union { uint_t i; float f; } v; v.i = ((uint_t)u) << 16; return v.f;
}
__device__ __forceinline__ uint_t pk2(float a, float b) {
    return (uint_t)f2bf(a) | ((uint_t)f2bf(b) << 16);
}

// ---------------------------------------------------------------------------
// Merged weight prep: all fp32->bf16 weight conversions in one dispatch.
// ---------------------------------------------------------------------------
__device__ __forceinline__ void wconv_body(const float* __restrict__ W,
                                           ushort_t* __restrict__ Wb, int idx) {
    const float* wp = W + (size_t)idx * 27;              // idx = co*384+ci
#pragma unroll
    for (int tap = 0; tap < 27; ++tap)
        Wb[(size_t)tap * (CDIM * CDIM) + idx] = f2bf(wp[tap]);
}
__device__ __forceinline__ void cvt_body(const float* __restrict__ src,
                                         ushort_t* __restrict__ dst, int i) {
    float4 v = ((const float4*)src)[i];
    uint2 o; o.x = pk2(v.x, v.y); o.y = pk2(v.z, v.w);
    ((uint2*)dst)[i] = o;
}
__global__ __launch_bounds__(256)
void prep_weights_kernel(const float* w1, const float* w2, const float* w3,
                         const float* w4, const float* ipw, const float* opw,
                         const float* xpw,
                         ushort_t* Wb1, ushort_t* Wb2, ushort_t* w3b, ushort_t* w4b,
                         ushort_t* ipwb, ushort_t* opwb, ushort_t* xpwb) {
    const int bid = blockIdx.x, t = threadIdx.x;
    if      (bid < 576)  wconv_body(w1, Wb1, bid * 256 + t);
    else if (bid < 1152) wconv_body(w2, Wb2, (bid - 576) * 256 + t);
    else if (bid < 1296) cvt_body(w3, w3b, (bid - 1152) * 256 + t);
    else if (bid < 1440) cvt_body(w4, w4b, (bid - 1296) * 256 + t);
    else if (bid < 2016) cvt_body(ipw, ipwb, (bid - 1440) * 256 + t);
    else if (bid < 2304) cvt_body(opw, opwb, (bid - 2016) * 256 + t);
    else                 cvt_body(xpw, xpwb, (bid - 2304) * 256 + t);
}

// ---------------------------------------------------------------------------
// Pad + transpose to channels-last bf16: src[b][c][16^3] -> Xp[b][18][18][18][384]
// ---------------------------------------------------------------------------
__global__ __launch_bounds__(384)
void pad_kernel(const float* __restrict__ src, ushort_t* __restrict__ Xp) {
    const int blk = blockIdx.x;                          // b(4) d(16) h(16)
    const int b = blk >> 8, d = (blk >> 4) & 15, h = blk & 15;
    const int ci = threadIdx.x;
    const float* sp = src + (size_t)(b * CDIM + ci) * SDIM + d * 256 + h * 16;
    ushort_t* dp = Xp + ((((size_t)(b * 18 + d + 1) * 18) + (h + 1)) * 18 + 1) * CDIM + ci;
#pragma unroll
    for (int w = 0; w < 16; ++w)
        dp[(size_t)w * CDIM] = f2bf(sp[w]);
}

// ---------------------------------------------------------------------------
// Fused: v = relu((P0+P1 - m)*r) -> pad/transpose to channels-last bf16 Xp.
// ---------------------------------------------------------------------------
__global__ __launch_bounds__(384)
void pad_fuse2_kernel(const float* __restrict__ P0, const float* __restrict__ P1,
                      const float* __restrict__ stats, ushort_t* __restrict__ Xp) {
    const int blk = blockIdx.x;
    const int b = blk >> 8, d = (blk >> 4) & 15, h = blk & 15;
    const int ci = threadIdx.x;
    const size_t o = (size_t)(b * CDIM + ci) * SDIM + d * 256 + h * 16;
    const float m = stats[(b * CDIM + ci) * 2], r = stats[(b * CDIM + ci) * 2 + 1];
    ushort_t* dp = Xp + ((((size_t)(b * 18 + d + 1) * 18) + (h + 1)) * 18 + 1) * CDIM + ci;
#pragma unroll
    for (int w = 0; w < 16; ++w) {
        const float v = P0[o + w] + P1[o + w];
        dp[(size_t)w * CDIM] = f2bf(fmaxf((v - m) * r, 0.f));
    }
}

// ---------------------------------------------------------------------------
// Fused: S = relu((P0+P1-m2)*r2) + relu((C3-m3)*r3) -> pad channels-last bf16.
// ---------------------------------------------------------------------------
__global__ __launch_bounds__(384)
void pad_fuse3_kernel(const float* __restrict__ P0, const float* __restrict__ P1,
                      const float* __restrict__ st2, const float* __restrict__ C3,
                      const float* __restrict__ st3, ushort_t* __restrict__ Xp) {
    const int blk = blockIdx.x;
    const int b = blk >> 8, d = (blk >> 4) & 15, h = blk & 15;
    const int ci = threadIdx.x;
    const size_t o = (size_t)(b * CDIM + ci) * SDIM + d * 256 + h * 16;
    const float m2 = st2[(b * CDIM + ci) * 2], r2 = st2[(b * CDIM + ci) * 2 + 1];
    const float m3 = st3[(b * CDIM + ci) * 2], r3 = st3[(b * CDIM + ci) * 2 + 1];
    ushort_t* dp = Xp + ((((size_t)(b * 18 + d + 1) * 18) + (h + 1)) * 18 + 1) * CDIM + ci;
#pragma unroll
    for (int w = 0; w < 16; ++w) {
        const float x1 = fmaxf((P0[o + w] + P1[o + w] - m2) * r2, 0.f);
        const float x2 = fmaxf((C3[o + w] - m3) * r3, 0.f);
        dp[(size_t)w * CDIM] = f2bf(x1 + x2);
    }
}

// ---------------------------------------------------------------------------
// Implicit-GEMM conv via MFMA bf16 (round-5 proven 128x128 structure) with
// XCD-chunked block swizzle (T1): flat 1-D grid, wid=(lin&7)*cpx+(lin>>3),
// co innermost -> blocks sharing an Xp B-region colocate on one XCD's L2.
// MODE 0: c2 (z in {0,1} tap-split, partials -> Y01+z*PSTRIDE)
// MODE 1: c1 (z in {0,1}) + c3 1x1 fused as z==2 (W3 -> Y2)
// MODE 2: pure 1x1 (c4, W3 -> Y2)
// ---------------------------------------------------------------------------
template<int MODE>
__global__ __launch_bounds__(256)
void conv_kernel(const ushort_t* __restrict__ Xp, const ushort_t* __restrict__ Wb,
                 const ushort_t* __restrict__ W3, float* __restrict__ Y01,
                 float* __restrict__ Y2) {
    constexpr int NZ = (MODE == 0) ? 2 : (MODE == 1 ? 3 : 1);
    const int cpx = gridDim.x >> 3;
    const int lin = blockIdx.x;
    const int wid = (lin & 7) * cpx + (lin >> 3);        // XCD-chunked
    const int co0 = (wid % 3) * 128;
    const int zz  = (wid / 3) % NZ;
    const int ntid = wid / (3 * NZ);
    const int b  = ntid >> 5;
    const int d  = (ntid >> 1) & 15;
    const int h0 = (ntid & 1) * 8;
    const int t = threadIdx.x;
    const int lane = t & 63;
    const int wy = (t >> 6) >> 1, wx = (t >> 6) & 1;

    const bool is1x1 = (MODE == 2) || (MODE == 1 && zz == 2);
    const ushort_t* Wsrc; int tap0, iters, kd0, kh0, kw0; float* Y;
    if (is1x1) {
        Wsrc = W3; tap0 = 0; iters = 12; kd0 = 1; kh0 = 1; kw0 = 1; Y = Y2;
    } else {
        Wsrc = Wb; tap0 = zz ? 14 : 0; iters = (zz ? 13 : 14) * 12;
        kd0 = zz ? 1 : 0; kh0 = zz ? 1 : 0; kw0 = zz ? 2 : 0;
        Y = Y01 + (size_t)zz * PSTRIDE;
    }

    __shared__ ushort_t As[2][128 * 40];
    __shared__ ushort_t Bs[2][128 * 40];

    f32x4 acc[4][4];
#pragma unroll
    for (int i = 0; i < 4; ++i)
#pragma unroll
        for (int j = 0; j < 4; ++j) acc[i][j] = (f32x4){0.f, 0.f, 0.f, 0.f};

    const int arow = t >> 1, half = t & 1;
    const int hl = arow >> 4, w = arow & 15;
    const int wA = arow * 40 + half * 16;

    const int lm = lane & 15, lk = (lane >> 4) * 8;
    const int rA0 = (wy * 64 + lm) * 40 + lk;
    const int rB0 = (wx * 64 + lm) * 40 + lk;

    // incremental pointers: +32/iter; A +147072 on tap wrap (12 chunks);
    // B: kw wraps seamless (12*32 == CDIM); kh wrap += 5760; kd wrap += 109440.
    const ushort_t* ap = Wsrc + (size_t)tap0 * (CDIM * CDIM)
                       + (size_t)(co0 + arow) * CDIM + half * 16;
    const ushort_t* bp = Xp + ((((size_t)(b * 18 + d + kd0) * 18) + (h0 + hl + kh0)) * 18
                               + (w + kw0)) * CDIM + half * 16;
    int c12 = 0, ckw = kw0, ckh = kh0;

    uint4 ra0, ra1, rb0, rb1;

    auto loadg = [&]() {
        const uint4* pa = reinterpret_cast<const uint4*>(ap);
        ra0 = pa[0]; ra1 = pa[1];
        const uint4* pb = reinterpret_cast<const uint4*>(bp);
        rb0 = pb[0]; rb1 = pb[1];
        ap += 32; bp += 32;
        if (++c12 == 12) {                               // tap wrap
            c12 = 0;
            ap += CDIM * CDIM - 384;
            if (++ckw == 3) {
                ckw = 0;
                if (++ckh == 3) { ckh = 0; bp += 109440; }
                else bp += 5760;
            }
        }
    };
    auto lwrite = [&](int buf) {
        *reinterpret_cast<uint4*>(&As[buf][wA])     = ra0;
        *reinterpret_cast<uint4*>(&As[buf][wA + 8]) = ra1;
        *reinterpret_cast<uint4*>(&Bs[buf][wA])     = rb0;
        *reinterpret_cast<uint4*>(&Bs[buf][wA + 8]) = rb1;
    };

    loadg();
    lwrite(0);
    __syncthreads();

    int buf = 0;
    for (int idx = 0; idx < iters; ++idx) {
        const bool more = (idx + 1) < iters;
        if (more) loadg();                               // issue early
        bf16x8 af[4], bfr[4];
#pragma unroll
        for (int mi = 0; mi < 4; ++mi)
            af[mi] = *reinterpret_cast<const bf16x8*>(&As[buf][rA0 + mi * 640]);
#pragma unroll
        for (int ni = 0; ni < 4; ++ni)
            bfr[ni] = *reinterpret_cast<const bf16x8*>(&Bs[buf][rB0 + ni * 640]);
#pragma unroll
        for (int mi = 0; mi < 4; ++mi)
#pragma unroll
            for (int ni = 0; ni < 4; ++ni)
                acc[mi][ni] = __builtin_amdgcn_mfma_f32_16x16x32_bf16(
                    af[mi], bfr[ni], acc[mi][ni], 0, 0, 0);
        if (more) lwrite(buf ^ 1);                       // write late
        __syncthreads();
        buf ^= 1;
    }

    // epilogue: C/D layout col(lane&15)=sp, row=(lane>>4)*4+j=co
    const int coB = co0 + wy * 64 + (lane >> 4) * 4;
    const int nB  = wx * 64 + lm;
#pragma unroll
    for (int mi = 0; mi < 4; ++mi) {
#pragma unroll
        for (int ni = 0; ni < 4; ++ni) {
            const int nl = nB + ni * 16;
            const int s = d * 256 + (h0 + (nl >> 4)) * 16 + (nl & 15);
            float* yp = Y + ((size_t)b * CDIM + (coB + mi * 16)) * SDIM + s;
#pragma unroll
            for (int j = 0; j < 4; ++j)
                yp[(size_t)j * SDIM] = acc[mi][ni][j];
        }
    }
}

// ---------------------------------------------------------------------------
// bf16 MFMA GEMM, NT: C[M,N] = A[M,K] x B[N,K]^T, flat grid + XCD swizzle.
// nx = number of 128-wide n-tiles. EPI 0: fp32 store (ldc);
// 1: xz split -> bf16 C/C2 (N=1536); 2: transposed fp32 float4 store C[b][n][l].
// ---------------------------------------------------------------------------
template<int EPI>
__global__ __launch_bounds__(256)
void gemm_mfma_kernel(const ushort_t* __restrict__ A, const ushort_t* __restrict__ Bw,
                      void* __restrict__ Cv, void* __restrict__ C2v,
                      int M, int N, int K, int ldc, int nx) {
    const int cpx = gridDim.x >> 3;
    const int lin = blockIdx.x;
    const int wid = (lin & 7) * cpx + (lin >> 3);
    const int n0 = (wid % nx) * 128;
    const int m0 = (wid / nx) * 128;
    const int t = threadIdx.x;
    const int lane = t & 63;
    const int wy = (t >> 6) >> 1, wx = (t >> 6) & 1;

    __shared__ ushort_t As[2][128 * 40];
    __shared__ ushort_t Bs[2][128 * 40];

    f32x4 acc[4][4];
#pragma unroll
    for (int i = 0; i < 4; ++i)
#pragma unroll
        for (int j = 0; j < 4; ++j) acc[i][j] = (f32x4){0.f, 0.f, 0.f, 0.f};

    const int arow = t >> 1, half = t & 1;
    const int wA = arow * 40 + half * 16;
    const int lm = lane & 15, lk = (lane >> 4) * 8;
    const int rA0 = (wy * 64 + lm) * 40 + lk;
    const int rB0 = (wx * 64 + lm) * 40 + lk;

    uint4 ra0, ra1, rb0, rb1;

    auto loadg = [&](int kk) {
        const int kb = kk * 32 + half * 16;
        const uint4* pa = reinterpret_cast<const uint4*>(
            A + (size_t)(m0 + arow) * K + kb);
        ra0 = pa[0]; ra1 = pa[1];
        if (n0 + arow < N) {
            const uint4* pb = reinterpret_cast<const uint4*>(
                Bw + (size_t)(n0 + arow) * K + kb);
            rb0 = pb[0]; rb1 = pb[1];
        } else {
            rb0 = make_uint4(0, 0, 0, 0); rb1 = rb0;
        }
    };
    auto lwrite = [&](int buf) {
        *reinterpret_cast<uint4*>(&As[buf][wA])     = ra0;
        *reinterpret_cast<uint4*>(&As[buf][wA + 8]) = ra1;
        *reinterpret_cast<uint4*>(&Bs[buf][wA])     = rb0;
        *reinterpret_cast<uint4*>(&Bs[buf][wA + 8]) = rb1;
    };

    const int KI = K >> 5;
    loadg(0);
    lwrite(0);
    __syncthreads();

    int buf = 0;
    for (int kk = 0; kk < KI; ++kk) {
        const bool more = (kk + 1) < KI;
        if (more) loadg(kk + 1);
        bf16x8 af[4], bfr[4];
#pragma unroll
        for (int mi = 0; mi < 4; ++mi)
            af[mi] = *reinterpret_cast<const bf16x8*>(&As[buf][rA0 + mi * 640]);
#pragma unroll
        for (int ni = 0; ni < 4; ++ni)
            bfr[ni] = *reinterpret_cast<const bf16x8*>(&Bs[buf][rB0 + ni * 640]);
#pragma unroll
        for (int mi = 0; mi < 4; ++mi)
#pragma unroll
            for (int ni = 0; ni < 4; ++ni)
                acc[mi][ni] = __builtin_amdgcn_mfma_f32_16x16x32_bf16(
                    af[mi], bfr[ni], acc[mi][ni], 0, 0, 0);
        if (more) lwrite(buf ^ 1);
        __syncthreads();
        buf ^= 1;
    }

    const int mB = m0 + wy * 64 + (lane >> 4) * 4;
    const int nB = n0 + wx * 64 + lm;
#pragma unroll
    for (int mi = 0; mi < 4; ++mi) {
#pragma unroll
        for (int ni = 0; ni < 4; ++ni) {
            const int n = nB + ni * 16;
            if (EPI == 2) {                              // transposed float4
                const int mrow = mB + mi * 16;
                const int bb = mrow >> 12, l = mrow & 4095;
                float4 st = {acc[mi][ni][0], acc[mi][ni][1],
                             acc[mi][ni][2], acc[mi][ni][3]};
                *reinterpret_cast<float4*>(
                    (float*)Cv + ((size_t)(bb * CDIM + n)) * SDIM + l) = st;
            } else {
#pragma unroll
                for (int j = 0; j < 4; ++j) {
                    const int m = mB + mi * 16 + j;
                    const float v = acc[mi][ni][j];
                    if (EPI == 0) {
                        if (n < N) ((float*)Cv)[(size_t)m * ldc + n] = v;
                    } else {                             // xz split, bf16 out
                        if (n < DINC) ((ushort_t*)Cv)[(size_t)m * DINC + n] = f2bf(v);
                        else ((ushort_t*)C2v)[(size_t)m * DINC + (n - DINC)] = f2bf(v);
                    }
                }
            }
        }
    }
}

// ---------------------------------------------------------------------------
// Reduction helper for instance-norm stats.
// ---------------------------------------------------------------------------
__device__ __forceinline__ void stats_reduce(float s, float ss, float* out) {
#pragma unroll
    for (int off = 32; off > 0; off >>= 1) {
        s += __shfl_down(s, off);
        ss += __shfl_down(ss, off);
    }
    __shared__ float rs[4], rss[4];
    const int wid = threadIdx.x >> 6;
    if ((threadIdx.x & 63) == 0) { rs[wid] = s; rss[wid] = ss; }
    __syncthreads();
    if (threadIdx.x == 0) {
        float S = rs[0] + rs[1] + rs[2] + rs[3];
        float SS = rss[0] + rss[1] + rss[2] + rss[3];
        float m = S * (1.f / SDIM);
        float var = SS * (1.f / SDIM) - m * m;
        out[0] = m;
        out[1] = rsqrtf(var + 1e-5f);
    }
}

// ---------------------------------------------------------------------------
// Combo stats: bc<1536 -> stats of (P0+P1) into SA; bc>=1536 -> stats of X3
// into SB (only when grid > 1536).
// ---------------------------------------------------------------------------
__global__ __launch_bounds__(256)
void inorm_stats_combo_kernel(const float* __restrict__ P0, const float* __restrict__ P1,
                              float* __restrict__ SA, const float* __restrict__ X3,
                              float* __restrict__ SB) {
    const int bid = blockIdx.x;
    float s = 0.f, ss = 0.f;
    if (bid < 1536) {
        const float* p0 = P0 + (size_t)bid * SDIM;
        const float* p1 = P1 + (size_t)bid * SDIM;
        for (int i = threadIdx.x * 4; i < SDIM; i += 1024) {
            float4 a = *(const float4*)(p0 + i);
            float4 c = *(const float4*)(p1 + i);
            const float vx = a.x + c.x, vy = a.y + c.y, vz = a.z + c.z, vw = a.w + c.w;
            s += vx + vy + vz + vw;
            ss += vx * vx + vy * vy + vz * vz + vw * vw;
        }
        stats_reduce(s, ss, SA + bid * 2);
    } else {
        const int bc = bid - 1536;
        const float* xp = X3 + (size_t)bc * SDIM;
        for (int i = threadIdx.x * 4; i < SDIM; i += 1024) {
            float4 v = *(const float4*)(xp + i);
            s += v.x + v.y + v.z + v.w;
            ss += v.x * v.x + v.y * v.y + v.z * v.z + v.w * v.w;
        }
        stats_reduce(s, ss, SB + bc * 2);
    }
}

// ---------------------------------------------------------------------------
// InstanceNorm stats, single input.
// ---------------------------------------------------------------------------
__global__ __launch_bounds__(256)
void inorm_stats_kernel(const float* __restrict__ X, float* __restrict__ stats) {
    const int bc = blockIdx.x;
    const float* xp = X + (size_t)bc * SDIM;
    float s = 0.f, ss = 0.f;
    for (int i = threadIdx.x * 4; i < SDIM; i += 1024) {
        float4 v = *(const float4*)(xp + i);
        s += v.x + v.y + v.z + v.w;
        ss += v.x * v.x + v.y * v.y + v.z * v.z + v.w * v.w;
    }
    stats_reduce(s, ss, stats + bc * 2);
}

// ---------------------------------------------------------------------------
// Fused LayerNorm: xg = relu((C4-m)*r) + x inline, LN over C, transpose
// -> tn [b][l][c] bf16.
// ---------------------------------------------------------------------------
__global__ __launch_bounds__(256)
void layernorm_kernel(const float* __restrict__ C4, const float* __restrict__ stats,
                      const float* __restrict__ X, const float* __restrict__ gam,
                      const float* __restrict__ bet, ushort_t* __restrict__ Tn) {
    const int token = blockIdx.x * 4 + (threadIdx.x >> 6);
    const int lane = threadIdx.x & 63;
    const int b = token >> 12, l = token & 4095;
    const size_t base = (size_t)b * CDIM * SDIM + l;
    float v[6];
    float s = 0.f, ss = 0.f;
#pragma unroll
    for (int i = 0; i < 6; ++i) {
        const int c = lane + i * 64;
        const size_t o = base + (size_t)c * SDIM;
        const float m = stats[(b * CDIM + c) * 2], r = stats[(b * CDIM + c) * 2 + 1];
        v[i] = fmaxf((C4[o] - m) * r, 0.f) + X[o];
        s += v[i]; ss += v[i] * v[i];
    }
#pragma unroll
    for (int off = 32; off > 0; off >>= 1) {
        s += __shfl_down(s, off);
        ss += __shfl_down(ss, off);
    }
    s = __shfl(s, 0); ss = __shfl(ss, 0);
    const float m = s * (1.f / CDIM);
    const float r = rsqrtf(ss * (1.f / CDIM) - m * m + 1e-5f);
    ushort_t* tp = Tn + (size_t)token * CDIM;
#pragma unroll
    for (int i = 0; i < 6; ++i) {
        const int c = lane + i * 64;
        tp[c] = f2bf((v[i] - m) * r * gam[c] + bet[c]);
    }
}

// ---------------------------------------------------------------------------
// Tiled fp32 GEMM for dt_proj (K=24), NT, bias+softplus, bf16 store.
// ---------------------------------------------------------------------------
__global__ __launch_bounds__(256)
void gemm_dtproj_kernel(const float* __restrict__ A, const float* __restrict__ B,
                        ushort_t* __restrict__ C, const float* __restrict__ bias,
                        int M, int N, int K, int lda, int ldb, int ldc) {
    __shared__ __align__(16) float As[16][132];
    __shared__ __align__(16) float Bs[16][68];
    const int t = threadIdx.x;
    const int m0 = blockIdx.y * 128;
    const int n0 = blockIdx.x * 64;

    float acc[8][4];
#pragma unroll
    for (int i = 0; i < 8; ++i)
#pragma unroll
        for (int j = 0; j < 4; ++j) acc[i][j] = 0.f;

    const int mr = (t & 15) * 8;
    const int nr = (t >> 4) * 4;

    for (int k0 = 0; k0 < K; k0 += 16) {
#pragma unroll
        for (int idx = 0; idx < 8; ++idx) {
            const int e = idx * 256 + t;
            const int k = e & 15, m = e >> 4;
            float v = 0.f;
            if (k0 + k < K) v = A[(size_t)(m0 + m) * lda + (k0 + k)];
            As[k][m] = v;
        }
#pragma unroll
        for (int idx = 0; idx < 4; ++idx) {
            const int e = idx * 256 + t;
            const int k = e & 15, n = e >> 4;
            float v = 0.f;
            if ((n0 + n) < N && (k0 + k) < K) v = B[(size_t)(n0 + n) * ldb + (k0 + k)];
            Bs[k][n] = v;
        }
        __syncthreads();
#pragma unroll
        for (int k = 0; k < 16; ++k) {
            float4 a0 = *(const float4*)&As[k][mr];
            float4 a1 = *(const float4*)&As[k][mr + 4];
            float4 b0 = *(const float4*)&Bs[k][nr];
            const float av[8] = {a0.x, a0.y, a0.z, a0.w, a1.x, a1.y, a1.z, a1.w};
            const float bv[4] = {b0.x, b0.y, b0.z, b0.w};
#pragma unroll
            for (int i = 0; i < 8; ++i)
#pragma unroll
                for (int j = 0; j < 4; ++j)
                    acc[i][j] = fmaf(av[i], bv[j], acc[i][j]);
        }
        __syncthreads();
    }

#pragma unroll
    for (int i = 0; i < 8; ++i) {
        const int m = m0 + mr + i;
#pragma unroll
        for (int j = 0; j < 4; ++j) {
            const int n = n0 + nr + j;
            if (n >= N) continue;
            float v = acc[i][j] + bias[n];
            v = (v > 20.f) ? v : log1pf(__expf(v));
            C[(size_t)m * ldc + n] = f2bf(v);
        }
    }
}

// ---------------------------------------------------------------------------
// Causal depthwise conv1d (K=4) + bias + SiLU, bf16 in/out. 4 tokens/thread
// (reuses 7 loaded rows for 4 outputs -> ~2.3x less read traffic).
// ---------------------------------------------------------------------------
__global__ __launch_bounds__(256)
void dwconv_silu_kernel(const ushort_t* __restrict__ Xin, const float* __restrict__ W,
                        const float* __restrict__ bias, ushort_t* __restrict__ U) {
    const int dch = blockIdx.x * 256 + threadIdx.x;
    const int l0 = blockIdx.y * 4, b = blockIdx.z;
    const float4 w4 = ((const float4*)W)[dch];
    const float wk[4] = {w4.x, w4.y, w4.z, w4.w};
    const float bs = bias[dch];
    const size_t base = ((size_t)b * 4096 + l0) * DINC + dch;
    float r[7];
#pragma unroll
    for (int k = 0; k < 7; ++k) {
        const int ll = l0 - 3 + k;
        r[k] = (ll >= 0) ? bf2f(Xin[base + (size_t)(k - 3) * DINC]) : 0.f;
    }
#pragma unroll
    for (int j = 0; j < 4; ++j) {
        float acc = bs;
#pragma unroll
        for (int k = 0; k < 4; ++k) acc = fmaf(r[j + k], wk[k], acc);
        U[base + (size_t)j * DINC] = f2bf(acc / (1.f + __expf(-acc)));
    }
}

// ---------------------------------------------------------------------------
// Chunked parallel selective scan (3 phases). dt/u/z/y bf16; B,C fp32.
// ---------------------------------------------------------------------------
__global__ __launch_bounds__(256)
void scan_phase1_kernel(const ushort_t* __restrict__ DT, const ushort_t* __restrict__ U,
                        const float* __restrict__ DBL, const float* __restrict__ A_log,
                        float* __restrict__ HOUT, float* __restrict__ SDT) {
    const int b = blockIdx.z, chunk = blockIdx.y;
    const int dch = blockIdx.x * 256 + threadIdx.x;
    float Arow[16];
#pragma unroll
    for (int n = 0; n < NST; ++n) Arow[n] = -__expf(A_log[dch * NST + n]);

    __shared__ float bcs[LCHUNK][16];
    const size_t tokbase = (size_t)b * 4096 + chunk * LCHUNK;
#pragma unroll
    for (int idx = 0; idx < 4; ++idx) {
        const int e = idx * 256 + threadIdx.x;
        bcs[e >> 4][e & 15] = DBL[(tokbase + (e >> 4)) * 56 + 24 + (e & 15)];
    }
    __syncthreads();

    size_t off = tokbase * DINC + dch;
    float h[16];
#pragma unroll
    for (int n = 0; n < NST; ++n) h[n] = 0.f;
    float sdt = 0.f;
    float cdt = bf2f(DT[off]), cu = bf2f(U[off]);
    for (int t = 0; t < LCHUNK; ++t) {
        float ndt = 0.f, nu = 0.f;
        if (t < LCHUNK - 1) { ndt = bf2f(DT[off + DINC]); nu = bf2f(U[off + DINC]); }
        sdt += cdt;
        const float du = cdt * cu;
#pragma unroll
        for (int n = 0; n < NST; ++n)
            h[n] = __expf(cdt * Arow[n]) * h[n] + du * bcs[t][n];
        off += DINC;
        cdt = ndt; cu = nu;
    }
    float* hp = HOUT + (((size_t)(b * DINC + dch) * NCHUNK + chunk) << 4);
#pragma unroll
    for (int n = 0; n < NST; ++n) hp[n] = h[n];
    SDT[(size_t)(b * DINC + dch) * NCHUNK + chunk] = sdt;
}

__global__ __launch_bounds__(256)
void scan_phase2_kernel(float* __restrict__ HOUT, const float* __restrict__ SDT,
                        const float* __restrict__ A_log) {
    const int t = blockIdx.x * 256 + threadIdx.x;        // 49152
    const int b = t / (DINC * NST);
    const int rem = t - b * (DINC * NST);
    const int d = rem >> 4, n = rem & 15;
    const float An = -__expf(A_log[d * NST + n]);
    float* hp = HOUT + (((size_t)(b * DINC + d) * NCHUNK) << 4) + n;
    const float* sp = SDT + (size_t)(b * DINC + d) * NCHUNK;
    float H = 0.f;
    for (int c = 0; c < NCHUNK; ++c) {
        const float tmp = hp[c * 16];
        const float dA = __expf(An * sp[c]);
        hp[c * 16] = H;
        H = dA * H + tmp;
    }
}

__global__ __launch_bounds__(256)
void scan_phase3_kernel(ushort_t* __restrict__ DT, const ushort_t* __restrict__ U,
                        const float* __restrict__ DBL, const ushort_t* __restrict__ Z,
                        const float* __restrict__ A_log, const float* __restrict__ D_skip,
                        const float* __restrict__ HOUT) {
    const int b = blockIdx.z, chunk = blockIdx.y;
    const int dch = blockIdx.x * 256 + threadIdx.x;
    float Arow[16];
#pragma unroll
    for (int n = 0; n < NST; ++n) Arow[n] = -__expf(A_log[dch * NST + n]);
    const float Dsk = D_skip[dch];

    __shared__ float bcs[LCHUNK][32];
    const size_t tokbase = (size_t)b * 4096 + chunk * LCHUNK;
#pragma unroll
    for (int idx = 0; idx < 8; ++idx) {
        const int e = idx * 256 + threadIdx.x;
        bcs[e >> 5][e & 31] = DBL[(tokbase + (e >> 5)) * 56 + 24 + (e & 31)];
    }
    __syncthreads();

    float h[16];
    const float* hp = HOUT + (((size_t)(b * DINC + dch) * NCHUNK + chunk) << 4);
#pragma unroll
    for (int n = 0; n < NST; ++n) h[n] = hp[n];

    size_t off = tokbase * DINC + dch;
    float cdt = bf2f(DT[off]), cu = bf2f(U[off]), cz = bf2f(Z[off]);
    for (int t = 0; t < LCHUNK; ++t) {
        float ndt = 0.f, nu = 0.f, nz = 0.f;
        if (t < LCHUNK - 1) {
            ndt = bf2f(DT[off + DINC]); nu = bf2f(U[off + DINC]); nz = bf2f(Z[off + DINC]);
        }
        const float du = cdt * cu;
        float y = 0.f;
#pragma unroll
        for (int n = 0; n < NST; ++n) {
            h[n] = __expf(cdt * Arow[n]) * h[n] + du * bcs[t][n];
            y = fmaf(h[n], bcs[t][16 + n], y);
        }
        y += cu * Dsk;
        const float sz = cz / (1.f + __expf(-cz));
        DT[off] = f2bf(y * sz);
        off += DINC;
        cdt = ndt; cu = nu; cz = nz;
    }
}

// ---------------------------------------------------------------------------
extern "C" void kernel_launch(void* const* d_in, const int* in_sizes, int n_in,
                              void* d_out, int out_size, void* d_ws, size_t ws_size,
                              hipStream_t stream) {
    (void)in_sizes; (void)n_in; (void)out_size; (void)ws_size;
    const float* x         = (const float*)d_in[0];
    const float* w1        = (const float*)d_in[1];
    const float* w2        = (const float*)d_in[3];
    const float* w3        = (const float*)d_in[5];
    const float* w4        = (const float*)d_in[7];
    const float* ln_g      = (const float*)d_in[9];
    const float* ln_b      = (const float*)d_in[10];
    const float* in_proj_w = (const float*)d_in[11];
    const float* conv1d_w  = (const float*)d_in[12];
    const float* conv1d_b  = (const float*)d_in[13];
    const float* x_proj_w  = (const float*)d_in[14];
    const float* dt_proj_w = (const float*)d_in[15];
    const float* dt_proj_b = (const float*)d_in[16];
    const float* A_log     = (const float*)d_in[17];
    const float* D_skip    = (const float*)d_in[18];
    const float* out_proj_w= (const float*)d_in[19];
    float* out = (float*)d_out;

    // Workspace regions (floats): R0..R4. Lifetimes disjoint where aliased.
    float* ws = (float*)d_ws;
    float* R0 = ws;                    //  6291456
    float* R1 = ws + 6291456;          //  6291456
    float* R2 = ws + 12582912;         // 12582912
    float* R3 = ws + 25165824;         // 12582912
    float* R4 = ws + 37748736;         // 12582912

    // GSC-phase aliases
    float*    P0    = R0;                            // conv partial z=0
    float*    P1    = R1;                            // conv partial z=1 (P0+PSTRIDE)
    ushort_t* Wb1   = (ushort_t*)R2;                 // 3981312 bf16 (2097152 fl)
    ushort_t* Xp    = (ushort_t*)(R2 + 2097152);     // 8957952 bf16 (4478976 fl)
    ushort_t* w3b   = (ushort_t*)(R2 + 6576128);     // 147456 bf16
    ushort_t* w4b   = (ushort_t*)(R2 + 6649856);     // 147456 bf16
    ushort_t* Wb2   = (ushort_t*)(R2 + 6723584);     // 3981312 bf16 -> ends 8714240
    float*    SA    = R4;                            // stats A (3072 fl)
    float*    SB    = R4 + 4096;                     // stats B (3072 fl)
    // weights in the permanently-free R4 tail (beyond Ub's 6291456 fl)
    ushort_t* ipwb  = (ushort_t*)(R4 + 6291456);     // 589824 bf16 (294912 fl)
    ushort_t* opwb  = (ushort_t*)(R4 + 6586368);     // 294912 bf16 (147456 fl)
    ushort_t* xpwb  = (ushort_t*)(R4 + 6733824);     // 43008 bf16
    // Mamba-phase aliases
    ushort_t* tnb   = (ushort_t*)R0;                 // 16384*384 bf16 (3145728 fl)
    float*    DBL   = R0 + 3145728;                  // 16384*56 fp32
    float*    HOUT  = R1;                            // 3145728 fl
    float*    SDT   = R1 + 3145728;                  // 196608 fl
    ushort_t* XIN   = (ushort_t*)R2;                 // 16384*768 bf16 (over conv bufs)
    ushort_t* Zb    = (ushort_t*)R3;                 // 16384*768 bf16
    ushort_t* Ub    = (ushort_t*)R4;                 // 16384*768 bf16 (over SA/SB, later)
    ushort_t* DTb   = (ushort_t*)R2;                 // dt/y bf16 over XIN

    const size_t XP_BYTES = (size_t)4 * 18 * 18 * 18 * CDIM * 2;

    // ---- upfront: zero pad borders, convert all weights, pad x ----
    hipMemsetAsync(Xp, 0, XP_BYTES, stream);
    prep_weights_kernel<<<2346, 256, 0, stream>>>(
        w1, w2, w3, w4, in_proj_w, out_proj_w, x_proj_w,
        Wb1, Wb2, w3b, w4b, ipwb, opwb, xpwb);
    pad_kernel<<<1024, 384, 0, stream>>>(x, Xp);
    // ---- c1 (3x3x3 z-split) + c3 (1x1) fused in one dispatch ----
    conv_kernel<1><<<1152, 256, 0, stream>>>(Xp, Wb1, w3b, P0, R3);
    inorm_stats_combo_kernel<<<3072, 256, 0, stream>>>(P0, P1, SA, R3, SB); // c1->SA, c3->SB
    pad_fuse2_kernel<<<1024, 384, 0, stream>>>(P0, P1, SA, Xp);             // x1a
    // ---- c2 ----
    conv_kernel<0><<<768, 256, 0, stream>>>(Xp, Wb2, nullptr, P0, nullptr);
    inorm_stats_combo_kernel<<<1536, 256, 0, stream>>>(P0, P1, SA, nullptr, nullptr);
    pad_fuse3_kernel<<<1024, 384, 0, stream>>>(P0, P1, SA, R3, SB, Xp);     // S
    // ---- c4 (1x1) ----
    conv_kernel<2><<<384, 256, 0, stream>>>(Xp, nullptr, w4b, nullptr, R3);
    inorm_stats_kernel<<<1536, 256, 0, stream>>>(R3, SA);
    // ---- fused relu(IN(c4)) + x residual + LayerNorm -> tn bf16 [b][l][c]
    layernorm_kernel<<<4096, 256, 0, stream>>>(R3, SA, x, ln_g, ln_b, tnb);
    // ---- in_proj (bf16 MFMA, swizzled): tn x W^T -> split XIN | Zb (bf16)
    gemm_mfma_kernel<1><<<1536, 256, 0, stream>>>(
        tnb, ipwb, XIN, Zb, 16384, 1536, CDIM, 0, 12);
    // ---- causal depthwise conv + SiLU -> Ub (bf16)
    dwconv_silu_kernel<<<dim3(3, 1024, 4), 256, 0, stream>>>(XIN, conv1d_w, conv1d_b, Ub);
    // ---- x_proj (bf16 MFMA, N=56 masked): u x W^T -> DBL (fp32)
    gemm_mfma_kernel<0><<<128, 256, 0, stream>>>(
        Ub, xpwb, DBL, nullptr, 16384, 56, DINC, 56, 1);
    // ---- dt_proj (fp32 VALU, K=24) + bias + softplus -> DTb (bf16, over XIN)
    gemm_dtproj_kernel<<<dim3(12, 128), 256, 0, stream>>>(
        DBL, dt_proj_w, DTb, dt_proj_b, 16384, DINC, 24, 56, 24, DINC);
    // ---- chunked parallel selective scan (y bf16 over DTb)
    scan_phase1_kernel<<<dim3(3, NCHUNK, 4), 256, 0, stream>>>(
        DTb, Ub, DBL, A_log, HOUT, SDT);
    scan_phase2_kernel<<<192, 256, 0, stream>>>(HOUT, SDT, A_log);
    scan_phase3_kernel<<<dim3(3, NCHUNK, 4), 256, 0, stream>>>(
        DTb, Ub, DBL, Zb, A_log, D_skip, HOUT);
    // ---- out_proj (bf16 MFMA, swizzled) -> d_out transposed fp32
    gemm_mfma_kernel<2><<<384, 256, 0, stream>>>(
        DTb, opwb, out, nullptr, 16384, CDIM, DINC, 0, 3);
}

// Round 9
// 810.166 us; speedup vs baseline: 1.4157x; 1.1011x over previous
//
#include <hip/hip_runtime.h>
#include <math.h>

#define CDIM 384
#define SDIM 4096
#define BDIM 4
#define DINC 768
#define NST  16
#define NCHUNK 64
#define LCHUNK 64
#define PSTRIDE 6291456   // floats per conv partial [B,C,S]

typedef unsigned short ushort_t;
typedef unsigned int uint_t;
typedef __attribute__((ext_vector_type(4))) float f32x4;
typedef __attribute__((ext_vector_type(8))) short bf16x8;

__device__ __forceinline__ ushort_t f2bf(float f) {
    union { float f; uint_t u; } v; v.f = f;
    uint_t r = v.u + 0x7FFFu + ((v.u >> 16) & 1u);   // round-to-nearest-even
    return (ushort_t)(r >> 16);
}
__device__ __forceinline__ float bf2f(ushort_t u) {
    union { uint_t i; float f; } v; v.i = ((uint_t)u) << 16; return v.f;
}
__device__ __forceinline__ uint_t pk2(float a, float b) {
    return (uint_t)f2bf(a) | ((uint_t)f2bf(b) << 16);
}
// async global->LDS, 16B per lane, dest = wave-uniform base + lane*16
__device__ __forceinline__ void gl16(const ushort_t* g, ushort_t* l) {
    __builtin_amdgcn_global_load_lds(
        (const __attribute__((address_space(1))) void*)(g),
        (__attribute__((address_space(3))) void*)(l), 16, 0, 0);
}

// ---------------------------------------------------------------------------
// Merged weight prep: all fp32->bf16 weight conversions in one dispatch.
// ---------------------------------------------------------------------------
__device__ __forceinline__ void wconv_body(const float* __restrict__ W,
                                           ushort_t* __restrict__ Wb, int idx) {
    const float* wp = W + (size_t)idx * 27;              // idx = co*384+ci
#pragma unroll
    for (int tap = 0; tap < 27; ++tap)
        Wb[(size_t)tap * (CDIM * CDIM) + idx] = f2bf(wp[tap]);
}
__device__ __forceinline__ void cvt_body(const float* __restrict__ src,
                                         ushort_t* __restrict__ dst, int i) {
    float4 v = ((const float4*)src)[i];
    uint2 o; o.x = pk2(v.x, v.y); o.y = pk2(v.z, v.w);
    ((uint2*)dst)[i] = o;
}
__global__ __launch_bounds__(256)
void prep_weights_kernel(const float* w1, const float* w2, const float* w3,
                         const float* w4, const float* ipw, const float* opw,
                         const float* xpw,
                         ushort_t* Wb1, ushort_t* Wb2, ushort_t* w3b, ushort_t* w4b,
                         ushort_t* ipwb, ushort_t* opwb, ushort_t* xpwb) {
    const int bid = blockIdx.x, t = threadIdx.x;
    if      (bid < 576)  wconv_body(w1, Wb1, bid * 256 + t);
    else if (bid < 1152) wconv_body(w2, Wb2, (bid - 576) * 256 + t);
    else if (bid < 1296) cvt_body(w3, w3b, (bid - 1152) * 256 + t);
    else if (bid < 1440) cvt_body(w4, w4b, (bid - 1296) * 256 + t);
    else if (bid < 2016) cvt_body(ipw, ipwb, (bid - 1440) * 256 + t);
    else if (bid < 2304) cvt_body(opw, opwb, (bid - 2016) * 256 + t);
    else                 cvt_body(xpw, xpwb, (bid - 2304) * 256 + t);
}

// ---------------------------------------------------------------------------
// Pad + transpose to channels-last bf16: src[b][c][16^3] -> Xp[b][18][18][18][384]
// ---------------------------------------------------------------------------
__global__ __launch_bounds__(384)
void pad_kernel(const float* __restrict__ src, ushort_t* __restrict__ Xp) {
    const int blk = blockIdx.x;                          // b(4) d(16) h(16)
    const int b = blk >> 8, d = (blk >> 4) & 15, h = blk & 15;
    const int ci = threadIdx.x;
    const float* sp = src + (size_t)(b * CDIM + ci) * SDIM + d * 256 + h * 16;
    ushort_t* dp = Xp + ((((size_t)(b * 18 + d + 1) * 18) + (h + 1)) * 18 + 1) * CDIM + ci;
#pragma unroll
    for (int w = 0; w < 16; ++w)
        dp[(size_t)w * CDIM] = f2bf(sp[w]);
}

// ---------------------------------------------------------------------------
// Fused: v = relu((P0+P1 - m)*r) -> pad/transpose to channels-last bf16 Xp.
// ---------------------------------------------------------------------------
__global__ __launch_bounds__(384)
void pad_fuse2_kernel(const float* __restrict__ P0, const float* __restrict__ P1,
                      const float* __restrict__ stats, ushort_t* __restrict__ Xp) {
    const int blk = blockIdx.x;
    const int b = blk >> 8, d = (blk >> 4) & 15, h = blk & 15;
    const int ci = threadIdx.x;
    const size_t o = (size_t)(b * CDIM + ci) * SDIM + d * 256 + h * 16;
    const float m = stats[(b * CDIM + ci) * 2], r = stats[(b * CDIM + ci) * 2 + 1];
    ushort_t* dp = Xp + ((((size_t)(b * 18 + d + 1) * 18) + (h + 1)) * 18 + 1) * CDIM + ci;
#pragma unroll
    for (int w = 0; w < 16; ++w) {
        const float v = P0[o + w] + P1[o + w];
        dp[(size_t)w * CDIM] = f2bf(fmaxf((v - m) * r, 0.f));
    }
}

// ---------------------------------------------------------------------------
// Fused: S = relu((P0+P1-m2)*r2) + relu((C3-m3)*r3) -> pad channels-last bf16.
// ---------------------------------------------------------------------------
__global__ __launch_bounds__(384)
void pad_fuse3_kernel(const float* __restrict__ P0, const float* __restrict__ P1,
                      const float* __restrict__ st2, const float* __restrict__ C3,
                      const float* __restrict__ st3, ushort_t* __restrict__ Xp) {
    const int blk = blockIdx.x;
    const int b = blk >> 8, d = (blk >> 4) & 15, h = blk & 15;
    const int ci = threadIdx.x;
    const size_t o = (size_t)(b * CDIM + ci) * SDIM + d * 256 + h * 16;
    const float m2 = st2[(b * CDIM + ci) * 2], r2 = st2[(b * CDIM + ci) * 2 + 1];
    const float m3 = st3[(b * CDIM + ci) * 2], r3 = st3[(b * CDIM + ci) * 2 + 1];
    ushort_t* dp = Xp + ((((size_t)(b * 18 + d + 1) * 18) + (h + 1)) * 18 + 1) * CDIM + ci;
#pragma unroll
    for (int w = 0; w < 16; ++w) {
        const float x1 = fmaxf((P0[o + w] + P1[o + w] - m2) * r2, 0.f);
        const float x2 = fmaxf((C3[o + w] - m3) * r3, 0.f);
        dp[(size_t)w * CDIM] = f2bf(x1 + x2);
    }
}

// ---------------------------------------------------------------------------
// Implicit-GEMM conv via MFMA bf16, global_load_lds staging (m97 structure):
// single 16KB LDS buffer, per iter {issue 4 gl_lds -> barrier -> ds_read+MFMA
// -> barrier}. LDS layout linear [128][32] bf16 with XOR-swizzled CONTENT:
// lane fetches global granule c = g ^ ((r>>1)&3) so b128 fragment reads (same
// involution) hit all 8 bank groups (optimal 2-way). Direct block mapping
// (nt innermost), no XCD swizzle.
// MODE 0: c2 (z in {0,1} tap-split, partials -> Y01+z*PSTRIDE)
// MODE 1: c1 (z in {0,1}) + c3 1x1 fused as z==2 (W3 -> Y2)
// MODE 2: pure 1x1 (c4, W3 -> Y2)
// ---------------------------------------------------------------------------
template<int MODE>
__global__ __launch_bounds__(256)
void conv_kernel(const ushort_t* __restrict__ Xp, const ushort_t* __restrict__ Wb,
                 const ushort_t* __restrict__ W3, float* __restrict__ Y01,
                 float* __restrict__ Y2) {
    const int wid = blockIdx.x;
    const int ntid = wid & 127;                          // nt innermost (round-5 order)
    const int rest = wid >> 7;
    const int co0 = (rest % 3) * 128;
    const int zz  = rest / 3;
    const int b  = ntid >> 5;
    const int d  = (ntid >> 1) & 15;
    const int h0 = (ntid & 1) * 8;
    const int t = threadIdx.x;
    const int lane = t & 63;
    const int wv = t >> 6;
    const int wy = wv >> 1, wx = wv & 1;

    const bool is1x1 = (MODE == 2) || (MODE == 1 && zz == 2);
    const ushort_t* Wsrc; int tap0, iters, kd0, kh0, kw0; float* Y;
    if (is1x1) {
        Wsrc = W3; tap0 = 0; iters = 12; kd0 = 1; kh0 = 1; kw0 = 1; Y = Y2;
    } else {
        Wsrc = Wb; tap0 = zz ? 14 : 0; iters = (zz ? 13 : 14) * 12;
        kd0 = zz ? 1 : 0; kh0 = zz ? 1 : 0; kw0 = zz ? 2 : 0;
        Y = Y01 + (size_t)zz * PSTRIDE;
    }

    __shared__ __align__(16) ushort_t As[4096];          // [128][32] bf16, 8KB
    __shared__ __align__(16) ushort_t Bs[4096];

    f32x4 acc[4][4];
#pragma unroll
    for (int i = 0; i < 4; ++i)
#pragma unroll
        for (int j = 0; j < 4; ++j) acc[i][j] = (f32x4){0.f, 0.f, 0.f, 0.f};

    // --- staging thread-constants (per-lane global offsets, fixed) ---
    const int l4 = lane >> 2;                            // row-within-16
    const int cg = (((lane & 3) ^ ((lane >> 3) & 3)) << 3);  // swizzled granule (elems)
    int aTC[2], bTC[2];
#pragma unroll
    for (int i = 0; i < 2; ++i) {
        const int r = wv * 32 + i * 16 + l4;             // LDS row this lane fills
        aTC[i] = (co0 + r) * CDIM + cg;
        bTC[i] = ((r >> 4) * 18 + (r & 15)) * CDIM + cg;
    }
    ushort_t* lA[2] = { &As[wv * 1024], &As[wv * 1024 + 512] };
    ushort_t* lB[2] = { &Bs[wv * 1024], &Bs[wv * 1024 + 512] };

    // --- uniform walking offsets (elems) ---
    int aoff = tap0 * (CDIM * CDIM);
    int goff = (((b * 18 + d + kd0) * 18 + (h0 + kh0)) * 18 + kw0) * CDIM;
    int c12 = 0, ckw = kw0, ckh = kh0;

    // --- fragment read bases (loop-invariant, same XOR involution) ---
    const int lm = lane & 15;
    const int sw8 = (((lane >> 4) ^ ((lm >> 1) & 3)) << 3);
    const int rA0 = (wy * 64 + lm) * 32 + sw8;           // + mi*512
    const int rB0 = (wx * 64 + lm) * 32 + sw8;           // + ni*512

    for (int idx = 0; idx < iters; ++idx) {
#pragma unroll
        for (int i = 0; i < 2; ++i) {
            gl16(Wsrc + aoff + aTC[i], lA[i]);
            gl16(Xp + goff + bTC[i], lB[i]);
        }
        aoff += 32; goff += 32;
        if (++c12 == 12) {                               // tap wrap
            c12 = 0;
            aoff += CDIM * CDIM - CDIM;
            if (++ckw == 3) {
                ckw = 0;
                if (++ckh == 3) { ckh = 0; goff += 109440; }
                else goff += 5760;
            }
        }
        __syncthreads();                                 // drains vmcnt: LDS ready
        bf16x8 af[4], bfr[4];
#pragma unroll
        for (int mi = 0; mi < 4; ++mi)
            af[mi] = *reinterpret_cast<const bf16x8*>(&As[rA0 + mi * 512]);
#pragma unroll
        for (int ni = 0; ni < 4; ++ni)
            bfr[ni] = *reinterpret_cast<const bf16x8*>(&Bs[rB0 + ni * 512]);
#pragma unroll
        for (int mi = 0; mi < 4; ++mi)
#pragma unroll
            for (int ni = 0; ni < 4; ++ni)
                acc[mi][ni] = __builtin_amdgcn_mfma_f32_16x16x32_bf16(
                    af[mi], bfr[ni], acc[mi][ni], 0, 0, 0);
        __syncthreads();                                 // reads done before overwrite
    }

    // epilogue: C/D layout col(lane&15)=sp, row=(lane>>4)*4+j=co
    const int coB = co0 + wy * 64 + (lane >> 4) * 4;
    const int nB  = wx * 64 + lm;
#pragma unroll
    for (int mi = 0; mi < 4; ++mi) {
#pragma unroll
        for (int ni = 0; ni < 4; ++ni) {
            const int nl = nB + ni * 16;
            const int s = d * 256 + (h0 + (nl >> 4)) * 16 + (nl & 15);
            float* yp = Y + ((size_t)b * CDIM + (coB + mi * 16)) * SDIM + s;
#pragma unroll
            for (int j = 0; j < 4; ++j)
                yp[(size_t)j * SDIM] = acc[mi][ni][j];
        }
    }
}

// ---------------------------------------------------------------------------
// bf16 MFMA GEMM, NT: C[M,N] = A[M,K] x B[N,K]^T, flat grid, direct mapping.
// nx = number of 128-wide n-tiles. EPI 0: fp32 store (ldc);
// 1: xz split -> bf16 C/C2 (N=1536); 2: transposed fp32 float4 store C[b][n][l].
// ---------------------------------------------------------------------------
template<int EPI>
__global__ __launch_bounds__(256)
void gemm_mfma_kernel(const ushort_t* __restrict__ A, const ushort_t* __restrict__ Bw,
                      void* __restrict__ Cv, void* __restrict__ C2v,
                      int M, int N, int K, int ldc, int nx) {
    const int wid = blockIdx.x;
    const int n0 = (wid % nx) * 128;
    const int m0 = (wid / nx) * 128;
    const int t = threadIdx.x;
    const int lane = t & 63;
    const int wy = (t >> 6) >> 1, wx = (t >> 6) & 1;

    __shared__ ushort_t As[2][128 * 40];
    __shared__ ushort_t Bs[2][128 * 40];

    f32x4 acc[4][4];
#pragma unroll
    for (int i = 0; i < 4; ++i)
#pragma unroll
        for (int j = 0; j < 4; ++j) acc[i][j] = (f32x4){0.f, 0.f, 0.f, 0.f};

    const int arow = t >> 1, half = t & 1;
    const int wA = arow * 40 + half * 16;
    const int lm = lane & 15, lk = (lane >> 4) * 8;
    const int rA0 = (wy * 64 + lm) * 40 + lk;
    const int rB0 = (wx * 64 + lm) * 40 + lk;

    uint4 ra0, ra1, rb0, rb1;

    auto loadg = [&](int kk) {
        const int kb = kk * 32 + half * 16;
        const uint4* pa = reinterpret_cast<const uint4*>(
            A + (size_t)(m0 + arow) * K + kb);
        ra0 = pa[0]; ra1 = pa[1];
        if (n0 + arow < N) {
            const uint4* pb = reinterpret_cast<const uint4*>(
                Bw + (size_t)(n0 + arow) * K + kb);
            rb0 = pb[0]; rb1 = pb[1];
        } else {
            rb0 = make_uint4(0, 0, 0, 0); rb1 = rb0;
        }
    };
    auto lwrite = [&](int buf) {
        *reinterpret_cast<uint4*>(&As[buf][wA])     = ra0;
        *reinterpret_cast<uint4*>(&As[buf][wA + 8]) = ra1;
        *reinterpret_cast<uint4*>(&Bs[buf][wA])     = rb0;
        *reinterpret_cast<uint4*>(&Bs[buf][wA + 8]) = rb1;
    };

    const int KI = K >> 5;
    loadg(0);
    lwrite(0);
    __syncthreads();

    int buf = 0;
    for (int kk = 0; kk < KI; ++kk) {
        const bool more = (kk + 1) < KI;
        if (more) loadg(kk + 1);
        bf16x8 af[4], bfr[4];
#pragma unroll
        for (int mi = 0; mi < 4; ++mi)
            af[mi] = *reinterpret_cast<const bf16x8*>(&As[buf][rA0 + mi * 640]);
#pragma unroll
        for (int ni = 0; ni < 4; ++ni)
            bfr[ni] = *reinterpret_cast<const bf16x8*>(&Bs[buf][rB0 + ni * 640]);
#pragma unroll
        for (int mi = 0; mi < 4; ++mi)
#pragma unroll
            for (int ni = 0; ni < 4; ++ni)
                acc[mi][ni] = __builtin_amdgcn_mfma_f32_16x16x32_bf16(
                    af[mi], bfr[ni], acc[mi][ni], 0, 0, 0);
        if (more) lwrite(buf ^ 1);
        __syncthreads();
        buf ^= 1;
    }

    const int mB = m0 + wy * 64 + (lane >> 4) * 4;
    const int nB = n0 + wx * 64 + lm;
#pragma unroll
    for (int mi = 0; mi < 4; ++mi) {
#pragma unroll
        for (int ni = 0; ni < 4; ++ni) {
            const int n = nB + ni * 16;
            if (EPI == 2) {                              // transposed float4
                const int mrow = mB + mi * 16;
                const int bb = mrow >> 12, l = mrow & 4095;
                float4 st = {acc[mi][ni][0], acc[mi][ni][1],
                             acc[mi][ni][2], acc[mi][ni][3]};
                *reinterpret_cast<float4*>(
                    (float*)Cv + ((size_t)(bb * CDIM + n)) * SDIM + l) = st;
            } else {
#pragma unroll
                for (int j = 0; j < 4; ++j) {
                    const int m = mB + mi * 16 + j;
                    const float v = acc[mi][ni][j];
                    if (EPI == 0) {
                        if (n < N) ((float*)Cv)[(size_t)m * ldc + n] = v;
                    } else {                             // xz split, bf16 out
                        if (n < DINC) ((ushort_t*)Cv)[(size_t)m * DINC + n] = f2bf(v);
                        else ((ushort_t*)C2v)[(size_t)m * DINC + (n - DINC)] = f2bf(v);
                    }
                }
            }
        }
    }
}

// ---------------------------------------------------------------------------
// Reduction helper for instance-norm stats.
// ---------------------------------------------------------------------------
__device__ __forceinline__ void stats_reduce(float s, float ss, float* out) {
#pragma unroll
    for (int off = 32; off > 0; off >>= 1) {
        s += __shfl_down(s, off);
        ss += __shfl_down(ss, off);
    }
    __shared__ float rs[4], rss[4];
    const int wid = threadIdx.x >> 6;
    if ((threadIdx.x & 63) == 0) { rs[wid] = s; rss[wid] = ss; }
    __syncthreads();
    if (threadIdx.x == 0) {
        float S = rs[0] + rs[1] + rs[2] + rs[3];
        float SS = rss[0] + rss[1] + rss[2] + rss[3];
        float m = S * (1.f / SDIM);
        float var = SS * (1.f / SDIM) - m * m;
        out[0] = m;
        out[1] = rsqrtf(var + 1e-5f);
    }
}

// ---------------------------------------------------------------------------
// Combo stats: bc<1536 -> stats of (P0+P1) into SA; bc>=1536 -> stats of X3
// into SB (only when grid > 1536).
// ---------------------------------------------------------------------------
__global__ __launch_bounds__(256)
void inorm_stats_combo_kernel(const float* __restrict__ P0, const float* __restrict__ P1,
                              float* __restrict__ SA, const float* __restrict__ X3,
                              float* __restrict__ SB) {
    const int bid = blockIdx.x;
    float s = 0.f, ss = 0.f;
    if (bid < 1536) {
        const float* p0 = P0 + (size_t)bid * SDIM;
        const float* p1 = P1 + (size_t)bid * SDIM;
        for (int i = threadIdx.x * 4; i < SDIM; i += 1024) {
            float4 a = *(const float4*)(p0 + i);
            float4 c = *(const float4*)(p1 + i);
            const float vx = a.x + c.x, vy = a.y + c.y, vz = a.z + c.z, vw = a.w + c.w;
            s += vx + vy + vz + vw;
            ss += vx * vx + vy * vy + vz * vz + vw * vw;
        }
        stats_reduce(s, ss, SA + bid * 2);
    } else {
        const int bc = bid - 1536;
        const float* xp = X3 + (size_t)bc * SDIM;
        for (int i = threadIdx.x * 4; i < SDIM; i += 1024) {
            float4 v = *(const float4*)(xp + i);
            s += v.x + v.y + v.z + v.w;
            ss += v.x * v.x + v.y * v.y + v.z * v.z + v.w * v.w;
        }
        stats_reduce(s, ss, SB + bc * 2);
    }
}

// ---------------------------------------------------------------------------
// InstanceNorm stats, single input.
// ---------------------------------------------------------------------------
__global__ __launch_bounds__(256)
void inorm_stats_kernel(const float* __restrict__ X, float* __restrict__ stats) {
    const int bc = blockIdx.x;
    const float* xp = X + (size_t)bc * SDIM;
    float s = 0.f, ss = 0.f;
    for (int i = threadIdx.x * 4; i < SDIM; i += 1024) {
        float4 v = *(const float4*)(xp + i);
        s += v.x + v.y + v.z + v.w;
        ss += v.x * v.x + v.y * v.y + v.z * v.z + v.w * v.w;
    }
    stats_reduce(s, ss, stats + bc * 2);
}

// ---------------------------------------------------------------------------
// Fused LayerNorm: xg = relu((C4-m)*r) + x inline, LN over C, transpose
// -> tn [b][l][c] bf16.
// ---------------------------------------------------------------------------
__global__ __launch_bounds__(256)
void layernorm_kernel(const float* __restrict__ C4, const float* __restrict__ stats,
                      const float* __restrict__ X, const float* __restrict__ gam,
                      const float* __restrict__ bet, ushort_t* __restrict__ Tn) {
    const int token = blockIdx.x * 4 + (threadIdx.x >> 6);
    const int lane = threadIdx.x & 63;
    const int b = token >> 12, l = token & 4095;
    const size_t base = (size_t)b * CDIM * SDIM + l;
    float v[6];
    float s = 0.f, ss = 0.f;
#pragma unroll
    for (int i = 0; i < 6; ++i) {
        const int c = lane + i * 64;
        const size_t o = base + (size_t)c * SDIM;
        const float m = stats[(b * CDIM + c) * 2], r = stats[(b * CDIM + c) * 2 + 1];
        v[i] = fmaxf((C4[o] - m) * r, 0.f) + X[o];
        s += v[i]; ss += v[i] * v[i];
    }
#pragma unroll
    for (int off = 32; off > 0; off >>= 1) {
        s += __shfl_down(s, off);
        ss += __shfl_down(ss, off);
    }
    s = __shfl(s, 0); ss = __shfl(ss, 0);
    const float m = s * (1.f / CDIM);
    const float r = rsqrtf(ss * (1.f / CDIM) - m * m + 1e-5f);
    ushort_t* tp = Tn + (size_t)token * CDIM;
#pragma unroll
    for (int i = 0; i < 6; ++i) {
        const int c = lane + i * 64;
        tp[c] = f2bf((v[i] - m) * r * gam[c] + bet[c]);
    }
}

// ---------------------------------------------------------------------------
// Tiled fp32 GEMM for dt_proj (K=24), NT, bias+softplus, bf16 store.
// ---------------------------------------------------------------------------
__global__ __launch_bounds__(256)
void gemm_dtproj_kernel(const float* __restrict__ A, const float* __restrict__ B,
                        ushort_t* __restrict__ C, const float* __restrict__ bias,
                        int M, int N, int K, int lda, int ldb, int ldc) {
    __shared__ __align__(16) float As[16][132];
    __shared__ __align__(16) float Bs[16][68];
    const int t = threadIdx.x;
    const int m0 = blockIdx.y * 128;
    const int n0 = blockIdx.x * 64;

    float acc[8][4];
#pragma unroll
    for (int i = 0; i < 8; ++i)
#pragma unroll
        for (int j = 0; j < 4; ++j) acc[i][j] = 0.f;

    const int mr = (t & 15) * 8;
    const int nr = (t >> 4) * 4;

    for (int k0 = 0; k0 < K; k0 += 16) {
#pragma unroll
        for (int idx = 0; idx < 8; ++idx) {
            const int e = idx * 256 + t;
            const int k = e & 15, m = e >> 4;
            float v = 0.f;
            if (k0 + k < K) v = A[(size_t)(m0 + m) * lda + (k0 + k)];
            As[k][m] = v;
        }
#pragma unroll
        for (int idx = 0; idx < 4; ++idx) {
            const int e = idx * 256 + t;
            const int k = e & 15, n = e >> 4;
            float v = 0.f;
            if ((n0 + n) < N && (k0 + k) < K) v = B[(size_t)(n0 + n) * ldb + (k0 + k)];
            Bs[k][n] = v;
        }
        __syncthreads();
#pragma unroll
        for (int k = 0; k < 16; ++k) {
            float4 a0 = *(const float4*)&As[k][mr];
            float4 a1 = *(const float4*)&As[k][mr + 4];
            float4 b0 = *(const float4*)&Bs[k][nr];
            const float av[8] = {a0.x, a0.y, a0.z, a0.w, a1.x, a1.y, a1.z, a1.w};
            const float bv[4] = {b0.x, b0.y, b0.z, b0.w};
#pragma unroll
            for (int i = 0; i < 8; ++i)
#pragma unroll
                for (int j = 0; j < 4; ++j)
                    acc[i][j] = fmaf(av[i], bv[j], acc[i][j]);
        }
        __syncthreads();
    }

#pragma unroll
    for (int i = 0; i < 8; ++i) {
        const int m = m0 + mr + i;
#pragma unroll
        for (int j = 0; j < 4; ++j) {
            const int n = n0 + nr + j;
            if (n >= N) continue;
            float v = acc[i][j] + bias[n];
            v = (v > 20.f) ? v : log1pf(__expf(v));
            C[(size_t)m * ldc + n] = f2bf(v);
        }
    }
}

// ---------------------------------------------------------------------------
// Causal depthwise conv1d (K=4) + bias + SiLU, bf16 in/out. 4 tokens/thread.
// ---------------------------------------------------------------------------
__global__ __launch_bounds__(256)
void dwconv_silu_kernel(const ushort_t* __restrict__ Xin, const float* __restrict__ W,
                        const float* __restrict__ bias, ushort_t* __restrict__ U) {
    const int dch = blockIdx.x * 256 + threadIdx.x;
    const int l0 = blockIdx.y * 4, b = blockIdx.z;
    const float4 w4 = ((const float4*)W)[dch];
    const float wk[4] = {w4.x, w4.y, w4.z, w4.w};
    const float bs = bias[dch];
    const size_t base = ((size_t)b * 4096 + l0) * DINC + dch;
    float r[7];
#pragma unroll
    for (int k = 0; k < 7; ++k) {
        const int ll = l0 - 3 + k;
        r[k] = (ll >= 0) ? bf2f(Xin[base + (size_t)(k - 3) * DINC]) : 0.f;
    }
#pragma unroll
    for (int j = 0; j < 4; ++j) {
        float acc = bs;
#pragma unroll
        for (int k = 0; k < 4; ++k) acc = fmaf(r[j + k], wk[k], acc);
        U[base + (size_t)j * DINC] = f2bf(acc / (1.f + __expf(-acc)));
    }
}

// ---------------------------------------------------------------------------
// Chunked parallel selective scan (3 phases). dt/u/z/y bf16; B,C fp32.
// ---------------------------------------------------------------------------
__global__ __launch_bounds__(256)
void scan_phase1_kernel(const ushort_t* __restrict__ DT, const ushort_t* __restrict__ U,
                        const float* __restrict__ DBL, const float* __restrict__ A_log,
                        float* __restrict__ HOUT, float* __restrict__ SDT) {
    const int b = blockIdx.z, chunk = blockIdx.y;
    const int dch = blockIdx.x * 256 + threadIdx.x;
    float Arow[16];
#pragma unroll
    for (int n = 0; n < NST; ++n) Arow[n] = -__expf(A_log[dch * NST + n]);

    __shared__ float bcs[LCHUNK][16];
    const size_t tokbase = (size_t)b * 4096 + chunk * LCHUNK;
#pragma unroll
    for (int idx = 0; idx < 4; ++idx) {
        const int e = idx * 256 + threadIdx.x;
        bcs[e >> 4][e & 15] = DBL[(tokbase + (e >> 4)) * 56 + 24 + (e & 15)];
    }
    __syncthreads();

    size_t off = tokbase * DINC + dch;
    float h[16];
#pragma unroll
    for (int n = 0; n < NST; ++n) h[n] = 0.f;
    float sdt = 0.f;
    float cdt = bf2f(DT[off]), cu = bf2f(U[off]);
    for (int t = 0; t < LCHUNK; ++t) {
        float ndt = 0.f, nu = 0.f;
        if (t < LCHUNK - 1) { ndt = bf2f(DT[off + DINC]); nu = bf2f(U[off + DINC]); }
        sdt += cdt;
        const float du = cdt * cu;
#pragma unroll
        for (int n = 0; n < NST; ++n)
            h[n] = __expf(cdt * Arow[n]) * h[n] + du * bcs[t][n];
        off += DINC;
        cdt = ndt; cu = nu;
    }
    float* hp = HOUT + (((size_t)(b * DINC + dch) * NCHUNK + chunk) << 4);
#pragma unroll
    for (int n = 0; n < NST; ++n) hp[n] = h[n];
    SDT[(size_t)(b * DINC + dch) * NCHUNK + chunk] = sdt;
}

__global__ __launch_bounds__(256)
void scan_phase2_kernel(float* __restrict__ HOUT, const float* __restrict__ SDT,
                        const float* __restrict__ A_log) {
    const int t = blockIdx.x * 256 + threadIdx.x;        // 49152
    const int b = t / (DINC * NST);
    const int rem = t - b * (DINC * NST);
    const int d = rem >> 4, n = rem & 15;
    const float An = -__expf(A_log[d * NST + n]);
    float* hp = HOUT + (((size_t)(b * DINC + d) * NCHUNK) << 4) + n;
    const float* sp = SDT + (size_t)(b * DINC + d) * NCHUNK;
    float H = 0.f;
    for (int c = 0; c < NCHUNK; ++c) {
        const float tmp = hp[c * 16];
        const float dA = __expf(An * sp[c]);
        hp[c * 16] = H;
        H = dA * H + tmp;
    }
}

__global__ __launch_bounds__(256)
void scan_phase3_kernel(ushort_t* __restrict__ DT, const ushort_t* __restrict__ U,
                        const float* __restrict__ DBL, const ushort_t* __restrict__ Z,
                        const float* __restrict__ A_log, const float* __restrict__ D_skip,
                        const float* __restrict__ HOUT) {
    const int b = blockIdx.z, chunk = blockIdx.y;
    const int dch = blockIdx.x * 256 + threadIdx.x;
    float Arow[16];
#pragma unroll
    for (int n = 0; n < NST; ++n) Arow[n] = -__expf(A_log[dch * NST + n]);
    const float Dsk = D_skip[dch];

    __shared__ float bcs[LCHUNK][32];
    const size_t tokbase = (size_t)b * 4096 + chunk * LCHUNK;
#pragma unroll
    for (int idx = 0; idx < 8; ++idx) {
        const int e = idx * 256 + threadIdx.x;
        bcs[e >> 5][e & 31] = DBL[(tokbase + (e >> 5)) * 56 + 24 + (e & 31)];
    }
    __syncthreads();

    float h[16];
    const float* hp = HOUT + (((size_t)(b * DINC + dch) * NCHUNK + chunk) << 4);
#pragma unroll
    for (int n = 0; n < NST; ++n) h[n] = hp[n];

    size_t off = tokbase * DINC + dch;
    float cdt = bf2f(DT[off]), cu = bf2f(U[off]), cz = bf2f(Z[off]);
    for (int t = 0; t < LCHUNK; ++t) {
        float ndt = 0.f, nu = 0.f, nz = 0.f;
        if (t < LCHUNK - 1) {
            ndt = bf2f(DT[off + DINC]); nu = bf2f(U[off + DINC]); nz = bf2f(Z[off + DINC]);
        }
        const float du = cdt * cu;
        float y = 0.f;
#pragma unroll
        for (int n = 0; n < NST; ++n) {
            h[n] = __expf(cdt * Arow[n]) * h[n] + du * bcs[t][n];
            y = fmaf(h[n], bcs[t][16 + n], y);
        }
        y += cu * Dsk;
        const float sz = cz / (1.f + __expf(-cz));
        DT[off] = f2bf(y * sz);
        off += DINC;
        cdt = ndt; cu = nu; cz = nz;
    }
}

// ---------------------------------------------------------------------------
extern "C" void kernel_launch(void* const* d_in, const int* in_sizes, int n_in,
                              void* d_out, int out_size, void* d_ws, size_t ws_size,
                              hipStream_t stream) {
    (void)in_sizes; (void)n_in; (void)out_size; (void)ws_size;
    const float* x         = (const float*)d_in[0];
    const float* w1        = (const float*)d_in[1];
    const float* w2        = (const float*)d_in[3];
    const float* w3        = (const float*)d_in[5];
    const float* w4        = (const float*)d_in[7];
    const float* ln_g      = (const float*)d_in[9];
    const float* ln_b      = (const float*)d_in[10];
    const float* in_proj_w = (const float*)d_in[11];
    const float* conv1d_w  = (const float*)d_in[12];
    const float* conv1d_b  = (const float*)d_in[13];
    const float* x_proj_w  = (const float*)d_in[14];
    const float* dt_proj_w = (const float*)d_in[15];
    const float* dt_proj_b = (const float*)d_in[16];
    const float* A_log     = (const float*)d_in[17];
    const float* D_skip    = (const float*)d_in[18];
    const float* out_proj_w= (const float*)d_in[19];
    float* out = (float*)d_out;

    // Workspace regions (floats): R0..R4. Lifetimes disjoint where aliased.
    float* ws = (float*)d_ws;
    float* R0 = ws;                    //  6291456
    float* R1 = ws + 6291456;          //  6291456
    float* R2 = ws + 12582912;         // 12582912
    float* R3 = ws + 25165824;         // 12582912
    float* R4 = ws + 37748736;         // 12582912

    // GSC-phase aliases
    float*    P0    = R0;                            // conv partial z=0
    float*    P1    = R1;                            // conv partial z=1 (P0+PSTRIDE)
    ushort_t* Wb1   = (ushort_t*)R2;                 // 3981312 bf16 (2097152 fl)
    ushort_t* Xp    = (ushort_t*)(R2 + 2097152);     // 8957952 bf16 (4478976 fl)
    ushort_t* w3b   = (ushort_t*)(R2 + 6576128);     // 147456 bf16
    ushort_t* w4b   = (ushort_t*)(R2 + 6649856);     // 147456 bf16
    ushort_t* Wb2   = (ushort_t*)(R2 + 6723584);     // 3981312 bf16 -> ends 8714240
    float*    SA    = R4;                            // stats A (3072 fl)
    float*    SB    = R4 + 4096;                     // stats B (3072 fl)
    // weights in the permanently-free R4 tail (beyond Ub's 6291456 fl)
    ushort_t* ipwb  = (ushort_t*)(R4 + 6291456);     // 589824 bf16 (294912 fl)
    ushort_t* opwb  = (ushort_t*)(R4 + 6586368);     // 294912 bf16 (147456 fl)
    ushort_t* xpwb  = (ushort_t*)(R4 + 6733824);     // 43008 bf16
    // Mamba-phase aliases
    ushort_t* tnb   = (ushort_t*)R0;                 // 16384*384 bf16 (3145728 fl)
    float*    DBL   = R0 + 3145728;                  // 16384*56 fp32
    float*    HOUT  = R1;                            // 3145728 fl
    float*    SDT   = R1 + 3145728;                  // 196608 fl
    ushort_t* XIN   = (ushort_t*)R2;                 // 16384*768 bf16 (over conv bufs)
    ushort_t* Zb    = (ushort_t*)R3;                 // 16384*768 bf16
    ushort_t* Ub    = (ushort_t*)R4;                 // 16384*768 bf16
    ushort_t* DTb   = (ushort_t*)R2;                 // dt/y bf16 over XIN

    const size_t XP_BYTES = (size_t)4 * 18 * 18 * 18 * CDIM * 2;

    // ---- upfront: zero pad borders, convert all weights, pad x ----
    hipMemsetAsync(Xp, 0, XP_BYTES, stream);
    prep_weights_kernel<<<2346, 256, 0, stream>>>(
        w1, w2, w3, w4, in_proj_w, out_proj_w, x_proj_w,
        Wb1, Wb2, w3b, w4b, ipwb, opwb, xpwb);
    pad_kernel<<<1024, 384, 0, stream>>>(x, Xp);
    // ---- c1 (3x3x3 z-split) + c3 (1x1) fused in one dispatch ----
    conv_kernel<1><<<1152, 256, 0, stream>>>(Xp, Wb1, w3b, P0, R3);
    inorm_stats_combo_kernel<<<3072, 256, 0, stream>>>(P0, P1, SA, R3, SB); // c1->SA, c3->SB
    pad_fuse2_kernel<<<1024, 384, 0, stream>>>(P0, P1, SA, Xp);             // x1a
    // ---- c2 ----
    conv_kernel<0><<<768, 256, 0, stream>>>(Xp, Wb2, nullptr, P0, nullptr);
    inorm_stats_combo_kernel<<<1536, 256, 0, stream>>>(P0, P1, SA, nullptr, nullptr);
    pad_fuse3_kernel<<<1024, 384, 0, stream>>>(P0, P1, SA, R3, SB, Xp);     // S
    // ---- c4 (1x1) ----
    conv_kernel<2><<<384, 256, 0, stream>>>(Xp, nullptr, w4b, nullptr, R3);
    inorm_stats_kernel<<<1536, 256, 0, stream>>>(R3, SA);
    // ---- fused relu(IN(c4)) + x residual + LayerNorm -> tn bf16 [b][l][c]
    layernorm_kernel<<<4096, 256, 0, stream>>>(R3, SA, x, ln_g, ln_b, tnb);
    // ---- in_proj (bf16 MFMA): tn x W^T -> split XIN | Zb (bf16)
    gemm_mfma_kernel<1><<<1536, 256, 0, stream>>>(
        tnb, ipwb, XIN, Zb, 16384, 1536, CDIM, 0, 12);
    // ---- causal depthwise conv + SiLU -> Ub (bf16)
    dwconv_silu_kernel<<<dim3(3, 1024, 4), 256, 0, stream>>>(XIN, conv1d_w, conv1d_b, Ub);
    // ---- x_proj (bf16 MFMA, N=56 masked): u x W^T -> DBL (fp32)
    gemm_mfma_kernel<0><<<128, 256, 0, stream>>>(
        Ub, xpwb, DBL, nullptr, 16384, 56, DINC, 56, 1);
    // ---- dt_proj (fp32 VALU, K=24) + bias + softplus -> DTb (bf16, over XIN)
    gemm_dtproj_kernel<<<dim3(12, 128), 256, 0, stream>>>(
        DBL, dt_proj_w, DTb, dt_proj_b, 16384, DINC, 24, 56, 24, DINC);
    // ---- chunked parallel selective scan (y bf16 over DTb)
    scan_phase1_kernel<<<dim3(3, NCHUNK, 4), 256, 0, stream>>>(
        DTb, Ub, DBL, A_log, HOUT, SDT);
    scan_phase2_kernel<<<192, 256, 0, stream>>>(HOUT, SDT, A_log);
    scan_phase3_kernel<<<dim3(3, NCHUNK, 4), 256, 0, stream>>>(
        DTb, Ub, DBL, Zb, A_log, D_skip, HOUT);
    // ---- out_proj (bf16 MFMA) -> d_out transposed fp32
    gemm_mfma_kernel<2><<<384, 256, 0, stream>>>(
        DTb, opwb, out, nullptr, 16384, CDIM, DINC, 0, 3);
}

// Round 10
// 750.753 us; speedup vs baseline: 1.5278x; 1.0791x over previous
//
#include <hip/hip_runtime.h>
#include <math.h>

#define CDIM 384
#define SDIM 4096
#define BDIM 4
#define DINC 768
#define NST  16
#define NCHUNK 64
#define LCHUNK 64
#define PSTRIDE 6291456   // ELEMENTS per conv partial [B,C,S] (bf16 now)

typedef unsigned short ushort_t;
typedef unsigned int uint_t;
typedef __attribute__((ext_vector_type(4))) float f32x4;
typedef __attribute__((ext_vector_type(8))) short bf16x8;

__device__ __forceinline__ ushort_t f2bf(float f) {
    union { float f; uint_t u; } v; v.f = f;
    uint_t r = v.u + 0x7FFFu + ((v.u >> 16) & 1u);   // round-to-nearest-even
    return (ushort_t)(r >> 16);
}
__device__ __forceinline__ float bf2f(ushort_t u) {
    union { uint_t i; float f; } v; v.i = ((uint_t)u) << 16; return v.f;
}
__device__ __forceinline__ uint_t pk2(float a, float b) {
    return (uint_t)f2bf(a) | ((uint_t)f2bf(b) << 16);
}
// async global->LDS, 16B per lane, dest = wave-uniform base + lane*16
__device__ __forceinline__ void gl16(const ushort_t* g, ushort_t* l) {
    __builtin_amdgcn_global_load_lds(
        (const __attribute__((address_space(1))) void*)(g),
        (__attribute__((address_space(3))) void*)(l), 16, 0, 0);
}

// ---------------------------------------------------------------------------
// Merged weight prep: all fp32->bf16 weight conversions in one dispatch.
// ---------------------------------------------------------------------------
__device__ __forceinline__ void wconv_body(const float* __restrict__ W,
                                           ushort_t* __restrict__ Wb, int idx) {
    const float* wp = W + (size_t)idx * 27;              // idx = co*384+ci
#pragma unroll
    for (int tap = 0; tap < 27; ++tap)
        Wb[(size_t)tap * (CDIM * CDIM) + idx] = f2bf(wp[tap]);
}
__device__ __forceinline__ void cvt_body(const float* __restrict__ src,
                                         ushort_t* __restrict__ dst, int i) {
    float4 v = ((const float4*)src)[i];
    uint2 o; o.x = pk2(v.x, v.y); o.y = pk2(v.z, v.w);
    ((uint2*)dst)[i] = o;
}
__global__ __launch_bounds__(256)
void prep_weights_kernel(const float* w1, const float* w2, const float* w3,
                         const float* w4, const float* ipw, const float* opw,
                         const float* xpw,
                         ushort_t* Wb1, ushort_t* Wb2, ushort_t* w3b, ushort_t* w4b,
                         ushort_t* ipwb, ushort_t* opwb, ushort_t* xpwb) {
    const int bid = blockIdx.x, t = threadIdx.x;
    if      (bid < 576)  wconv_body(w1, Wb1, bid * 256 + t);
    else if (bid < 1152) wconv_body(w2, Wb2, (bid - 576) * 256 + t);
    else if (bid < 1296) cvt_body(w3, w3b, (bid - 1152) * 256 + t);
    else if (bid < 1440) cvt_body(w4, w4b, (bid - 1296) * 256 + t);
    else if (bid < 2016) cvt_body(ipw, ipwb, (bid - 1440) * 256 + t);
    else if (bid < 2304) cvt_body(opw, opwb, (bid - 2016) * 256 + t);
    else                 cvt_body(xpw, xpwb, (bid - 2304) * 256 + t);
}

// ---------------------------------------------------------------------------
// Pad + transpose to channels-last bf16: src[b][c][16^3] -> Xp[b][18][18][18][384]
// ---------------------------------------------------------------------------
__global__ __launch_bounds__(384)
void pad_kernel(const float* __restrict__ src, ushort_t* __restrict__ Xp) {
    const int blk = blockIdx.x;                          // b(4) d(16) h(16)
    const int b = blk >> 8, d = (blk >> 4) & 15, h = blk & 15;
    const int ci = threadIdx.x;
    const float* sp = src + (size_t)(b * CDIM + ci) * SDIM + d * 256 + h * 16;
    ushort_t* dp = Xp + ((((size_t)(b * 18 + d + 1) * 18) + (h + 1)) * 18 + 1) * CDIM + ci;
#pragma unroll
    for (int w = 0; w < 16; ++w)
        dp[(size_t)w * CDIM] = f2bf(sp[w]);
}

// ---------------------------------------------------------------------------
// Fused: v = relu((P0+P1 - m)*r) -> pad/transpose channels-last bf16 Xp.
// Partials are bf16.
// ---------------------------------------------------------------------------
__global__ __launch_bounds__(384)
void pad_fuse2_kernel(const ushort_t* __restrict__ P0, const ushort_t* __restrict__ P1,
                      const float* __restrict__ stats, ushort_t* __restrict__ Xp) {
    const int blk = blockIdx.x;
    const int b = blk >> 8, d = (blk >> 4) & 15, h = blk & 15;
    const int ci = threadIdx.x;
    const size_t o = (size_t)(b * CDIM + ci) * SDIM + d * 256 + h * 16;
    const float m = stats[(b * CDIM + ci) * 2], r = stats[(b * CDIM + ci) * 2 + 1];
    union { uint4 q[2]; ushort_t u[16]; } a, c;
    a.q[0] = ((const uint4*)(P0 + o))[0]; a.q[1] = ((const uint4*)(P0 + o))[1];
    c.q[0] = ((const uint4*)(P1 + o))[0]; c.q[1] = ((const uint4*)(P1 + o))[1];
    ushort_t* dp = Xp + ((((size_t)(b * 18 + d + 1) * 18) + (h + 1)) * 18 + 1) * CDIM + ci;
#pragma unroll
    for (int w = 0; w < 16; ++w) {
        const float v = bf2f(a.u[w]) + bf2f(c.u[w]);
        dp[(size_t)w * CDIM] = f2bf(fmaxf((v - m) * r, 0.f));
    }
}

// ---------------------------------------------------------------------------
// Fused: S = relu((P0+P1-m2)*r2) + relu((C3-m3)*r3) -> pad channels-last bf16.
// ---------------------------------------------------------------------------
__global__ __launch_bounds__(384)
void pad_fuse3_kernel(const ushort_t* __restrict__ P0, const ushort_t* __restrict__ P1,
                      const float* __restrict__ st2, const ushort_t* __restrict__ C3,
                      const float* __restrict__ st3, ushort_t* __restrict__ Xp) {
    const int blk = blockIdx.x;
    const int b = blk >> 8, d = (blk >> 4) & 15, h = blk & 15;
    const int ci = threadIdx.x;
    const size_t o = (size_t)(b * CDIM + ci) * SDIM + d * 256 + h * 16;
    const float m2 = st2[(b * CDIM + ci) * 2], r2 = st2[(b * CDIM + ci) * 2 + 1];
    const float m3 = st3[(b * CDIM + ci) * 2], r3 = st3[(b * CDIM + ci) * 2 + 1];
    union { uint4 q[2]; ushort_t u[16]; } a, c, e;
    a.q[0] = ((const uint4*)(P0 + o))[0]; a.q[1] = ((const uint4*)(P0 + o))[1];
    c.q[0] = ((const uint4*)(P1 + o))[0]; c.q[1] = ((const uint4*)(P1 + o))[1];
    e.q[0] = ((const uint4*)(C3 + o))[0]; e.q[1] = ((const uint4*)(C3 + o))[1];
    ushort_t* dp = Xp + ((((size_t)(b * 18 + d + 1) * 18) + (h + 1)) * 18 + 1) * CDIM + ci;
#pragma unroll
    for (int w = 0; w < 16; ++w) {
        const float x1 = fmaxf((bf2f(a.u[w]) + bf2f(c.u[w]) - m2) * r2, 0.f);
        const float x2 = fmaxf((bf2f(e.u[w]) - m3) * r3, 0.f);
        dp[(size_t)w * CDIM] = f2bf(x1 + x2);
    }
}

// ---------------------------------------------------------------------------
// Implicit-GEMM conv via MFMA bf16, global_load_lds staging (round-9 proven).
// Outputs stored as bf16 (halves epilogue+downstream traffic).
// MODE 0: c2 (z in {0,1} tap-split -> Y01+z*PSTRIDE)
// MODE 1: c1 (z in {0,1}) + c3 1x1 fused as z==2 (W3 -> Y2)
// MODE 2: pure 1x1 (c4 -> Y2)
// ---------------------------------------------------------------------------
template<int MODE>
__global__ __launch_bounds__(256)
void conv_kernel(const ushort_t* __restrict__ Xp, const ushort_t* __restrict__ Wb,
                 const ushort_t* __restrict__ W3, ushort_t* __restrict__ Y01,
                 ushort_t* __restrict__ Y2) {
    const int wid = blockIdx.x;
    const int ntid = wid & 127;                          // nt innermost
    const int rest = wid >> 7;
    const int co0 = (rest % 3) * 128;
    const int zz  = rest / 3;
    const int b  = ntid >> 5;
    const int d  = (ntid >> 1) & 15;
    const int h0 = (ntid & 1) * 8;
    const int t = threadIdx.x;
    const int lane = t & 63;
    const int wv = t >> 6;
    const int wy = wv >> 1, wx = wv & 1;

    const bool is1x1 = (MODE == 2) || (MODE == 1 && zz == 2);
    const ushort_t* Wsrc; int tap0, iters, kd0, kh0, kw0; ushort_t* Y;
    if (is1x1) {
        Wsrc = W3; tap0 = 0; iters = 12; kd0 = 1; kh0 = 1; kw0 = 1; Y = Y2;
    } else {
        Wsrc = Wb; tap0 = zz ? 14 : 0; iters = (zz ? 13 : 14) * 12;
        kd0 = zz ? 1 : 0; kh0 = zz ? 1 : 0; kw0 = zz ? 2 : 0;
        Y = Y01 + (size_t)zz * PSTRIDE;
    }

    __shared__ __align__(16) ushort_t As[4096];          // [128][32] bf16, 8KB
    __shared__ __align__(16) ushort_t Bs[4096];

    f32x4 acc[4][4];
#pragma unroll
    for (int i = 0; i < 4; ++i)
#pragma unroll
        for (int j = 0; j < 4; ++j) acc[i][j] = (f32x4){0.f, 0.f, 0.f, 0.f};

    const int l4 = lane >> 2;
    const int cg = (((lane & 3) ^ ((lane >> 3) & 3)) << 3);
    int aTC[2], bTC[2];
#pragma unroll
    for (int i = 0; i < 2; ++i) {
        const int r = wv * 32 + i * 16 + l4;
        aTC[i] = (co0 + r) * CDIM + cg;
        bTC[i] = ((r >> 4) * 18 + (r & 15)) * CDIM + cg;
    }
    ushort_t* lA[2] = { &As[wv * 1024], &As[wv * 1024 + 512] };
    ushort_t* lB[2] = { &Bs[wv * 1024], &Bs[wv * 1024 + 512] };

    int aoff = tap0 * (CDIM * CDIM);
    int goff = (((b * 18 + d + kd0) * 18 + (h0 + kh0)) * 18 + kw0) * CDIM;
    int c12 = 0, ckw = kw0, ckh = kh0;

    const int lm = lane & 15;
    const int sw8 = (((lane >> 4) ^ ((lm >> 1) & 3)) << 3);
    const int rA0 = (wy * 64 + lm) * 32 + sw8;
    const int rB0 = (wx * 64 + lm) * 32 + sw8;

    for (int idx = 0; idx < iters; ++idx) {
#pragma unroll
        for (int i = 0; i < 2; ++i) {
            gl16(Wsrc + aoff + aTC[i], lA[i]);
            gl16(Xp + goff + bTC[i], lB[i]);
        }
        aoff += 32; goff += 32;
        if (++c12 == 12) {                               // tap wrap
            c12 = 0;
            aoff += CDIM * CDIM - CDIM;
            if (++ckw == 3) {
                ckw = 0;
                if (++ckh == 3) { ckh = 0; goff += 109440; }
                else goff += 5760;
            }
        }
        __syncthreads();                                 // drains vmcnt
        bf16x8 af[4], bfr[4];
#pragma unroll
        for (int mi = 0; mi < 4; ++mi)
            af[mi] = *reinterpret_cast<const bf16x8*>(&As[rA0 + mi * 512]);
#pragma unroll
        for (int ni = 0; ni < 4; ++ni)
            bfr[ni] = *reinterpret_cast<const bf16x8*>(&Bs[rB0 + ni * 512]);
#pragma unroll
        for (int mi = 0; mi < 4; ++mi)
#pragma unroll
            for (int ni = 0; ni < 4; ++ni)
                acc[mi][ni] = __builtin_amdgcn_mfma_f32_16x16x32_bf16(
                    af[mi], bfr[ni], acc[mi][ni], 0, 0, 0);
        __syncthreads();
    }

    // epilogue: C/D layout col(lane&15)=sp, row=(lane>>4)*4+j=co; bf16 store
    const int coB = co0 + wy * 64 + (lane >> 4) * 4;
    const int nB  = wx * 64 + lm;
#pragma unroll
    for (int mi = 0; mi < 4; ++mi) {
#pragma unroll
        for (int ni = 0; ni < 4; ++ni) {
            const int nl = nB + ni * 16;
            const int s = d * 256 + (h0 + (nl >> 4)) * 16 + (nl & 15);
            ushort_t* yp = Y + ((size_t)b * CDIM + (coB + mi * 16)) * SDIM + s;
#pragma unroll
            for (int j = 0; j < 4; ++j)
                yp[(size_t)j * SDIM] = f2bf(acc[mi][ni][j]);
        }
    }
}

// ---------------------------------------------------------------------------
// bf16 MFMA GEMM NT with global_load_lds staging (conv's proven structure).
// C[M,N] = A[M,K] x B[N,K]^T; A,B bf16 row-major K-contiguous. N masked via
// address clamp on stage + mask on store. nx = n-tiles.
// EPI 0: fp32 store (ldc); 1: xz split -> bf16 C/C2 (N=1536);
// 2: transposed fp32 float4 store C[b][n][l].
// ---------------------------------------------------------------------------
template<int EPI>
__global__ __launch_bounds__(256)
void gemm_gl_kernel(const ushort_t* __restrict__ A, const ushort_t* __restrict__ Bw,
                    void* __restrict__ Cv, void* __restrict__ C2v,
                    int M, int N, int K, int ldc, int nx) {
    const int wid = blockIdx.x;
    const int n0 = (wid % nx) * 128;
    const int m0 = (wid / nx) * 128;
    const int t = threadIdx.x;
    const int lane = t & 63;
    const int wv = t >> 6;
    const int wy = wv >> 1, wx = wv & 1;

    __shared__ __align__(16) ushort_t As[4096];
    __shared__ __align__(16) ushort_t Bs[4096];

    f32x4 acc[4][4];
#pragma unroll
    for (int i = 0; i < 4; ++i)
#pragma unroll
        for (int j = 0; j < 4; ++j) acc[i][j] = (f32x4){0.f, 0.f, 0.f, 0.f};

    const int l4 = lane >> 2;
    const int cg = (((lane & 3) ^ ((lane >> 3) & 3)) << 3);
    size_t aTC[2], bTC[2];
#pragma unroll
    for (int i = 0; i < 2; ++i) {
        const int r = wv * 32 + i * 16 + l4;
        aTC[i] = (size_t)(m0 + r) * K + cg;
        int br = n0 + r; if (br >= N) br = N - 1;        // clamp (masked at store)
        bTC[i] = (size_t)br * K + cg;
    }
    ushort_t* lA[2] = { &As[wv * 1024], &As[wv * 1024 + 512] };
    ushort_t* lB[2] = { &Bs[wv * 1024], &Bs[wv * 1024 + 512] };

    const int lm = lane & 15;
    const int sw8 = (((lane >> 4) ^ ((lm >> 1) & 3)) << 3);
    const int rA0 = (wy * 64 + lm) * 32 + sw8;
    const int rB0 = (wx * 64 + lm) * 32 + sw8;

    const int KI = K >> 5;
    for (int kk = 0; kk < KI; ++kk) {
        const int ko = kk * 32;
#pragma unroll
        for (int i = 0; i < 2; ++i) {
            gl16(A + aTC[i] + ko, lA[i]);
            gl16(Bw + bTC[i] + ko, lB[i]);
        }
        __syncthreads();
        bf16x8 af[4], bfr[4];
#pragma unroll
        for (int mi = 0; mi < 4; ++mi)
            af[mi] = *reinterpret_cast<const bf16x8*>(&As[rA0 + mi * 512]);
#pragma unroll
        for (int ni = 0; ni < 4; ++ni)
            bfr[ni] = *reinterpret_cast<const bf16x8*>(&Bs[rB0 + ni * 512]);
#pragma unroll
        for (int mi = 0; mi < 4; ++mi)
#pragma unroll
            for (int ni = 0; ni < 4; ++ni)
                acc[mi][ni] = __builtin_amdgcn_mfma_f32_16x16x32_bf16(
                    af[mi], bfr[ni], acc[mi][ni], 0, 0, 0);
        __syncthreads();
    }

    const int mB = m0 + wy * 64 + (lane >> 4) * 4;
    const int nB = n0 + wx * 64 + lm;
#pragma unroll
    for (int mi = 0; mi < 4; ++mi) {
#pragma unroll
        for (int ni = 0; ni < 4; ++ni) {
            const int n = nB + ni * 16;
            if (EPI == 2) {                              // transposed float4
                const int mrow = mB + mi * 16;
                const int bb = mrow >> 12, l = mrow & 4095;
                float4 st = {acc[mi][ni][0], acc[mi][ni][1],
                             acc[mi][ni][2], acc[mi][ni][3]};
                *reinterpret_cast<float4*>(
                    (float*)Cv + ((size_t)(bb * CDIM + n)) * SDIM + l) = st;
            } else {
#pragma unroll
                for (int j = 0; j < 4; ++j) {
                    const int m = mB + mi * 16 + j;
                    const float v = acc[mi][ni][j];
                    if (EPI == 0) {
                        if (n < N) ((float*)Cv)[(size_t)m * ldc + n] = v;
                    } else {                             // xz split, bf16 out
                        if (n < DINC) ((ushort_t*)Cv)[(size_t)m * DINC + n] = f2bf(v);
                        else ((ushort_t*)C2v)[(size_t)m * DINC + (n - DINC)] = f2bf(v);
                    }
                }
            }
        }
    }
}

// ---------------------------------------------------------------------------
// Reduction helper for instance-norm stats.
// ---------------------------------------------------------------------------
__device__ __forceinline__ void stats_reduce(float s, float ss, float* out) {
#pragma unroll
    for (int off = 32; off > 0; off >>= 1) {
        s += __shfl_down(s, off);
        ss += __shfl_down(ss, off);
    }
    __shared__ float rs[4], rss[4];
    const int wid = threadIdx.x >> 6;
    if ((threadIdx.x & 63) == 0) { rs[wid] = s; rss[wid] = ss; }
    __syncthreads();
    if (threadIdx.x == 0) {
        float S = rs[0] + rs[1] + rs[2] + rs[3];
        float SS = rss[0] + rss[1] + rss[2] + rss[3];
        float m = S * (1.f / SDIM);
        float var = SS * (1.f / SDIM) - m * m;
        out[0] = m;
        out[1] = rsqrtf(var + 1e-5f);
    }
}

// ---------------------------------------------------------------------------
// Combo stats (bf16 inputs): bc<1536 -> stats of (P0+P1) into SA;
// bc>=1536 -> stats of X3 into SB (only when grid > 1536).
// ---------------------------------------------------------------------------
__global__ __launch_bounds__(256)
void inorm_stats_combo_kernel(const ushort_t* __restrict__ P0,
                              const ushort_t* __restrict__ P1,
                              float* __restrict__ SA,
                              const ushort_t* __restrict__ X3,
                              float* __restrict__ SB) {
    const int bid = blockIdx.x;
    float s = 0.f, ss = 0.f;
    if (bid < 1536) {
        const ushort_t* p0 = P0 + (size_t)bid * SDIM;
        const ushort_t* p1 = P1 + (size_t)bid * SDIM;
        for (int i = threadIdx.x * 8; i < SDIM; i += 2048) {
            union { uint4 q; ushort_t u[8]; } a, c;
            a.q = *(const uint4*)(p0 + i);
            c.q = *(const uint4*)(p1 + i);
#pragma unroll
            for (int j = 0; j < 8; ++j) {
                const float v = bf2f(a.u[j]) + bf2f(c.u[j]);
                s += v; ss += v * v;
            }
        }
        stats_reduce(s, ss, SA + bid * 2);
    } else {
        const int bc = bid - 1536;
        const ushort_t* xp = X3 + (size_t)bc * SDIM;
        for (int i = threadIdx.x * 8; i < SDIM; i += 2048) {
            union { uint4 q; ushort_t u[8]; } a;
            a.q = *(const uint4*)(xp + i);
#pragma unroll
            for (int j = 0; j < 8; ++j) {
                const float v = bf2f(a.u[j]);
                s += v; ss += v * v;
            }
        }
        stats_reduce(s, ss, SB + bc * 2);
    }
}

// ---------------------------------------------------------------------------
// InstanceNorm stats, single bf16 input.
// ---------------------------------------------------------------------------
__global__ __launch_bounds__(256)
void inorm_stats_kernel(const ushort_t* __restrict__ X, float* __restrict__ stats) {
    const int bc = blockIdx.x;
    const ushort_t* xp = X + (size_t)bc * SDIM;
    float s = 0.f, ss = 0.f;
    for (int i = threadIdx.x * 8; i < SDIM; i += 2048) {
        union { uint4 q; ushort_t u[8]; } a;
        a.q = *(const uint4*)(xp + i);
#pragma unroll
        for (int j = 0; j < 8; ++j) {
            const float v = bf2f(a.u[j]);
            s += v; ss += v * v;
        }
    }
    stats_reduce(s, ss, stats + bc * 2);
}

// ---------------------------------------------------------------------------
// Fused LayerNorm, coalesced: wave handles 8 consecutive tokens. Lane reads
// 8-token chunks per channel (uint4 bf16 C4 + 2x float4 X), computes
// xg = relu((C4-m)*r)+x, butterfly shfl_xor reduce of 8 (s,ss) pairs, then
// stages tn tile [32 tok][384 c] in LDS and writes coalesced uint4 rows.
// grid 512 = 4 b x 128 tiles of 32 tokens.
// ---------------------------------------------------------------------------
__global__ __launch_bounds__(256)
void layernorm_kernel(const ushort_t* __restrict__ C4, const float* __restrict__ stats,
                      const float* __restrict__ X, const float* __restrict__ gam,
                      const float* __restrict__ bet, ushort_t* __restrict__ Tn) {
    const int blk = blockIdx.x;
    const int b = blk >> 7;
    const int tile0 = (blk & 127) * 32;                  // first token of block
    const int wv = threadIdx.x >> 6;
    const int lane = threadIdx.x & 63;
    const int l0 = tile0 + wv * 8;                       // wave's 8 tokens

    __shared__ ushort_t tile[32 * 384];                  // 24KB

    float v[6][8];
    float s[8], ss[8];
#pragma unroll
    for (int t = 0; t < 8; ++t) { s[t] = 0.f; ss[t] = 0.f; }
    float g[6], be[6];

#pragma unroll
    for (int i = 0; i < 6; ++i) {
        const int c = lane + i * 64;
        g[i] = gam[c]; be[i] = bet[c];
        const size_t base = (size_t)(b * CDIM + c) * SDIM + l0;
        union { uint4 q; ushort_t u[8]; } cv;
        cv.q = *(const uint4*)(C4 + base);
        const float4 x0 = *(const float4*)(X + base);
        const float4 x1 = *(const float4*)(X + base + 4);
        const float xs[8] = {x0.x, x0.y, x0.z, x0.w, x1.x, x1.y, x1.z, x1.w};
        const float m = stats[(b * CDIM + c) * 2];
        const float r = stats[(b * CDIM + c) * 2 + 1];
#pragma unroll
        for (int t = 0; t < 8; ++t) {
            const float val = fmaxf((bf2f(cv.u[t]) - m) * r, 0.f) + xs[t];
            v[i][t] = val;
            s[t] += val; ss[t] += val * val;
        }
    }
#pragma unroll
    for (int off = 32; off > 0; off >>= 1) {
#pragma unroll
        for (int t = 0; t < 8; ++t) {
            s[t] += __shfl_xor(s[t], off);
            ss[t] += __shfl_xor(ss[t], off);
        }
    }
#pragma unroll
    for (int t = 0; t < 8; ++t) {
        const float mean = s[t] * (1.f / CDIM);
        const float rstd = rsqrtf(ss[t] * (1.f / CDIM) - mean * mean + 1e-5f);
        const int trow = (wv * 8 + t) * 384;
#pragma unroll
        for (int i = 0; i < 6; ++i) {
            const int c = lane + i * 64;
            tile[trow + c] = f2bf((v[i][t] - mean) * rstd * g[i] + be[i]);
        }
    }
    __syncthreads();
    // coalesced write: 32x384 ushort = 1536 uint4; 256 threads x 6
    uint4* dst = (uint4*)(Tn + ((size_t)b * 4096 + tile0) * CDIM);
    const uint4* srcp = (const uint4*)tile;
#pragma unroll
    for (int k = 0; k < 6; ++k)
        dst[k * 256 + threadIdx.x] = srcp[k * 256 + threadIdx.x];
}

// ---------------------------------------------------------------------------
// Tiled fp32 GEMM for dt_proj (K=24), NT, bias+softplus, bf16 store.
// ---------------------------------------------------------------------------
__global__ __launch_bounds__(256)
void gemm_dtproj_kernel(const float* __restrict__ A, const float* __restrict__ B,
                        ushort_t* __restrict__ C, const float* __restrict__ bias,
                        int M, int N, int K, int lda, int ldb, int ldc) {
    __shared__ __align__(16) float As[16][132];
    __shared__ __align__(16) float Bs[16][68];
    const int t = threadIdx.x;
    const int m0 = blockIdx.y * 128;
    const int n0 = blockIdx.x * 64;

    float acc[8][4];
#pragma unroll
    for (int i = 0; i < 8; ++i)
#pragma unroll
        for (int j = 0; j < 4; ++j) acc[i][j] = 0.f;

    const int mr = (t & 15) * 8;
    const int nr = (t >> 4) * 4;

    for (int k0 = 0; k0 < K; k0 += 16) {
#pragma unroll
        for (int idx = 0; idx < 8; ++idx) {
            const int e = idx * 256 + t;
            const int k = e & 15, m = e >> 4;
            float v = 0.f;
            if (k0 + k < K) v = A[(size_t)(m0 + m) * lda + (k0 + k)];
            As[k][m] = v;
        }
#pragma unroll
        for (int idx = 0; idx < 4; ++idx) {
            const int e = idx * 256 + t;
            const int k = e & 15, n = e >> 4;
            float v = 0.f;
            if ((n0 + n) < N && (k0 + k) < K) v = B[(size_t)(n0 + n) * ldb + (k0 + k)];
            Bs[k][n] = v;
        }
        __syncthreads();
#pragma unroll
        for (int k = 0; k < 16; ++k) {
            float4 a0 = *(const float4*)&As[k][mr];
            float4 a1 = *(const float4*)&As[k][mr + 4];
            float4 b0 = *(const float4*)&Bs[k][nr];
            const float av[8] = {a0.x, a0.y, a0.z, a0.w, a1.x, a1.y, a1.z, a1.w};
            const float bv[4] = {b0.x, b0.y, b0.z, b0.w};
#pragma unroll
            for (int i = 0; i < 8; ++i)
#pragma unroll
                for (int j = 0; j < 4; ++j)
                    acc[i][j] = fmaf(av[i], bv[j], acc[i][j]);
        }
        __syncthreads();
    }

#pragma unroll
    for (int i = 0; i < 8; ++i) {
        const int m = m0 + mr + i;
#pragma unroll
        for (int j = 0; j < 4; ++j) {
            const int n = n0 + nr + j;
            if (n >= N) continue;
            float v = acc[i][j] + bias[n];
            v = (v > 20.f) ? v : log1pf(__expf(v));
            C[(size_t)m * ldc + n] = f2bf(v);
        }
    }
}

// ---------------------------------------------------------------------------
// Causal depthwise conv1d (K=4) + bias + SiLU, bf16 in/out. 4 tokens/thread.
// ---------------------------------------------------------------------------
__global__ __launch_bounds__(256)
void dwconv_silu_kernel(const ushort_t* __restrict__ Xin, const float* __restrict__ W,
                        const float* __restrict__ bias, ushort_t* __restrict__ U) {
    const int dch = blockIdx.x * 256 + threadIdx.x;
    const int l0 = blockIdx.y * 4, b = blockIdx.z;
    const float4 w4 = ((const float4*)W)[dch];
    const float wk[4] = {w4.x, w4.y, w4.z, w4.w};
    const float bs = bias[dch];
    const size_t base = ((size_t)b * 4096 + l0) * DINC + dch;
    float r[7];
#pragma unroll
    for (int k = 0; k < 7; ++k) {
        const int ll = l0 - 3 + k;
        r[k] = (ll >= 0) ? bf2f(Xin[base + (size_t)(k - 3) * DINC]) : 0.f;
    }
#pragma unroll
    for (int j = 0; j < 4; ++j) {
        float acc = bs;
#pragma unroll
        for (int k = 0; k < 4; ++k) acc = fmaf(r[j + k], wk[k], acc);
        U[base + (size_t)j * DINC] = f2bf(acc / (1.f + __expf(-acc)));
    }
}

// ---------------------------------------------------------------------------
// Chunked parallel selective scan (3 phases). dt/u/z/y bf16; B,C fp32.
// ---------------------------------------------------------------------------
__global__ __launch_bounds__(256)
void scan_phase1_kernel(const ushort_t* __restrict__ DT, const ushort_t* __restrict__ U,
                        const float* __restrict__ DBL, const float* __restrict__ A_log,
                        float* __restrict__ HOUT, float* __restrict__ SDT) {
    const int b = blockIdx.z, chunk = blockIdx.y;
    const int dch = blockIdx.x * 256 + threadIdx.x;
    float Arow[16];
#pragma unroll
    for (int n = 0; n < NST; ++n) Arow[n] = -__expf(A_log[dch * NST + n]);

    __shared__ float bcs[LCHUNK][16];
    const size_t tokbase = (size_t)b * 4096 + chunk * LCHUNK;
#pragma unroll
    for (int idx = 0; idx < 4; ++idx) {
        const int e = idx * 256 + threadIdx.x;
        bcs[e >> 4][e & 15] = DBL[(tokbase + (e >> 4)) * 56 + 24 + (e & 15)];
    }
    __syncthreads();

    size_t off = tokbase * DINC + dch;
    float h[16];
#pragma unroll
    for (int n = 0; n < NST; ++n) h[n] = 0.f;
    float sdt = 0.f;
    float cdt = bf2f(DT[off]), cu = bf2f(U[off]);
    for (int t = 0; t < LCHUNK; ++t) {
        float ndt = 0.f, nu = 0.f;
        if (t < LCHUNK - 1) { ndt = bf2f(DT[off + DINC]); nu = bf2f(U[off + DINC]); }
        sdt += cdt;
        const float du = cdt * cu;
#pragma unroll
        for (int n = 0; n < NST; ++n)
            h[n] = __expf(cdt * Arow[n]) * h[n] + du * bcs[t][n];
        off += DINC;
        cdt = ndt; cu = nu;
    }
    float* hp = HOUT + (((size_t)(b * DINC + dch) * NCHUNK + chunk) << 4);
#pragma unroll
    for (int n = 0; n < NST; ++n) hp[n] = h[n];
    SDT[(size_t)(b * DINC + dch) * NCHUNK + chunk] = sdt;
}

__global__ __launch_bounds__(256)
void scan_phase2_kernel(float* __restrict__ HOUT, const float* __restrict__ SDT,
                        const float* __restrict__ A_log) {
    const int t = blockIdx.x * 256 + threadIdx.x;        // 49152
    const int b = t / (DINC * NST);
    const int rem = t - b * (DINC * NST);
    const int d = rem >> 4, n = rem & 15;
    const float An = -__expf(A_log[d * NST + n]);
    float* hp = HOUT + (((size_t)(b * DINC + d) * NCHUNK) << 4) + n;
    const float* sp = SDT + (size_t)(b * DINC + d) * NCHUNK;
    float H = 0.f;
    for (int c = 0; c < NCHUNK; ++c) {
        const float tmp = hp[c * 16];
        const float dA = __expf(An * sp[c]);
        hp[c * 16] = H;
        H = dA * H + tmp;
    }
}

__global__ __launch_bounds__(256)
void scan_phase3_kernel(ushort_t* __restrict__ DT, const ushort_t* __restrict__ U,
                        const float* __restrict__ DBL, const ushort_t* __restrict__ Z,
                        const float* __restrict__ A_log, const float* __restrict__ D_skip,
                        const float* __restrict__ HOUT) {
    const int b = blockIdx.z, chunk = blockIdx.y;
    const int dch = blockIdx.x * 256 + threadIdx.x;
    float Arow[16];
#pragma unroll
    for (int n = 0; n < NST; ++n) Arow[n] = -__expf(A_log[dch * NST + n]);
    const float Dsk = D_skip[dch];

    __shared__ float bcs[LCHUNK][32];
    const size_t tokbase = (size_t)b * 4096 + chunk * LCHUNK;
#pragma unroll
    for (int idx = 0; idx < 8; ++idx) {
        const int e = idx * 256 + threadIdx.x;
        bcs[e >> 5][e & 31] = DBL[(tokbase + (e >> 5)) * 56 + 24 + (e & 31)];
    }
    __syncthreads();

    float h[16];
    const float* hp = HOUT + (((size_t)(b * DINC + dch) * NCHUNK + chunk) << 4);
#pragma unroll
    for (int n = 0; n < NST; ++n) h[n] = hp[n];

    size_t off = tokbase * DINC + dch;
    float cdt = bf2f(DT[off]), cu = bf2f(U[off]), cz = bf2f(Z[off]);
    for (int t = 0; t < LCHUNK; ++t) {
        float ndt = 0.f, nu = 0.f, nz = 0.f;
        if (t < LCHUNK - 1) {
            ndt = bf2f(DT[off + DINC]); nu = bf2f(U[off + DINC]); nz = bf2f(Z[off + DINC]);
        }
        const float du = cdt * cu;
        float y = 0.f;
#pragma unroll
        for (int n = 0; n < NST; ++n) {
            h[n] = __expf(cdt * Arow[n]) * h[n] + du * bcs[t][n];
            y = fmaf(h[n], bcs[t][16 + n], y);
        }
        y += cu * Dsk;
        const float sz = cz / (1.f + __expf(-cz));
        DT[off] = f2bf(y * sz);
        off += DINC;
        cdt = ndt; cu = nu; cz = nz;
    }
}

// ---------------------------------------------------------------------------
extern "C" void kernel_launch(void* const* d_in, const int* in_sizes, int n_in,
                              void* d_out, int out_size, void* d_ws, size_t ws_size,
                              hipStream_t stream) {
    (void)in_sizes; (void)n_in; (void)out_size; (void)ws_size;
    const float* x         = (const float*)d_in[0];
    const float* w1        = (const float*)d_in[1];
    const float* w2        = (const float*)d_in[3];
    const float* w3        = (const float*)d_in[5];
    const float* w4        = (const float*)d_in[7];
    const float* ln_g      = (const float*)d_in[9];
    const float* ln_b      = (const float*)d_in[10];
    const float* in_proj_w = (const float*)d_in[11];
    const float* conv1d_w  = (const float*)d_in[12];
    const float* conv1d_b  = (const float*)d_in[13];
    const float* x_proj_w  = (const float*)d_in[14];
    const float* dt_proj_w = (const float*)d_in[15];
    const float* dt_proj_b = (const float*)d_in[16];
    const float* A_log     = (const float*)d_in[17];
    const float* D_skip    = (const float*)d_in[18];
    const float* out_proj_w= (const float*)d_in[19];
    float* out = (float*)d_out;

    // Workspace regions (floats): R0..R4. Lifetimes disjoint where aliased.
    float* ws = (float*)d_ws;
    float* R0 = ws;                    //  6291456
    float* R1 = ws + 6291456;          //  6291456
    float* R2 = ws + 12582912;         // 12582912
    float* R3 = ws + 25165824;         // 12582912
    float* R4 = ws + 37748736;         // 12582912

    // GSC-phase aliases (conv partials/outputs now bf16)
    ushort_t* P0    = (ushort_t*)R0;                 // partial z=0 (6291456 us)
    ushort_t* P1    = P0 + PSTRIDE;                  // partial z=1 (second half of R0)
    ushort_t* C34   = (ushort_t*)R3;                 // c3/c4 outputs bf16
    ushort_t* Wb1   = (ushort_t*)R2;                 // 3981312 bf16 (2097152 fl)
    ushort_t* Xp    = (ushort_t*)(R2 + 2097152);     // 8957952 bf16 (4478976 fl)
    ushort_t* w3b   = (ushort_t*)(R2 + 6576128);     // 147456 bf16
    ushort_t* w4b   = (ushort_t*)(R2 + 6649856);     // 147456 bf16
    ushort_t* Wb2   = (ushort_t*)(R2 + 6723584);     // 3981312 bf16 -> ends 8714240
    float*    SA    = R4;                            // stats A (3072 fl)
    float*    SB    = R4 + 4096;                     // stats B (3072 fl)
    // weights in the permanently-free R4 tail (beyond Ub's 6291456 fl... elems)
    ushort_t* ipwb  = (ushort_t*)(R4 + 6291456);     // 589824 bf16 (294912 fl)
    ushort_t* opwb  = (ushort_t*)(R4 + 6586368);     // 294912 bf16 (147456 fl)
    ushort_t* xpwb  = (ushort_t*)(R4 + 6733824);     // 43008 bf16
    // Mamba-phase aliases
    ushort_t* tnb   = (ushort_t*)R0;                 // 16384*384 bf16 (3145728 fl)
    float*    DBL   = R0 + 3145728;                  // 16384*56 fp32 (over dead P1)
    float*    HOUT  = R1;                            // 3145728 fl
    float*    SDT   = R1 + 3145728;                  // 196608 fl
    ushort_t* XIN   = (ushort_t*)R2;                 // 16384*768 bf16 (over conv bufs)
    ushort_t* Zb    = (ushort_t*)R3;                 // 16384*768 bf16
    ushort_t* Ub    = (ushort_t*)R4;                 // 16384*768 bf16
    ushort_t* DTb   = (ushort_t*)R2;                 // dt/y bf16 over XIN

    const size_t XP_BYTES = (size_t)4 * 18 * 18 * 18 * CDIM * 2;

    // ---- upfront: zero pad borders, convert all weights, pad x ----
    hipMemsetAsync(Xp, 0, XP_BYTES, stream);
    prep_weights_kernel<<<2346, 256, 0, stream>>>(
        w1, w2, w3, w4, in_proj_w, out_proj_w, x_proj_w,
        Wb1, Wb2, w3b, w4b, ipwb, opwb, xpwb);
    pad_kernel<<<1024, 384, 0, stream>>>(x, Xp);
    // ---- c1 (3x3x3 z-split) + c3 (1x1) fused in one dispatch ----
    conv_kernel<1><<<1152, 256, 0, stream>>>(Xp, Wb1, w3b, P0, C34);
    inorm_stats_combo_kernel<<<3072, 256, 0, stream>>>(P0, P1, SA, C34, SB);
    pad_fuse2_kernel<<<1024, 384, 0, stream>>>(P0, P1, SA, Xp);             // x1a
    // ---- c2 ----
    conv_kernel<0><<<768, 256, 0, stream>>>(Xp, Wb2, nullptr, P0, nullptr);
    inorm_stats_combo_kernel<<<1536, 256, 0, stream>>>(P0, P1, SA, nullptr, nullptr);
    pad_fuse3_kernel<<<1024, 384, 0, stream>>>(P0, P1, SA, C34, SB, Xp);    // S
    // ---- c4 (1x1) ----
    conv_kernel<2><<<384, 256, 0, stream>>>(Xp, nullptr, w4b, nullptr, C34);
    inorm_stats_kernel<<<1536, 256, 0, stream>>>(C34, SA);
    // ---- fused relu(IN(c4)) + x residual + LayerNorm -> tn bf16 [b][l][c]
    layernorm_kernel<<<512, 256, 0, stream>>>(C34, SA, x, ln_g, ln_b, tnb);
    // ---- in_proj (bf16 MFMA, gl_lds): tn x W^T -> split XIN | Zb (bf16)
    gemm_gl_kernel<1><<<1536, 256, 0, stream>>>(
        tnb, ipwb, XIN, Zb, 16384, 1536, CDIM, 0, 12);
    // ---- causal depthwise conv + SiLU -> Ub (bf16)
    dwconv_silu_kernel<<<dim3(3, 1024, 4), 256, 0, stream>>>(XIN, conv1d_w, conv1d_b, Ub);
    // ---- x_proj (bf16 MFMA, gl_lds, N=56 masked): u x W^T -> DBL (fp32)
    gemm_gl_kernel<0><<<128, 256, 0, stream>>>(
        Ub, xpwb, DBL, nullptr, 16384, 56, DINC, 56, 1);
    // ---- dt_proj (fp32 VALU, K=24) + bias + softplus -> DTb (bf16, over XIN)
    gemm_dtproj_kernel<<<dim3(12, 128), 256, 0, stream>>>(
        DBL, dt_proj_w, DTb, dt_proj_b, 16384, DINC, 24, 56, 24, DINC);
    // ---- chunked parallel selective scan (y bf16 over DTb)
    scan_phase1_kernel<<<dim3(3, NCHUNK, 4), 256, 0, stream>>>(
        DTb, Ub, DBL, A_log, HOUT, SDT);
    scan_phase2_kernel<<<192, 256, 0, stream>>>(HOUT, SDT, A_log);
    scan_phase3_kernel<<<dim3(3, NCHUNK, 4), 256, 0, stream>>>(
        DTb, Ub, DBL, Zb, A_log, D_skip, HOUT);
    // ---- out_proj (bf16 MFMA, gl_lds) -> d_out transposed fp32
    gemm_gl_kernel<2><<<384, 256, 0, stream>>>(
        DTb, opwb, out, nullptr, 16384, CDIM, DINC, 0, 3);
}

// Round 11
// 746.304 us; speedup vs baseline: 1.5369x; 1.0060x over previous
//
#include <hip/hip_runtime.h>
#include <math.h>

#define CDIM 384
#define SDIM 4096
#define BDIM 4
#define DINC 768
#define NST  16
#define NCHUNK 64
#define LCHUNK 64
#define PSTRIDE 6291456   // ELEMENTS per conv partial [B,C,S] (bf16)

typedef unsigned short ushort_t;
typedef unsigned int uint_t;
typedef __attribute__((ext_vector_type(4))) float f32x4;
typedef __attribute__((ext_vector_type(8))) short bf16x8;

__device__ __forceinline__ ushort_t f2bf(float f) {
    union { float f; uint_t u; } v; v.f = f;
    uint_t r = v.u + 0x7FFFu + ((v.u >> 16) & 1u);   // round-to-nearest-even
    return (ushort_t)(r >> 16);
}
__device__ __forceinline__ float bf2f(ushort_t u) {
    union { uint_t i; float f; } v; v.i = ((uint_t)u) << 16; return v.f;
}
__device__ __forceinline__ uint_t pk2(float a, float b) {
    return (uint_t)f2bf(a) | ((uint_t)f2bf(b) << 16);
}
// async global->LDS, 16B per lane, dest = wave-uniform base + lane*16
__device__ __forceinline__ void gl16(const ushort_t* g, ushort_t* l) {
    __builtin_amdgcn_global_load_lds(
        (const __attribute__((address_space(1))) void*)(g),
        (__attribute__((address_space(3))) void*)(l), 16, 0, 0);
}

// ---------------------------------------------------------------------------
// Merged weight prep: all fp32->bf16 weight conversions in one dispatch.
// ---------------------------------------------------------------------------
__device__ __forceinline__ void wconv_body(const float* __restrict__ W,
                                           ushort_t* __restrict__ Wb, int idx) {
    const float* wp = W + (size_t)idx * 27;              // idx = co*384+ci
#pragma unroll
    for (int tap = 0; tap < 27; ++tap)
        Wb[(size_t)tap * (CDIM * CDIM) + idx] = f2bf(wp[tap]);
}
__device__ __forceinline__ void cvt_body(const float* __restrict__ src,
                                         ushort_t* __restrict__ dst, int i) {
    float4 v = ((const float4*)src)[i];
    uint2 o; o.x = pk2(v.x, v.y); o.y = pk2(v.z, v.w);
    ((uint2*)dst)[i] = o;
}
__global__ __launch_bounds__(256)
void prep_weights_kernel(const float* w1, const float* w2, const float* w3,
                         const float* w4, const float* ipw, const float* opw,
                         const float* xpw,
                         ushort_t* Wb1, ushort_t* Wb2, ushort_t* w3b, ushort_t* w4b,
                         ushort_t* ipwb, ushort_t* opwb, ushort_t* xpwb) {
    const int bid = blockIdx.x, t = threadIdx.x;
    if      (bid < 576)  wconv_body(w1, Wb1, bid * 256 + t);
    else if (bid < 1152) wconv_body(w2, Wb2, (bid - 576) * 256 + t);
    else if (bid < 1296) cvt_body(w3, w3b, (bid - 1152) * 256 + t);
    else if (bid < 1440) cvt_body(w4, w4b, (bid - 1296) * 256 + t);
    else if (bid < 2016) cvt_body(ipw, ipwb, (bid - 1440) * 256 + t);
    else if (bid < 2304) cvt_body(opw, opwb, (bid - 2016) * 256 + t);
    else                 cvt_body(xpw, xpwb, (bid - 2304) * 256 + t);
}

// ---------------------------------------------------------------------------
// Pad + transpose to channels-last bf16: src[b][c][16^3] -> Xp[b][18][18][18][384]
// ---------------------------------------------------------------------------
__global__ __launch_bounds__(384)
void pad_kernel(const float* __restrict__ src, ushort_t* __restrict__ Xp) {
    const int blk = blockIdx.x;                          // b(4) d(16) h(16)
    const int b = blk >> 8, d = (blk >> 4) & 15, h = blk & 15;
    const int ci = threadIdx.x;
    const float* sp = src + (size_t)(b * CDIM + ci) * SDIM + d * 256 + h * 16;
    ushort_t* dp = Xp + ((((size_t)(b * 18 + d + 1) * 18) + (h + 1)) * 18 + 1) * CDIM + ci;
#pragma unroll
    for (int w = 0; w < 16; ++w)
        dp[(size_t)w * CDIM] = f2bf(sp[w]);
}

// ---------------------------------------------------------------------------
// Fused: v = relu((P0+P1 - m)*r) -> pad/transpose channels-last bf16 Xp.
// ---------------------------------------------------------------------------
__global__ __launch_bounds__(384)
void pad_fuse2_kernel(const ushort_t* __restrict__ P0, const ushort_t* __restrict__ P1,
                      const float* __restrict__ stats, ushort_t* __restrict__ Xp) {
    const int blk = blockIdx.x;
    const int b = blk >> 8, d = (blk >> 4) & 15, h = blk & 15;
    const int ci = threadIdx.x;
    const size_t o = (size_t)(b * CDIM + ci) * SDIM + d * 256 + h * 16;
    const float m = stats[(b * CDIM + ci) * 2], r = stats[(b * CDIM + ci) * 2 + 1];
    union { uint4 q[2]; ushort_t u[16]; } a, c;
    a.q[0] = ((const uint4*)(P0 + o))[0]; a.q[1] = ((const uint4*)(P0 + o))[1];
    c.q[0] = ((const uint4*)(P1 + o))[0]; c.q[1] = ((const uint4*)(P1 + o))[1];
    ushort_t* dp = Xp + ((((size_t)(b * 18 + d + 1) * 18) + (h + 1)) * 18 + 1) * CDIM + ci;
#pragma unroll
    for (int w = 0; w < 16; ++w) {
        const float v = bf2f(a.u[w]) + bf2f(c.u[w]);
        dp[(size_t)w * CDIM] = f2bf(fmaxf((v - m) * r, 0.f));
    }
}

// ---------------------------------------------------------------------------
// Fused: S = relu((P0+P1-m2)*r2) + relu((C3-m3)*r3) -> pad channels-last bf16.
// ---------------------------------------------------------------------------
__global__ __launch_bounds__(384)
void pad_fuse3_kernel(const ushort_t* __restrict__ P0, const ushort_t* __restrict__ P1,
                      const float* __restrict__ st2, const ushort_t* __restrict__ C3,
                      const float* __restrict__ st3, ushort_t* __restrict__ Xp) {
    const int blk = blockIdx.x;
    const int b = blk >> 8, d = (blk >> 4) & 15, h = blk & 15;
    const int ci = threadIdx.x;
    const size_t o = (size_t)(b * CDIM + ci) * SDIM + d * 256 + h * 16;
    const float m2 = st2[(b * CDIM + ci) * 2], r2 = st2[(b * CDIM + ci) * 2 + 1];
    const float m3 = st3[(b * CDIM + ci) * 2], r3 = st3[(b * CDIM + ci) * 2 + 1];
    union { uint4 q[2]; ushort_t u[16]; } a, c, e;
    a.q[0] = ((const uint4*)(P0 + o))[0]; a.q[1] = ((const uint4*)(P0 + o))[1];
    c.q[0] = ((const uint4*)(P1 + o))[0]; c.q[1] = ((const uint4*)(P1 + o))[1];
    e.q[0] = ((const uint4*)(C3 + o))[0]; e.q[1] = ((const uint4*)(C3 + o))[1];
    ushort_t* dp = Xp + ((((size_t)(b * 18 + d + 1) * 18) + (h + 1)) * 18 + 1) * CDIM + ci;
#pragma unroll
    for (int w = 0; w < 16; ++w) {
        const float x1 = fmaxf((bf2f(a.u[w]) + bf2f(c.u[w]) - m2) * r2, 0.f);
        const float x2 = fmaxf((bf2f(e.u[w]) - m3) * r3, 0.f);
        dp[(size_t)w * CDIM] = f2bf(x1 + x2);
    }
}

// ---------------------------------------------------------------------------
// Implicit-GEMM conv via MFMA bf16, global_load_lds + 2-phase prefetch
// (T3-lite): stage tile t+1 into buf^1, compute tile t from buf, ONE
// __syncthreads per iter (drains own-wave vmcnt; load latency hides under
// the 16 MFMAs). LDS 2x(8+8)KB = 32KB. bf16 outputs.
// MODE 0: c2 (z in {0,1} tap-split -> Y01+z*PSTRIDE)
// MODE 1: c1 (z in {0,1}) + c3 1x1 fused as z==2 (W3 -> Y2)
// MODE 2: pure 1x1 (c4 -> Y2)
// ---------------------------------------------------------------------------
template<int MODE>
__global__ __launch_bounds__(256)
void conv_kernel(const ushort_t* __restrict__ Xp, const ushort_t* __restrict__ Wb,
                 const ushort_t* __restrict__ W3, ushort_t* __restrict__ Y01,
                 ushort_t* __restrict__ Y2) {
    const int wid = blockIdx.x;
    const int ntid = wid & 127;                          // nt innermost
    const int rest = wid >> 7;
    const int co0 = (rest % 3) * 128;
    const int zz  = rest / 3;
    const int b  = ntid >> 5;
    const int d  = (ntid >> 1) & 15;
    const int h0 = (ntid & 1) * 8;
    const int t = threadIdx.x;
    const int lane = t & 63;
    const int wv = t >> 6;
    const int wy = wv >> 1, wx = wv & 1;

    const bool is1x1 = (MODE == 2) || (MODE == 1 && zz == 2);
    const ushort_t* Wsrc; int tap0, iters, kd0, kh0, kw0; ushort_t* Y;
    if (is1x1) {
        Wsrc = W3; tap0 = 0; iters = 12; kd0 = 1; kh0 = 1; kw0 = 1; Y = Y2;
    } else {
        Wsrc = Wb; tap0 = zz ? 14 : 0; iters = (zz ? 13 : 14) * 12;
        kd0 = zz ? 1 : 0; kh0 = zz ? 1 : 0; kw0 = zz ? 2 : 0;
        Y = Y01 + (size_t)zz * PSTRIDE;
    }

    __shared__ __align__(16) ushort_t As[2][4096];       // [128][32] bf16 x2
    __shared__ __align__(16) ushort_t Bs[2][4096];

    f32x4 acc[4][4];
#pragma unroll
    for (int i = 0; i < 4; ++i)
#pragma unroll
        for (int j = 0; j < 4; ++j) acc[i][j] = (f32x4){0.f, 0.f, 0.f, 0.f};

    const int l4 = lane >> 2;
    const int cg = (((lane & 3) ^ ((lane >> 3) & 3)) << 3);
    int aTC[2], bTC[2];
#pragma unroll
    for (int i = 0; i < 2; ++i) {
        const int r = wv * 32 + i * 16 + l4;
        aTC[i] = (co0 + r) * CDIM + cg;
        bTC[i] = ((r >> 4) * 18 + (r & 15)) * CDIM + cg;
    }

    int aoff = tap0 * (CDIM * CDIM);
    int goff = (((b * 18 + d + kd0) * 18 + (h0 + kh0)) * 18 + kw0) * CDIM;
    int c12 = 0, ckw = kw0, ckh = kh0;

    const int lm = lane & 15;
    const int sw8 = (((lane >> 4) ^ ((lm >> 1) & 3)) << 3);
    const int rA0 = (wy * 64 + lm) * 32 + sw8;
    const int rB0 = (wx * 64 + lm) * 32 + sw8;

    auto stage = [&](int bf) {                           // issue 4 gl_lds + walk
        ushort_t* la = &As[bf][wv * 1024];
        ushort_t* lb = &Bs[bf][wv * 1024];
        gl16(Wsrc + aoff + aTC[0], la);
        gl16(Wsrc + aoff + aTC[1], la + 512);
        gl16(Xp + goff + bTC[0], lb);
        gl16(Xp + goff + bTC[1], lb + 512);
        aoff += 32; goff += 32;
        if (++c12 == 12) {                               // tap wrap
            c12 = 0;
            aoff += CDIM * CDIM - CDIM;
            if (++ckw == 3) {
                ckw = 0;
                if (++ckh == 3) { ckh = 0; goff += 109440; }
                else goff += 5760;
            }
        }
    };

    stage(0);
    __syncthreads();                                     // buf0 ready

    int buf = 0;
    for (int idx = 0; idx < iters; ++idx) {
        if (idx + 1 < iters) stage(buf ^ 1);             // prefetch next tile
        bf16x8 af[4], bfr[4];
#pragma unroll
        for (int mi = 0; mi < 4; ++mi)
            af[mi] = *reinterpret_cast<const bf16x8*>(&As[buf][rA0 + mi * 512]);
#pragma unroll
        for (int ni = 0; ni < 4; ++ni)
            bfr[ni] = *reinterpret_cast<const bf16x8*>(&Bs[buf][rB0 + ni * 512]);
#pragma unroll
        for (int mi = 0; mi < 4; ++mi)
#pragma unroll
            for (int ni = 0; ni < 4; ++ni)
                acc[mi][ni] = __builtin_amdgcn_mfma_f32_16x16x32_bf16(
                    af[mi], bfr[ni], acc[mi][ni], 0, 0, 0);
        __syncthreads();                                 // reads done + prefetch landed
        buf ^= 1;
    }

    // epilogue: C/D layout col(lane&15)=sp, row=(lane>>4)*4+j=co; bf16 store
    const int coB = co0 + wy * 64 + (lane >> 4) * 4;
    const int nB  = wx * 64 + lm;
#pragma unroll
    for (int mi = 0; mi < 4; ++mi) {
#pragma unroll
        for (int ni = 0; ni < 4; ++ni) {
            const int nl = nB + ni * 16;
            const int s = d * 256 + (h0 + (nl >> 4)) * 16 + (nl & 15);
            ushort_t* yp = Y + ((size_t)b * CDIM + (coB + mi * 16)) * SDIM + s;
#pragma unroll
            for (int j = 0; j < 4; ++j)
                yp[(size_t)j * SDIM] = f2bf(acc[mi][ni][j]);
        }
    }
}

// ---------------------------------------------------------------------------
// bf16 MFMA GEMM NT with gl_lds + 2-phase prefetch (same structure as conv).
// C[M,N] = A[M,K] x B[N,K]^T. N masked via address clamp + store mask.
// EPI 0: fp32 store (ldc); 1: xz split -> bf16 C/C2 (N=1536);
// 2: transposed fp32 float4 store C[b][n][l].
// ---------------------------------------------------------------------------
template<int EPI>
__global__ __launch_bounds__(256)
void gemm_gl_kernel(const ushort_t* __restrict__ A, const ushort_t* __restrict__ Bw,
                    void* __restrict__ Cv, void* __restrict__ C2v,
                    int M, int N, int K, int ldc, int nx) {
    const int wid = blockIdx.x;
    const int n0 = (wid % nx) * 128;
    const int m0 = (wid / nx) * 128;
    const int t = threadIdx.x;
    const int lane = t & 63;
    const int wv = t >> 6;
    const int wy = wv >> 1, wx = wv & 1;

    __shared__ __align__(16) ushort_t As[2][4096];
    __shared__ __align__(16) ushort_t Bs[2][4096];

    f32x4 acc[4][4];
#pragma unroll
    for (int i = 0; i < 4; ++i)
#pragma unroll
        for (int j = 0; j < 4; ++j) acc[i][j] = (f32x4){0.f, 0.f, 0.f, 0.f};

    const int l4 = lane >> 2;
    const int cg = (((lane & 3) ^ ((lane >> 3) & 3)) << 3);
    size_t aTC[2], bTC[2];
#pragma unroll
    for (int i = 0; i < 2; ++i) {
        const int r = wv * 32 + i * 16 + l4;
        aTC[i] = (size_t)(m0 + r) * K + cg;
        int br = n0 + r; if (br >= N) br = N - 1;        // clamp (masked at store)
        bTC[i] = (size_t)br * K + cg;
    }

    const int lm = lane & 15;
    const int sw8 = (((lane >> 4) ^ ((lm >> 1) & 3)) << 3);
    const int rA0 = (wy * 64 + lm) * 32 + sw8;
    const int rB0 = (wx * 64 + lm) * 32 + sw8;

    auto stage = [&](int bf, int ko) {
        ushort_t* la = &As[bf][wv * 1024];
        ushort_t* lb = &Bs[bf][wv * 1024];
        gl16(A + aTC[0] + ko, la);
        gl16(A + aTC[1] + ko, la + 512);
        gl16(Bw + bTC[0] + ko, lb);
        gl16(Bw + bTC[1] + ko, lb + 512);
    };

    const int KI = K >> 5;
    stage(0, 0);
    __syncthreads();

    int buf = 0;
    for (int kk = 0; kk < KI; ++kk) {
        if (kk + 1 < KI) stage(buf ^ 1, (kk + 1) * 32);
        bf16x8 af[4], bfr[4];
#pragma unroll
        for (int mi = 0; mi < 4; ++mi)
            af[mi] = *reinterpret_cast<const bf16x8*>(&As[buf][rA0 + mi * 512]);
#pragma unroll
        for (int ni = 0; ni < 4; ++ni)
            bfr[ni] = *reinterpret_cast<const bf16x8*>(&Bs[buf][rB0 + ni * 512]);
#pragma unroll
        for (int mi = 0; mi < 4; ++mi)
#pragma unroll
            for (int ni = 0; ni < 4; ++ni)
                acc[mi][ni] = __builtin_amdgcn_mfma_f32_16x16x32_bf16(
                    af[mi], bfr[ni], acc[mi][ni], 0, 0, 0);
        __syncthreads();
        buf ^= 1;
    }

    const int mB = m0 + wy * 64 + (lane >> 4) * 4;
    const int nB = n0 + wx * 64 + lm;
#pragma unroll
    for (int mi = 0; mi < 4; ++mi) {
#pragma unroll
        for (int ni = 0; ni < 4; ++ni) {
            const int n = nB + ni * 16;
            if (EPI == 2) {                              // transposed float4
                const int mrow = mB + mi * 16;
                const int bb = mrow >> 12, l = mrow & 4095;
                float4 st = {acc[mi][ni][0], acc[mi][ni][1],
                             acc[mi][ni][2], acc[mi][ni][3]};
                *reinterpret_cast<float4*>(
                    (float*)Cv + ((size_t)(bb * CDIM + n)) * SDIM + l) = st;
            } else {
#pragma unroll
                for (int j = 0; j < 4; ++j) {
                    const int m = mB + mi * 16 + j;
                    const float v = acc[mi][ni][j];
                    if (EPI == 0) {
                        if (n < N) ((float*)Cv)[(size_t)m * ldc + n] = v;
                    } else {                             // xz split, bf16 out
                        if (n < DINC) ((ushort_t*)Cv)[(size_t)m * DINC + n] = f2bf(v);
                        else ((ushort_t*)C2v)[(size_t)m * DINC + (n - DINC)] = f2bf(v);
                    }
                }
            }
        }
    }
}

// ---------------------------------------------------------------------------
// Reduction helper for instance-norm stats.
// ---------------------------------------------------------------------------
__device__ __forceinline__ void stats_reduce(float s, float ss, float* out) {
#pragma unroll
    for (int off = 32; off > 0; off >>= 1) {
        s += __shfl_down(s, off);
        ss += __shfl_down(ss, off);
    }
    __shared__ float rs[4], rss[4];
    const int wid = threadIdx.x >> 6;
    if ((threadIdx.x & 63) == 0) { rs[wid] = s; rss[wid] = ss; }
    __syncthreads();
    if (threadIdx.x == 0) {
        float S = rs[0] + rs[1] + rs[2] + rs[3];
        float SS = rss[0] + rss[1] + rss[2] + rss[3];
        float m = S * (1.f / SDIM);
        float var = SS * (1.f / SDIM) - m * m;
        out[0] = m;
        out[1] = rsqrtf(var + 1e-5f);
    }
}

// ---------------------------------------------------------------------------
// Combo stats (bf16 inputs): bc<1536 -> stats of (P0+P1) into SA;
// bc>=1536 -> stats of X3 into SB (only when grid > 1536).
// ---------------------------------------------------------------------------
__global__ __launch_bounds__(256)
void inorm_stats_combo_kernel(const ushort_t* __restrict__ P0,
                              const ushort_t* __restrict__ P1,
                              float* __restrict__ SA,
                              const ushort_t* __restrict__ X3,
                              float* __restrict__ SB) {
    const int bid = blockIdx.x;
    float s = 0.f, ss = 0.f;
    if (bid < 1536) {
        const ushort_t* p0 = P0 + (size_t)bid * SDIM;
        const ushort_t* p1 = P1 + (size_t)bid * SDIM;
        for (int i = threadIdx.x * 8; i < SDIM; i += 2048) {
            union { uint4 q; ushort_t u[8]; } a, c;
            a.q = *(const uint4*)(p0 + i);
            c.q = *(const uint4*)(p1 + i);
#pragma unroll
            for (int j = 0; j < 8; ++j) {
                const float v = bf2f(a.u[j]) + bf2f(c.u[j]);
                s += v; ss += v * v;
            }
        }
        stats_reduce(s, ss, SA + bid * 2);
    } else {
        const int bc = bid - 1536;
        const ushort_t* xp = X3 + (size_t)bc * SDIM;
        for (int i = threadIdx.x * 8; i < SDIM; i += 2048) {
            union { uint4 q; ushort_t u[8]; } a;
            a.q = *(const uint4*)(xp + i);
#pragma unroll
            for (int j = 0; j < 8; ++j) {
                const float v = bf2f(a.u[j]);
                s += v; ss += v * v;
            }
        }
        stats_reduce(s, ss, SB + bc * 2);
    }
}

// ---------------------------------------------------------------------------
// InstanceNorm stats, single bf16 input.
// ---------------------------------------------------------------------------
__global__ __launch_bounds__(256)
void inorm_stats_kernel(const ushort_t* __restrict__ X, float* __restrict__ stats) {
    const int bc = blockIdx.x;
    const ushort_t* xp = X + (size_t)bc * SDIM;
    float s = 0.f, ss = 0.f;
    for (int i = threadIdx.x * 8; i < SDIM; i += 2048) {
        union { uint4 q; ushort_t u[8]; } a;
        a.q = *(const uint4*)(xp + i);
#pragma unroll
        for (int j = 0; j < 8; ++j) {
            const float v = bf2f(a.u[j]);
            s += v; ss += v * v;
        }
    }
    stats_reduce(s, ss, stats + bc * 2);
}

// ---------------------------------------------------------------------------
// Fused LayerNorm, coalesced (round-10 proven): wave handles 8 tokens,
// butterfly reduce, LDS-staged coalesced output.
// ---------------------------------------------------------------------------
__global__ __launch_bounds__(256)
void layernorm_kernel(const ushort_t* __restrict__ C4, const float* __restrict__ stats,
                      const float* __restrict__ X, const float* __restrict__ gam,
                      const float* __restrict__ bet, ushort_t* __restrict__ Tn) {
    const int blk = blockIdx.x;
    const int b = blk >> 7;
    const int tile0 = (blk & 127) * 32;
    const int wv = threadIdx.x >> 6;
    const int lane = threadIdx.x & 63;
    const int l0 = tile0 + wv * 8;

    __shared__ ushort_t tile[32 * 384];

    float v[6][8];
    float s[8], ss[8];
#pragma unroll
    for (int t = 0; t < 8; ++t) { s[t] = 0.f; ss[t] = 0.f; }
    float g[6], be[6];

#pragma unroll
    for (int i = 0; i < 6; ++i) {
        const int c = lane + i * 64;
        g[i] = gam[c]; be[i] = bet[c];
        const size_t base = (size_t)(b * CDIM + c) * SDIM + l0;
        union { uint4 q; ushort_t u[8]; } cv;
        cv.q = *(const uint4*)(C4 + base);
        const float4 x0 = *(const float4*)(X + base);
        const float4 x1 = *(const float4*)(X + base + 4);
        const float xs[8] = {x0.x, x0.y, x0.z, x0.w, x1.x, x1.y, x1.z, x1.w};
        const float m = stats[(b * CDIM + c) * 2];
        const float r = stats[(b * CDIM + c) * 2 + 1];
#pragma unroll
        for (int t = 0; t < 8; ++t) {
            const float val = fmaxf((bf2f(cv.u[t]) - m) * r, 0.f) + xs[t];
            v[i][t] = val;
            s[t] += val; ss[t] += val * val;
        }
    }
#pragma unroll
    for (int off = 32; off > 0; off >>= 1) {
#pragma unroll
        for (int t = 0; t < 8; ++t) {
            s[t] += __shfl_xor(s[t], off);
            ss[t] += __shfl_xor(ss[t], off);
        }
    }
#pragma unroll
    for (int t = 0; t < 8; ++t) {
        const float mean = s[t] * (1.f / CDIM);
        const float rstd = rsqrtf(ss[t] * (1.f / CDIM) - mean * mean + 1e-5f);
        const int trow = (wv * 8 + t) * 384;
#pragma unroll
        for (int i = 0; i < 6; ++i) {
            const int c = lane + i * 64;
            tile[trow + c] = f2bf((v[i][t] - mean) * rstd * g[i] + be[i]);
        }
    }
    __syncthreads();
    uint4* dst = (uint4*)(Tn + ((size_t)b * 4096 + tile0) * CDIM);
    const uint4* srcp = (const uint4*)tile;
#pragma unroll
    for (int k = 0; k < 6; ++k)
        dst[k * 256 + threadIdx.x] = srcp[k * 256 + threadIdx.x];
}

// ---------------------------------------------------------------------------
// Tiled fp32 GEMM for dt_proj (K=24), NT, bias+softplus, bf16 store.
// ---------------------------------------------------------------------------
__global__ __launch_bounds__(256)
void gemm_dtproj_kernel(const float* __restrict__ A, const float* __restrict__ B,
                        ushort_t* __restrict__ C, const float* __restrict__ bias,
                        int M, int N, int K, int lda, int ldb, int ldc) {
    __shared__ __align__(16) float As[16][132];
    __shared__ __align__(16) float Bs[16][68];
    const int t = threadIdx.x;
    const int m0 = blockIdx.y * 128;
    const int n0 = blockIdx.x * 64;

    float acc[8][4];
#pragma unroll
    for (int i = 0; i < 8; ++i)
#pragma unroll
        for (int j = 0; j < 4; ++j) acc[i][j] = 0.f;

    const int mr = (t & 15) * 8;
    const int nr = (t >> 4) * 4;

    for (int k0 = 0; k0 < K; k0 += 16) {
#pragma unroll
        for (int idx = 0; idx < 8; ++idx) {
            const int e = idx * 256 + t;
            const int k = e & 15, m = e >> 4;
            float v = 0.f;
            if (k0 + k < K) v = A[(size_t)(m0 + m) * lda + (k0 + k)];
            As[k][m] = v;
        }
#pragma unroll
        for (int idx = 0; idx < 4; ++idx) {
            const int e = idx * 256 + t;
            const int k = e & 15, n = e >> 4;
            float v = 0.f;
            if ((n0 + n) < N && (k0 + k) < K) v = B[(size_t)(n0 + n) * ldb + (k0 + k)];
            Bs[k][n] = v;
        }
        __syncthreads();
#pragma unroll
        for (int k = 0; k < 16; ++k) {
            float4 a0 = *(const float4*)&As[k][mr];
            float4 a1 = *(const float4*)&As[k][mr + 4];
            float4 b0 = *(const float4*)&Bs[k][nr];
            const float av[8] = {a0.x, a0.y, a0.z, a0.w, a1.x, a1.y, a1.z, a1.w};
            const float bv[4] = {b0.x, b0.y, b0.z, b0.w};
#pragma unroll
            for (int i = 0; i < 8; ++i)
#pragma unroll
                for (int j = 0; j < 4; ++j)
                    acc[i][j] = fmaf(av[i], bv[j], acc[i][j]);
        }
        __syncthreads();
    }

#pragma unroll
    for (int i = 0; i < 8; ++i) {
        const int m = m0 + mr + i;
#pragma unroll
        for (int j = 0; j < 4; ++j) {
            const int n = n0 + nr + j;
            if (n >= N) continue;
            float v = acc[i][j] + bias[n];
            v = (v > 20.f) ? v : log1pf(__expf(v));
            C[(size_t)m * ldc + n] = f2bf(v);
        }
    }
}

// ---------------------------------------------------------------------------
// Causal depthwise conv1d (K=4) + bias + SiLU, bf16 in/out. 4 tokens/thread.
// ---------------------------------------------------------------------------
__global__ __launch_bounds__(256)
void dwconv_silu_kernel(const ushort_t* __restrict__ Xin, const float* __restrict__ W,
                        const float* __restrict__ bias, ushort_t* __restrict__ U) {
    const int dch = blockIdx.x * 256 + threadIdx.x;
    const int l0 = blockIdx.y * 4, b = blockIdx.z;
    const float4 w4 = ((const float4*)W)[dch];
    const float wk[4] = {w4.x, w4.y, w4.z, w4.w};
    const float bs = bias[dch];
    const size_t base = ((size_t)b * 4096 + l0) * DINC + dch;
    float r[7];
#pragma unroll
    for (int k = 0; k < 7; ++k) {
        const int ll = l0 - 3 + k;
        r[k] = (ll >= 0) ? bf2f(Xin[base + (size_t)(k - 3) * DINC]) : 0.f;
    }
#pragma unroll
    for (int j = 0; j < 4; ++j) {
        float acc = bs;
#pragma unroll
        for (int k = 0; k < 4; ++k) acc = fmaf(r[j + k], wk[k], acc);
        U[base + (size_t)j * DINC] = f2bf(acc / (1.f + __expf(-acc)));
    }
}

// ---------------------------------------------------------------------------
// Chunked parallel selective scan (3 phases). dt/u/z/y bf16; B,C fp32.
// ---------------------------------------------------------------------------
__global__ __launch_bounds__(256)
void scan_phase1_kernel(const ushort_t* __restrict__ DT, const ushort_t* __restrict__ U,
                        const float* __restrict__ DBL, const float* __restrict__ A_log,
                        float* __restrict__ HOUT, float* __restrict__ SDT) {
    const int b = blockIdx.z, chunk = blockIdx.y;
    const int dch = blockIdx.x * 256 + threadIdx.x;
    float Arow[16];
#pragma unroll
    for (int n = 0; n < NST; ++n) Arow[n] = -__expf(A_log[dch * NST + n]);

    __shared__ float bcs[LCHUNK][16];
    const size_t tokbase = (size_t)b * 4096 + chunk * LCHUNK;
#pragma unroll
    for (int idx = 0; idx < 4; ++idx) {
        const int e = idx * 256 + threadIdx.x;
        bcs[e >> 4][e & 15] = DBL[(tokbase + (e >> 4)) * 56 + 24 + (e & 15)];
    }
    __syncthreads();

    size_t off = tokbase * DINC + dch;
    float h[16];
#pragma unroll
    for (int n = 0; n < NST; ++n) h[n] = 0.f;
    float sdt = 0.f;
    float cdt = bf2f(DT[off]), cu = bf2f(U[off]);
    for (int t = 0; t < LCHUNK; ++t) {
        float ndt = 0.f, nu = 0.f;
        if (t < LCHUNK - 1) { ndt = bf2f(DT[off + DINC]); nu = bf2f(U[off + DINC]); }
        sdt += cdt;
        const float du = cdt * cu;
#pragma unroll
        for (int n = 0; n < NST; ++n)
            h[n] = __expf(cdt * Arow[n]) * h[n] + du * bcs[t][n];
        off += DINC;
        cdt = ndt; cu = nu;
    }
    float* hp = HOUT + (((size_t)(b * DINC + dch) * NCHUNK + chunk) << 4);
#pragma unroll
    for (int n = 0; n < NST; ++n) hp[n] = h[n];
    SDT[(size_t)(b * DINC + dch) * NCHUNK + chunk] = sdt;
}

__global__ __launch_bounds__(256)
void scan_phase2_kernel(float* __restrict__ HOUT, const float* __restrict__ SDT,
                        const float* __restrict__ A_log) {
    const int t = blockIdx.x * 256 + threadIdx.x;        // 49152
    const int b = t / (DINC * NST);
    const int rem = t - b * (DINC * NST);
    const int d = rem >> 4, n = rem & 15;
    const float An = -__expf(A_log[d * NST + n]);
    float* hp = HOUT + (((size_t)(b * DINC + d) * NCHUNK) << 4) + n;
    const float* sp = SDT + (size_t)(b * DINC + d) * NCHUNK;
    float H = 0.f;
    for (int c = 0; c < NCHUNK; ++c) {
        const float tmp = hp[c * 16];
        const float dA = __expf(An * sp[c]);
        hp[c * 16] = H;
        H = dA * H + tmp;
    }
}

__global__ __launch_bounds__(256)
void scan_phase3_kernel(ushort_t* __restrict__ DT, const ushort_t* __restrict__ U,
                        const float* __restrict__ DBL, const ushort_t* __restrict__ Z,
                        const float* __restrict__ A_log, const float* __restrict__ D_skip,
                        const float* __restrict__ HOUT) {
    const int b = blockIdx.z, chunk = blockIdx.y;
    const int dch = blockIdx.x * 256 + threadIdx.x;
    float Arow[16];
#pragma unroll
    for (int n = 0; n < NST; ++n) Arow[n] = -__expf(A_log[dch * NST + n]);
    const float Dsk = D_skip[dch];

    __shared__ float bcs[LCHUNK][32];
    const size_t tokbase = (size_t)b * 4096 + chunk * LCHUNK;
#pragma unroll
    for (int idx = 0; idx < 8; ++idx) {
        const int e = idx * 256 + threadIdx.x;
        bcs[e >> 5][e & 31] = DBL[(tokbase + (e >> 5)) * 56 + 24 + (e & 31)];
    }
    __syncthreads();

    float h[16];
    const float* hp = HOUT + (((size_t)(b * DINC + dch) * NCHUNK + chunk) << 4);
#pragma unroll
    for (int n = 0; n < NST; ++n) h[n] = hp[n];

    size_t off = tokbase * DINC + dch;
    float cdt = bf2f(DT[off]), cu = bf2f(U[off]), cz = bf2f(Z[off]);
    for (int t = 0; t < LCHUNK; ++t) {
        float ndt = 0.f, nu = 0.f, nz = 0.f;
        if (t < LCHUNK - 1) {
            ndt = bf2f(DT[off + DINC]); nu = bf2f(U[off + DINC]); nz = bf2f(Z[off + DINC]);
        }
        const float du = cdt * cu;
        float y = 0.f;
#pragma unroll
        for (int n = 0; n < NST; ++n) {
            h[n] = __expf(cdt * Arow[n]) * h[n] + du * bcs[t][n];
            y = fmaf(h[n], bcs[t][16 + n], y);
        }
        y += cu * Dsk;
        const float sz = cz / (1.f + __expf(-cz));
        DT[off] = f2bf(y * sz);
        off += DINC;
        cdt = ndt; cu = nu; cz = nz;
    }
}

// ---------------------------------------------------------------------------
extern "C" void kernel_launch(void* const* d_in, const int* in_sizes, int n_in,
                              void* d_out, int out_size, void* d_ws, size_t ws_size,
                              hipStream_t stream) {
    (void)in_sizes; (void)n_in; (void)out_size; (void)ws_size;
    const float* x         = (const float*)d_in[0];
    const float* w1        = (const float*)d_in[1];
    const float* w2        = (const float*)d_in[3];
    const float* w3        = (const float*)d_in[5];
    const float* w4        = (const float*)d_in[7];
    const float* ln_g      = (const float*)d_in[9];
    const float* ln_b      = (const float*)d_in[10];
    const float* in_proj_w = (const float*)d_in[11];
    const float* conv1d_w  = (const float*)d_in[12];
    const float* conv1d_b  = (const float*)d_in[13];
    const float* x_proj_w  = (const float*)d_in[14];
    const float* dt_proj_w = (const float*)d_in[15];
    const float* dt_proj_b = (const float*)d_in[16];
    const float* A_log     = (const float*)d_in[17];
    const float* D_skip    = (const float*)d_in[18];
    const float* out_proj_w= (const float*)d_in[19];
    float* out = (float*)d_out;

    // Workspace regions (floats): R0..R4. Lifetimes disjoint where aliased.
    float* ws = (float*)d_ws;
    float* R0 = ws;                    //  6291456
    float* R1 = ws + 6291456;          //  6291456
    float* R2 = ws + 12582912;         // 12582912
    float* R3 = ws + 25165824;         // 12582912
    float* R4 = ws + 37748736;         // 12582912

    // GSC-phase aliases (conv partials/outputs bf16)
    ushort_t* P0    = (ushort_t*)R0;                 // partial z=0
    ushort_t* P1    = P0 + PSTRIDE;                  // partial z=1
    ushort_t* C34   = (ushort_t*)R3;                 // c3/c4 outputs bf16
    ushort_t* Wb1   = (ushort_t*)R2;                 // 3981312 bf16
    ushort_t* Xp    = (ushort_t*)(R2 + 2097152);     // 8957952 bf16
    ushort_t* w3b   = (ushort_t*)(R2 + 6576128);     // 147456 bf16
    ushort_t* w4b   = (ushort_t*)(R2 + 6649856);     // 147456 bf16
    ushort_t* Wb2   = (ushort_t*)(R2 + 6723584);     // 3981312 bf16
    float*    SA    = R4;                            // stats A
    float*    SB    = R4 + 4096;                     // stats B
    ushort_t* ipwb  = (ushort_t*)(R4 + 6291456);
    ushort_t* opwb  = (ushort_t*)(R4 + 6586368);
    ushort_t* xpwb  = (ushort_t*)(R4 + 6733824);
    // Mamba-phase aliases
    ushort_t* tnb   = (ushort_t*)R0;                 // 16384*384 bf16
    float*    DBL   = R0 + 3145728;                  // 16384*56 fp32
    float*    HOUT  = R1;
    float*    SDT   = R1 + 3145728;
    ushort_t* XIN   = (ushort_t*)R2;
    ushort_t* Zb    = (ushort_t*)R3;
    ushort_t* Ub    = (ushort_t*)R4;
    ushort_t* DTb   = (ushort_t*)R2;

    const size_t XP_BYTES = (size_t)4 * 18 * 18 * 18 * CDIM * 2;

    // ---- upfront: zero pad borders, convert all weights, pad x ----
    hipMemsetAsync(Xp, 0, XP_BYTES, stream);
    prep_weights_kernel<<<2346, 256, 0, stream>>>(
        w1, w2, w3, w4, in_proj_w, out_proj_w, x_proj_w,
        Wb1, Wb2, w3b, w4b, ipwb, opwb, xpwb);
    pad_kernel<<<1024, 384, 0, stream>>>(x, Xp);
    // ---- c1 (3x3x3 z-split) + c3 (1x1) fused ----
    conv_kernel<1><<<1152, 256, 0, stream>>>(Xp, Wb1, w3b, P0, C34);
    inorm_stats_combo_kernel<<<3072, 256, 0, stream>>>(P0, P1, SA, C34, SB);
    pad_fuse2_kernel<<<1024, 384, 0, stream>>>(P0, P1, SA, Xp);             // x1a
    // ---- c2 ----
    conv_kernel<0><<<768, 256, 0, stream>>>(Xp, Wb2, nullptr, P0, nullptr);
    inorm_stats_combo_kernel<<<1536, 256, 0, stream>>>(P0, P1, SA, nullptr, nullptr);
    pad_fuse3_kernel<<<1024, 384, 0, stream>>>(P0, P1, SA, C34, SB, Xp);    // S
    // ---- c4 (1x1) ----
    conv_kernel<2><<<384, 256, 0, stream>>>(Xp, nullptr, w4b, nullptr, C34);
    inorm_stats_kernel<<<1536, 256, 0, stream>>>(C34, SA);
    // ---- fused relu(IN(c4)) + x residual + LayerNorm -> tn bf16 [b][l][c]
    layernorm_kernel<<<512, 256, 0, stream>>>(C34, SA, x, ln_g, ln_b, tnb);
    // ---- in_proj (bf16 MFMA, gl_lds+prefetch): tn x W^T -> XIN | Zb (bf16)
    gemm_gl_kernel<1><<<1536, 256, 0, stream>>>(
        tnb, ipwb, XIN, Zb, 16384, 1536, CDIM, 0, 12);
    // ---- causal depthwise conv + SiLU -> Ub (bf16)
    dwconv_silu_kernel<<<dim3(3, 1024, 4), 256, 0, stream>>>(XIN, conv1d_w, conv1d_b, Ub);
    // ---- x_proj (bf16 MFMA, N=56 masked): u x W^T -> DBL (fp32)
    gemm_gl_kernel<0><<<128, 256, 0, stream>>>(
        Ub, xpwb, DBL, nullptr, 16384, 56, DINC, 56, 1);
    // ---- dt_proj (fp32 VALU, K=24) + bias + softplus -> DTb (bf16)
    gemm_dtproj_kernel<<<dim3(12, 128), 256, 0, stream>>>(
        DBL, dt_proj_w, DTb, dt_proj_b, 16384, DINC, 24, 56, 24, DINC);
    // ---- chunked parallel selective scan (y bf16 over DTb)
    scan_phase1_kernel<<<dim3(3, NCHUNK, 4), 256, 0, stream>>>(
        DTb, Ub, DBL, A_log, HOUT, SDT);
    scan_phase2_kernel<<<192, 256, 0, stream>>>(HOUT, SDT, A_log);
    scan_phase3_kernel<<<dim3(3, NCHUNK, 4), 256, 0, stream>>>(
        DTb, Ub, DBL, Zb, A_log, D_skip, HOUT);
    // ---- out_proj (bf16 MFMA) -> d_out transposed fp32
    gemm_gl_kernel<2><<<384, 256, 0, stream>>>(
        DTb, opwb, out, nullptr, 16384, CDIM, DINC, 0, 3);
}

// Round 12
// 725.617 us; speedup vs baseline: 1.5807x; 1.0285x over previous
//
#include <hip/hip_runtime.h>
#include <math.h>

#define CDIM 384
#define SDIM 4096
#define BDIM 4
#define DINC 768
#define NST  16
#define NCHUNK 64
#define LCHUNK 64
#define PSTRIDE 6291456   // ELEMENTS per conv partial [B,C,S] (bf16)

typedef unsigned short ushort_t;
typedef unsigned int uint_t;
typedef __attribute__((ext_vector_type(4))) float f32x4;
typedef __attribute__((ext_vector_type(8))) short bf16x8;

__device__ __forceinline__ ushort_t f2bf(float f) {
    union { float f; uint_t u; } v; v.f = f;
    uint_t r = v.u + 0x7FFFu + ((v.u >> 16) & 1u);   // round-to-nearest-even
    return (ushort_t)(r >> 16);
}
__device__ __forceinline__ float bf2f(ushort_t u) {
    union { uint_t i; float f; } v; v.i = ((uint_t)u) << 16; return v.f;
}
__device__ __forceinline__ uint_t pk2(float a, float b) {
    return (uint_t)f2bf(a) | ((uint_t)f2bf(b) << 16);
}
// async global->LDS, 16B per lane, dest = wave-uniform base + lane*16
__device__ __forceinline__ void gl16(const ushort_t* g, ushort_t* l) {
    __builtin_amdgcn_global_load_lds(
        (const __attribute__((address_space(1))) void*)(g),
        (__attribute__((address_space(3))) void*)(l), 16, 0, 0);
}

// ---------------------------------------------------------------------------
// Merged weight prep: all fp32->bf16 weight conversions in one dispatch.
// ---------------------------------------------------------------------------
__device__ __forceinline__ void wconv_body(const float* __restrict__ W,
                                           ushort_t* __restrict__ Wb, int idx) {
    const float* wp = W + (size_t)idx * 27;              // idx = co*384+ci
#pragma unroll
    for (int tap = 0; tap < 27; ++tap)
        Wb[(size_t)tap * (CDIM * CDIM) + idx] = f2bf(wp[tap]);
}
__device__ __forceinline__ void cvt_body(const float* __restrict__ src,
                                         ushort_t* __restrict__ dst, int i) {
    float4 v = ((const float4*)src)[i];
    uint2 o; o.x = pk2(v.x, v.y); o.y = pk2(v.z, v.w);
    ((uint2*)dst)[i] = o;
}
__global__ __launch_bounds__(256)
void prep_weights_kernel(const float* w1, const float* w2, const float* w3,
                         const float* w4, const float* ipw, const float* opw,
                         const float* xpw,
                         ushort_t* Wb1, ushort_t* Wb2, ushort_t* w3b, ushort_t* w4b,
                         ushort_t* ipwb, ushort_t* opwb, ushort_t* xpwb) {
    const int bid = blockIdx.x, t = threadIdx.x;
    if      (bid < 576)  wconv_body(w1, Wb1, bid * 256 + t);
    else if (bid < 1152) wconv_body(w2, Wb2, (bid - 576) * 256 + t);
    else if (bid < 1296) cvt_body(w3, w3b, (bid - 1152) * 256 + t);
    else if (bid < 1440) cvt_body(w4, w4b, (bid - 1296) * 256 + t);
    else if (bid < 2016) cvt_body(ipw, ipwb, (bid - 1440) * 256 + t);
    else if (bid < 2304) cvt_body(opw, opwb, (bid - 2016) * 256 + t);
    else                 cvt_body(xpw, xpwb, (bid - 2304) * 256 + t);
}

// ---------------------------------------------------------------------------
// Pad + transpose to channels-last bf16: src[b][c][16^3] -> Xp[b][18][18][18][384]
// ---------------------------------------------------------------------------
__global__ __launch_bounds__(384)
void pad_kernel(const float* __restrict__ src, ushort_t* __restrict__ Xp) {
    const int blk = blockIdx.x;                          // b(4) d(16) h(16)
    const int b = blk >> 8, d = (blk >> 4) & 15, h = blk & 15;
    const int ci = threadIdx.x;
    const float* sp = src + (size_t)(b * CDIM + ci) * SDIM + d * 256 + h * 16;
    ushort_t* dp = Xp + ((((size_t)(b * 18 + d + 1) * 18) + (h + 1)) * 18 + 1) * CDIM + ci;
#pragma unroll
    for (int w = 0; w < 16; ++w)
        dp[(size_t)w * CDIM] = f2bf(sp[w]);
}

// ---------------------------------------------------------------------------
// Fused: v = relu((P0+P1 - m)*r) -> pad/transpose channels-last bf16 Xp.
// ---------------------------------------------------------------------------
__global__ __launch_bounds__(384)
void pad_fuse2_kernel(const ushort_t* __restrict__ P0, const ushort_t* __restrict__ P1,
                      const float* __restrict__ stats, ushort_t* __restrict__ Xp) {
    const int blk = blockIdx.x;
    const int b = blk >> 8, d = (blk >> 4) & 15, h = blk & 15;
    const int ci = threadIdx.x;
    const size_t o = (size_t)(b * CDIM + ci) * SDIM + d * 256 + h * 16;
    const float m = stats[(b * CDIM + ci) * 2], r = stats[(b * CDIM + ci) * 2 + 1];
    union { uint4 q[2]; ushort_t u[16]; } a, c;
    a.q[0] = ((const uint4*)(P0 + o))[0]; a.q[1] = ((const uint4*)(P0 + o))[1];
    c.q[0] = ((const uint4*)(P1 + o))[0]; c.q[1] = ((const uint4*)(P1 + o))[1];
    ushort_t* dp = Xp + ((((size_t)(b * 18 + d + 1) * 18) + (h + 1)) * 18 + 1) * CDIM + ci;
#pragma unroll
    for (int w = 0; w < 16; ++w) {
        const float v = bf2f(a.u[w]) + bf2f(c.u[w]);
        dp[(size_t)w * CDIM] = f2bf(fmaxf((v - m) * r, 0.f));
    }
}

// ---------------------------------------------------------------------------
// Fused: S = relu((P0+P1-m2)*r2) + relu((C3-m3)*r3) -> pad channels-last bf16.
// ---------------------------------------------------------------------------
__global__ __launch_bounds__(384)
void pad_fuse3_kernel(const ushort_t* __restrict__ P0, const ushort_t* __restrict__ P1,
                      const float* __restrict__ st2, const ushort_t* __restrict__ C3,
                      const float* __restrict__ st3, ushort_t* __restrict__ Xp) {
    const int blk = blockIdx.x;
    const int b = blk >> 8, d = (blk >> 4) & 15, h = blk & 15;
    const int ci = threadIdx.x;
    const size_t o = (size_t)(b * CDIM + ci) * SDIM + d * 256 + h * 16;
    const float m2 = st2[(b * CDIM + ci) * 2], r2 = st2[(b * CDIM + ci) * 2 + 1];
    const float m3 = st3[(b * CDIM + ci) * 2], r3 = st3[(b * CDIM + ci) * 2 + 1];
    union { uint4 q[2]; ushort_t u[16]; } a, c, e;
    a.q[0] = ((const uint4*)(P0 + o))[0]; a.q[1] = ((const uint4*)(P0 + o))[1];
    c.q[0] = ((const uint4*)(P1 + o))[0]; c.q[1] = ((const uint4*)(P1 + o))[1];
    e.q[0] = ((const uint4*)(C3 + o))[0]; e.q[1] = ((const uint4*)(C3 + o))[1];
    ushort_t* dp = Xp + ((((size_t)(b * 18 + d + 1) * 18) + (h + 1)) * 18 + 1) * CDIM + ci;
#pragma unroll
    for (int w = 0; w < 16; ++w) {
        const float x1 = fmaxf((bf2f(a.u[w]) + bf2f(c.u[w]) - m2) * r2, 0.f);
        const float x2 = fmaxf((bf2f(e.u[w]) - m3) * r3, 0.f);
        dp[(size_t)w * CDIM] = f2bf(x1 + x2);
    }
}

// ---------------------------------------------------------------------------
// Implicit-GEMM conv via MFMA bf16, v3: 512 threads (8 waves, 2co x 4sp),
// block 128co x 256sp (full d-plane). Per-wave math identical to the proven
// 64x64 kernel (acc[4][4], gl_lds staging, XOR-swizzled content). Staging:
// A staged ONCE per iter for the whole block (8KB) + B 16KB -> 88KB LDS
// traffic per 2 MFLOP vs 96KB for two 128x128 blocks; LDS-BW cap ~46%.
// Single 24KB buffer, 2 barriers/iter.
// MODE 0: c2 (z in {0,1} tap-split -> Y01+z*PSTRIDE)
// MODE 1: c1 (z in {0,1}) + c3 1x1 fused as z==2 (W3 -> Y2)
// MODE 2: pure 1x1 (c4 -> Y2)
// ---------------------------------------------------------------------------
template<int MODE>
__global__ __launch_bounds__(512)
void conv_kernel(const ushort_t* __restrict__ Xp, const ushort_t* __restrict__ Wb,
                 const ushort_t* __restrict__ W3, ushort_t* __restrict__ Y01,
                 ushort_t* __restrict__ Y2) {
    const int wid = blockIdx.x;
    const int ntid = wid & 63;                           // (b,d) innermost
    const int rest = wid >> 6;
    const int co0 = (rest % 3) * 128;
    const int zz  = rest / 3;
    const int b  = ntid >> 4;
    const int d  = ntid & 15;
    const int t = threadIdx.x;
    const int lane = t & 63;
    const int wv = t >> 6;                               // 0..7
    const int wy = wv >> 2, wx = wv & 3;                 // co-half / sp-quarter

    const bool is1x1 = (MODE == 2) || (MODE == 1 && zz == 2);
    const ushort_t* Wsrc; int tap0, iters, kd0, kh0, kw0; ushort_t* Y;
    if (is1x1) {
        Wsrc = W3; tap0 = 0; iters = 12; kd0 = 1; kh0 = 1; kw0 = 1; Y = Y2;
    } else {
        Wsrc = Wb; tap0 = zz ? 14 : 0; iters = (zz ? 13 : 14) * 12;
        kd0 = zz ? 1 : 0; kh0 = zz ? 1 : 0; kw0 = zz ? 2 : 0;
        Y = Y01 + (size_t)zz * PSTRIDE;
    }

    __shared__ __align__(16) ushort_t As[4096];          // [128][32] bf16, 8KB
    __shared__ __align__(16) ushort_t Bs[8192];          // [256][32] bf16, 16KB

    f32x4 acc[4][4];
#pragma unroll
    for (int i = 0; i < 4; ++i)
#pragma unroll
        for (int j = 0; j < 4; ++j) acc[i][j] = (f32x4){0.f, 0.f, 0.f, 0.f};

    // staging thread-constants (per-lane, fixed): swizzled source granule
    const int l4 = lane >> 2;
    const int cg = (((lane & 3) ^ ((lane >> 3) & 3)) << 3);
    const int rA = wv * 16 + l4;                         // A row (1 instr/wave)
    const int aTC = (co0 + rA) * CDIM + cg;
    int bTC[2];
#pragma unroll
    for (int i = 0; i < 2; ++i) {
        const int r = wv * 32 + i * 16 + l4;             // B row (2 instr/wave)
        bTC[i] = ((r >> 4) * 18 + (r & 15)) * CDIM + cg;
    }
    ushort_t* lA = &As[wv * 512];
    ushort_t* lB[2] = { &Bs[wv * 1024], &Bs[wv * 1024 + 512] };

    // uniform walking offsets
    int aoff = tap0 * (CDIM * CDIM);
    int goff = (((b * 18 + d + kd0) * 18 + kh0) * 18 + kw0) * CDIM;
    int c12 = 0, ckw = kw0, ckh = kh0;

    // fragment read bases (same XOR involution as writes)
    const int lm = lane & 15;
    const int sw8 = (((lane >> 4) ^ ((lm >> 1) & 3)) << 3);
    const int rA0 = (wy * 64 + lm) * 32 + sw8;           // + mi*512
    const int rB0 = (wx * 64 + lm) * 32 + sw8;           // + ni*512

    for (int idx = 0; idx < iters; ++idx) {
        gl16(Wsrc + aoff + aTC, lA);
        gl16(Xp + goff + bTC[0], lB[0]);
        gl16(Xp + goff + bTC[1], lB[1]);
        aoff += 32; goff += 32;
        if (++c12 == 12) {                               // tap wrap
            c12 = 0;
            aoff += CDIM * CDIM - CDIM;
            if (++ckw == 3) {
                ckw = 0;
                if (++ckh == 3) { ckh = 0; goff += 109440; }
                else goff += 5760;
            }
        }
        __syncthreads();                                 // drains vmcnt: LDS ready
        bf16x8 af[4], bfr[4];
#pragma unroll
        for (int mi = 0; mi < 4; ++mi)
            af[mi] = *reinterpret_cast<const bf16x8*>(&As[rA0 + mi * 512]);
#pragma unroll
        for (int ni = 0; ni < 4; ++ni)
            bfr[ni] = *reinterpret_cast<const bf16x8*>(&Bs[rB0 + ni * 512]);
#pragma unroll
        for (int mi = 0; mi < 4; ++mi)
#pragma unroll
            for (int ni = 0; ni < 4; ++ni)
                acc[mi][ni] = __builtin_amdgcn_mfma_f32_16x16x32_bf16(
                    af[mi], bfr[ni], acc[mi][ni], 0, 0, 0);
        __syncthreads();                                 // reads done before overwrite
    }

    // epilogue: C/D layout col(lane&15)=sp, row=(lane>>4)*4+j=co; bf16 store
    const int coB = co0 + wy * 64 + (lane >> 4) * 4;
#pragma unroll
    for (int mi = 0; mi < 4; ++mi) {
#pragma unroll
        for (int ni = 0; ni < 4; ++ni) {
            const int nl = wx * 64 + ni * 16 + lm;       // sp within plane
            const int s = d * 256 + nl;
            ushort_t* yp = Y + ((size_t)b * CDIM + (coB + mi * 16)) * SDIM + s;
#pragma unroll
            for (int j = 0; j < 4; ++j)
                yp[(size_t)j * SDIM] = f2bf(acc[mi][ni][j]);
        }
    }
}

// ---------------------------------------------------------------------------
// bf16 MFMA GEMM NT with gl_lds + 2-phase prefetch (round-11, unchanged).
// C[M,N] = A[M,K] x B[N,K]^T. N masked via address clamp + store mask.
// EPI 0: fp32 store (ldc); 1: xz split -> bf16 C/C2 (N=1536);
// 2: transposed fp32 float4 store C[b][n][l].
// ---------------------------------------------------------------------------
template<int EPI>
__global__ __launch_bounds__(256)
void gemm_gl_kernel(const ushort_t* __restrict__ A, const ushort_t* __restrict__ Bw,
                    void* __restrict__ Cv, void* __restrict__ C2v,
                    int M, int N, int K, int ldc, int nx) {
    const int wid = blockIdx.x;
    const int n0 = (wid % nx) * 128;
    const int m0 = (wid / nx) * 128;
    const int t = threadIdx.x;
    const int lane = t & 63;
    const int wv = t >> 6;
    const int wy = wv >> 1, wx = wv & 1;

    __shared__ __align__(16) ushort_t As[2][4096];
    __shared__ __align__(16) ushort_t Bs[2][4096];

    f32x4 acc[4][4];
#pragma unroll
    for (int i = 0; i < 4; ++i)
#pragma unroll
        for (int j = 0; j < 4; ++j) acc[i][j] = (f32x4){0.f, 0.f, 0.f, 0.f};

    const int l4 = lane >> 2;
    const int cg = (((lane & 3) ^ ((lane >> 3) & 3)) << 3);
    size_t aTC[2], bTC[2];
#pragma unroll
    for (int i = 0; i < 2; ++i) {
        const int r = wv * 32 + i * 16 + l4;
        aTC[i] = (size_t)(m0 + r) * K + cg;
        int br = n0 + r; if (br >= N) br = N - 1;        // clamp (masked at store)
        bTC[i] = (size_t)br * K + cg;
    }

    const int lm = lane & 15;
    const int sw8 = (((lane >> 4) ^ ((lm >> 1) & 3)) << 3);
    const int rA0 = (wy * 64 + lm) * 32 + sw8;
    const int rB0 = (wx * 64 + lm) * 32 + sw8;

    auto stage = [&](int bf, int ko) {
        ushort_t* la = &As[bf][wv * 1024];
        ushort_t* lb = &Bs[bf][wv * 1024];
        gl16(A + aTC[0] + ko, la);
        gl16(A + aTC[1] + ko, la + 512);
        gl16(Bw + bTC[0] + ko, lb);
        gl16(Bw + bTC[1] + ko, lb + 512);
    };

    const int KI = K >> 5;
    stage(0, 0);
    __syncthreads();

    int buf = 0;
    for (int kk = 0; kk < KI; ++kk) {
        if (kk + 1 < KI) stage(buf ^ 1, (kk + 1) * 32);
        bf16x8 af[4], bfr[4];
#pragma unroll
        for (int mi = 0; mi < 4; ++mi)
            af[mi] = *reinterpret_cast<const bf16x8*>(&As[buf][rA0 + mi * 512]);
#pragma unroll
        for (int ni = 0; ni < 4; ++ni)
            bfr[ni] = *reinterpret_cast<const bf16x8*>(&Bs[buf][rB0 + ni * 512]);
#pragma unroll
        for (int mi = 0; mi < 4; ++mi)
#pragma unroll
            for (int ni = 0; ni < 4; ++ni)
                acc[mi][ni] = __builtin_amdgcn_mfma_f32_16x16x32_bf16(
                    af[mi], bfr[ni], acc[mi][ni], 0, 0, 0);
        __syncthreads();
        buf ^= 1;
    }

    const int mB = m0 + wy * 64 + (lane >> 4) * 4;
    const int nB = n0 + wx * 64 + lm;
#pragma unroll
    for (int mi = 0; mi < 4; ++mi) {
#pragma unroll
        for (int ni = 0; ni < 4; ++ni) {
            const int n = nB + ni * 16;
            if (EPI == 2) {                              // transposed float4
                const int mrow = mB + mi * 16;
                const int bb = mrow >> 12, l = mrow & 4095;
                float4 st = {acc[mi][ni][0], acc[mi][ni][1],
                             acc[mi][ni][2], acc[mi][ni][3]};
                *reinterpret_cast<float4*>(
                    (float*)Cv + ((size_t)(bb * CDIM + n)) * SDIM + l) = st;
            } else {
#pragma unroll
                for (int j = 0; j < 4; ++j) {
                    const int m = mB + mi * 16 + j;
                    const float v = acc[mi][ni][j];
                    if (EPI == 0) {
                        if (n < N) ((float*)Cv)[(size_t)m * ldc + n] = v;
                    } else {                             // xz split, bf16 out
                        if (n < DINC) ((ushort_t*)Cv)[(size_t)m * DINC + n] = f2bf(v);
                        else ((ushort_t*)C2v)[(size_t)m * DINC + (n - DINC)] = f2bf(v);
                    }
                }
            }
        }
    }
}

// ---------------------------------------------------------------------------
// Reduction helper for instance-norm stats.
// ---------------------------------------------------------------------------
__device__ __forceinline__ void stats_reduce(float s, float ss, float* out) {
#pragma unroll
    for (int off = 32; off > 0; off >>= 1) {
        s += __shfl_down(s, off);
        ss += __shfl_down(ss, off);
    }
    __shared__ float rs[4], rss[4];
    const int wid = threadIdx.x >> 6;
    if ((threadIdx.x & 63) == 0) { rs[wid] = s; rss[wid] = ss; }
    __syncthreads();
    if (threadIdx.x == 0) {
        float S = rs[0] + rs[1] + rs[2] + rs[3];
        float SS = rss[0] + rss[1] + rss[2] + rss[3];
        float m = S * (1.f / SDIM);
        float var = SS * (1.f / SDIM) - m * m;
        out[0] = m;
        out[1] = rsqrtf(var + 1e-5f);
    }
}

// ---------------------------------------------------------------------------
// Combo stats (bf16 inputs): bc<1536 -> stats of (P0+P1) into SA;
// bc>=1536 -> stats of X3 into SB (only when grid > 1536).
// ---------------------------------------------------------------------------
__global__ __launch_bounds__(256)
void inorm_stats_combo_kernel(const ushort_t* __restrict__ P0,
                              const ushort_t* __restrict__ P1,
                              float* __restrict__ SA,
                              const ushort_t* __restrict__ X3,
                              float* __restrict__ SB) {
    const int bid = blockIdx.x;
    float s = 0.f, ss = 0.f;
    if (bid < 1536) {
        const ushort_t* p0 = P0 + (size_t)bid * SDIM;
        const ushort_t* p1 = P1 + (size_t)bid * SDIM;
        for (int i = threadIdx.x * 8; i < SDIM; i += 2048) {
            union { uint4 q; ushort_t u[8]; } a, c;
            a.q = *(const uint4*)(p0 + i);
            c.q = *(const uint4*)(p1 + i);
#pragma unroll
            for (int j = 0; j < 8; ++j) {
                const float v = bf2f(a.u[j]) + bf2f(c.u[j]);
                s += v; ss += v * v;
            }
        }
        stats_reduce(s, ss, SA + bid * 2);
    } else {
        const int bc = bid - 1536;
        const ushort_t* xp = X3 + (size_t)bc * SDIM;
        for (int i = threadIdx.x * 8; i < SDIM; i += 2048) {
            union { uint4 q; ushort_t u[8]; } a;
            a.q = *(const uint4*)(xp + i);
#pragma unroll
            for (int j = 0; j < 8; ++j) {
                const float v = bf2f(a.u[j]);
                s += v; ss += v * v;
            }
        }
        stats_reduce(s, ss, SB + bc * 2);
    }
}

// ---------------------------------------------------------------------------
// InstanceNorm stats, single bf16 input.
// ---------------------------------------------------------------------------
__global__ __launch_bounds__(256)
void inorm_stats_kernel(const ushort_t* __restrict__ X, float* __restrict__ stats) {
    const int bc = blockIdx.x;
    const ushort_t* xp = X + (size_t)bc * SDIM;
    float s = 0.f, ss = 0.f;
    for (int i = threadIdx.x * 8; i < SDIM; i += 2048) {
        union { uint4 q; ushort_t u[8]; } a;
        a.q = *(const uint4*)(xp + i);
#pragma unroll
        for (int j = 0; j < 8; ++j) {
            const float v = bf2f(a.u[j]);
            s += v; ss += v * v;
        }
    }
    stats_reduce(s, ss, stats + bc * 2);
}

// ---------------------------------------------------------------------------
// Fused LayerNorm, coalesced (round-10 proven): wave handles 8 tokens,
// butterfly reduce, LDS-staged coalesced output.
// ---------------------------------------------------------------------------
__global__ __launch_bounds__(256)
void layernorm_kernel(const ushort_t* __restrict__ C4, const float* __restrict__ stats,
                      const float* __restrict__ X, const float* __restrict__ gam,
                      const float* __restrict__ bet, ushort_t* __restrict__ Tn) {
    const int blk = blockIdx.x;
    const int b = blk >> 7;
    const int tile0 = (blk & 127) * 32;
    const int wv = threadIdx.x >> 6;
    const int lane = threadIdx.x & 63;
    const int l0 = tile0 + wv * 8;

    __shared__ ushort_t tile[32 * 384];

    float v[6][8];
    float s[8], ss[8];
#pragma unroll
    for (int t = 0; t < 8; ++t) { s[t] = 0.f; ss[t] = 0.f; }
    float g[6], be[6];

#pragma unroll
    for (int i = 0; i < 6; ++i) {
        const int c = lane + i * 64;
        g[i] = gam[c]; be[i] = bet[c];
        const size_t base = (size_t)(b * CDIM + c) * SDIM + l0;
        union { uint4 q; ushort_t u[8]; } cv;
        cv.q = *(const uint4*)(C4 + base);
        const float4 x0 = *(const float4*)(X + base);
        const float4 x1 = *(const float4*)(X + base + 4);
        const float xs[8] = {x0.x, x0.y, x0.z, x0.w, x1.x, x1.y, x1.z, x1.w};
        const float m = stats[(b * CDIM + c) * 2];
        const float r = stats[(b * CDIM + c) * 2 + 1];
#pragma unroll
        for (int t = 0; t < 8; ++t) {
            const float val = fmaxf((bf2f(cv.u[t]) - m) * r, 0.f) + xs[t];
            v[i][t] = val;
            s[t] += val; ss[t] += val * val;
        }
    }
#pragma unroll
    for (int off = 32; off > 0; off >>= 1) {
#pragma unroll
        for (int t = 0; t < 8; ++t) {
            s[t] += __shfl_xor(s[t], off);
            ss[t] += __shfl_xor(ss[t], off);
        }
    }
#pragma unroll
    for (int t = 0; t < 8; ++t) {
        const float mean = s[t] * (1.f / CDIM);
        const float rstd = rsqrtf(ss[t] * (1.f / CDIM) - mean * mean + 1e-5f);
        const int trow = (wv * 8 + t) * 384;
#pragma unroll
        for (int i = 0; i < 6; ++i) {
            const int c = lane + i * 64;
            tile[trow + c] = f2bf((v[i][t] - mean) * rstd * g[i] + be[i]);
        }
    }
    __syncthreads();
    uint4* dst = (uint4*)(Tn + ((size_t)b * 4096 + tile0) * CDIM);
    const uint4* srcp = (const uint4*)tile;
#pragma unroll
    for (int k = 0; k < 6; ++k)
        dst[k * 256 + threadIdx.x] = srcp[k * 256 + threadIdx.x];
}

// ---------------------------------------------------------------------------
// Tiled fp32 GEMM for dt_proj (K=24), NT, bias+softplus, bf16 store.
// ---------------------------------------------------------------------------
__global__ __launch_bounds__(256)
void gemm_dtproj_kernel(const float* __restrict__ A, const float* __restrict__ B,
                        ushort_t* __restrict__ C, const float* __restrict__ bias,
                        int M, int N, int K, int lda, int ldb, int ldc) {
    __shared__ __align__(16) float As[16][132];
    __shared__ __align__(16) float Bs[16][68];
    const int t = threadIdx.x;
    const int m0 = blockIdx.y * 128;
    const int n0 = blockIdx.x * 64;

    float acc[8][4];
#pragma unroll
    for (int i = 0; i < 8; ++i)
#pragma unroll
        for (int j = 0; j < 4; ++j) acc[i][j] = 0.f;

    const int mr = (t & 15) * 8;
    const int nr = (t >> 4) * 4;

    for (int k0 = 0; k0 < K; k0 += 16) {
#pragma unroll
        for (int idx = 0; idx < 8; ++idx) {
            const int e = idx * 256 + t;
            const int k = e & 15, m = e >> 4;
            float v = 0.f;
            if (k0 + k < K) v = A[(size_t)(m0 + m) * lda + (k0 + k)];
            As[k][m] = v;
        }
#pragma unroll
        for (int idx = 0; idx < 4; ++idx) {
            const int e = idx * 256 + t;
            const int k = e & 15, n = e >> 4;
            float v = 0.f;
            if ((n0 + n) < N && (k0 + k) < K) v = B[(size_t)(n0 + n) * ldb + (k0 + k)];
            Bs[k][n] = v;
        }
        __syncthreads();
#pragma unroll
        for (int k = 0; k < 16; ++k) {
            float4 a0 = *(const float4*)&As[k][mr];
            float4 a1 = *(const float4*)&As[k][mr + 4];
            float4 b0 = *(const float4*)&Bs[k][nr];
            const float av[8] = {a0.x, a0.y, a0.z, a0.w, a1.x, a1.y, a1.z, a1.w};
            const float bv[4] = {b0.x, b0.y, b0.z, b0.w};
#pragma unroll
            for (int i = 0; i < 8; ++i)
#pragma unroll
                for (int j = 0; j < 4; ++j)
                    acc[i][j] = fmaf(av[i], bv[j], acc[i][j]);
        }
        __syncthreads();
    }

#pragma unroll
    for (int i = 0; i < 8; ++i) {
        const int m = m0 + mr + i;
#pragma unroll
        for (int j = 0; j < 4; ++j) {
            const int n = n0 + nr + j;
            if (n >= N) continue;
            float v = acc[i][j] + bias[n];
            v = (v > 20.f) ? v : log1pf(__expf(v));
            C[(size_t)m * ldc + n] = f2bf(v);
        }
    }
}

// ---------------------------------------------------------------------------
// Causal depthwise conv1d (K=4) + bias + SiLU, bf16 in/out. 4 tokens/thread.
// ---------------------------------------------------------------------------
__global__ __launch_bounds__(256)
void dwconv_silu_kernel(const ushort_t* __restrict__ Xin, const float* __restrict__ W,
                        const float* __restrict__ bias, ushort_t* __restrict__ U) {
    const int dch = blockIdx.x * 256 + threadIdx.x;
    const int l0 = blockIdx.y * 4, b = blockIdx.z;
    const float4 w4 = ((const float4*)W)[dch];
    const float wk[4] = {w4.x, w4.y, w4.z, w4.w};
    const float bs = bias[dch];
    const size_t base = ((size_t)b * 4096 + l0) * DINC + dch;
    float r[7];
#pragma unroll
    for (int k = 0; k < 7; ++k) {
        const int ll = l0 - 3 + k;
        r[k] = (ll >= 0) ? bf2f(Xin[base + (size_t)(k - 3) * DINC]) : 0.f;
    }
#pragma unroll
    for (int j = 0; j < 4; ++j) {
        float acc = bs;
#pragma unroll
        for (int k = 0; k < 4; ++k) acc = fmaf(r[j + k], wk[k], acc);
        U[base + (size_t)j * DINC] = f2bf(acc / (1.f + __expf(-acc)));
    }
}

// ---------------------------------------------------------------------------
// Chunked parallel selective scan (3 phases). dt/u/z/y bf16; B,C fp32.
// ---------------------------------------------------------------------------
__global__ __launch_bounds__(256)
void scan_phase1_kernel(const ushort_t* __restrict__ DT, const ushort_t* __restrict__ U,
                        const float* __restrict__ DBL, const float* __restrict__ A_log,
                        float* __restrict__ HOUT, float* __restrict__ SDT) {
    const int b = blockIdx.z, chunk = blockIdx.y;
    const int dch = blockIdx.x * 256 + threadIdx.x;
    float Arow[16];
#pragma unroll
    for (int n = 0; n < NST; ++n) Arow[n] = -__expf(A_log[dch * NST + n]);

    __shared__ float bcs[LCHUNK][16];
    const size_t tokbase = (size_t)b * 4096 + chunk * LCHUNK;
#pragma unroll
    for (int idx = 0; idx < 4; ++idx) {
        const int e = idx * 256 + threadIdx.x;
        bcs[e >> 4][e & 15] = DBL[(tokbase + (e >> 4)) * 56 + 24 + (e & 15)];
    }
    __syncthreads();

    size_t off = tokbase * DINC + dch;
    float h[16];
#pragma unroll
    for (int n = 0; n < NST; ++n) h[n] = 0.f;
    float sdt = 0.f;
    float cdt = bf2f(DT[off]), cu = bf2f(U[off]);
    for (int t = 0; t < LCHUNK; ++t) {
        float ndt = 0.f, nu = 0.f;
        if (t < LCHUNK - 1) { ndt = bf2f(DT[off + DINC]); nu = bf2f(U[off + DINC]); }
        sdt += cdt;
        const float du = cdt * cu;
#pragma unroll
        for (int n = 0; n < NST; ++n)
            h[n] = __expf(cdt * Arow[n]) * h[n] + du * bcs[t][n];
        off += DINC;
        cdt = ndt; cu = nu;
    }
    float* hp = HOUT + (((size_t)(b * DINC + dch) * NCHUNK + chunk) << 4);
#pragma unroll
    for (int n = 0; n < NST; ++n) hp[n] = h[n];
    SDT[(size_t)(b * DINC + dch) * NCHUNK + chunk] = sdt;
}

__global__ __launch_bounds__(256)
void scan_phase2_kernel(float* __restrict__ HOUT, const float* __restrict__ SDT,
                        const float* __restrict__ A_log) {
    const int t = blockIdx.x * 256 + threadIdx.x;        // 49152
    const int b = t / (DINC * NST);
    const int rem = t - b * (DINC * NST);
    const int d = rem >> 4, n = rem & 15;
    const float An = -__expf(A_log[d * NST + n]);
    float* hp = HOUT + (((size_t)(b * DINC + d) * NCHUNK) << 4) + n;
    const float* sp = SDT + (size_t)(b * DINC + d) * NCHUNK;
    float H = 0.f;
    for (int c = 0; c < NCHUNK; ++c) {
        const float tmp = hp[c * 16];
        const float dA = __expf(An * sp[c]);
        hp[c * 16] = H;
        H = dA * H + tmp;
    }
}

__global__ __launch_bounds__(256)
void scan_phase3_kernel(ushort_t* __restrict__ DT, const ushort_t* __restrict__ U,
                        const float* __restrict__ DBL, const ushort_t* __restrict__ Z,
                        const float* __restrict__ A_log, const float* __restrict__ D_skip,
                        const float* __restrict__ HOUT) {
    const int b = blockIdx.z, chunk = blockIdx.y;
    const int dch = blockIdx.x * 256 + threadIdx.x;
    float Arow[16];
#pragma unroll
    for (int n = 0; n < NST; ++n) Arow[n] = -__expf(A_log[dch * NST + n]);
    const float Dsk = D_skip[dch];

    __shared__ float bcs[LCHUNK][32];
    const size_t tokbase = (size_t)b * 4096 + chunk * LCHUNK;
#pragma unroll
    for (int idx = 0; idx < 8; ++idx) {
        const int e = idx * 256 + threadIdx.x;
        bcs[e >> 5][e & 31] = DBL[(tokbase + (e >> 5)) * 56 + 24 + (e & 31)];
    }
    __syncthreads();

    float h[16];
    const float* hp = HOUT + (((size_t)(b * DINC + dch) * NCHUNK + chunk) << 4);
#pragma unroll
    for (int n = 0; n < NST; ++n) h[n] = hp[n];

    size_t off = tokbase * DINC + dch;
    float cdt = bf2f(DT[off]), cu = bf2f(U[off]), cz = bf2f(Z[off]);
    for (int t = 0; t < LCHUNK; ++t) {
        float ndt = 0.f, nu = 0.f, nz = 0.f;
        if (t < LCHUNK - 1) {
            ndt = bf2f(DT[off + DINC]); nu = bf2f(U[off + DINC]); nz = bf2f(Z[off + DINC]);
        }
        const float du = cdt * cu;
        float y = 0.f;
#pragma unroll
        for (int n = 0; n < NST; ++n) {
            h[n] = __expf(cdt * Arow[n]) * h[n] + du * bcs[t][n];
            y = fmaf(h[n], bcs[t][16 + n], y);
        }
        y += cu * Dsk;
        const float sz = cz / (1.f + __expf(-cz));
        DT[off] = f2bf(y * sz);
        off += DINC;
        cdt = ndt; cu = nu; cz = nz;
    }
}

// ---------------------------------------------------------------------------
extern "C" void kernel_launch(void* const* d_in, const int* in_sizes, int n_in,
                              void* d_out, int out_size, void* d_ws, size_t ws_size,
                              hipStream_t stream) {
    (void)in_sizes; (void)n_in; (void)out_size; (void)ws_size;
    const float* x         = (const float*)d_in[0];
    const float* w1        = (const float*)d_in[1];
    const float* w2        = (const float*)d_in[3];
    const float* w3        = (const float*)d_in[5];
    const float* w4        = (const float*)d_in[7];
    const float* ln_g      = (const float*)d_in[9];
    const float* ln_b      = (const float*)d_in[10];
    const float* in_proj_w = (const float*)d_in[11];
    const float* conv1d_w  = (const float*)d_in[12];
    const float* conv1d_b  = (const float*)d_in[13];
    const float* x_proj_w  = (const float*)d_in[14];
    const float* dt_proj_w = (const float*)d_in[15];
    const float* dt_proj_b = (const float*)d_in[16];
    const float* A_log     = (const float*)d_in[17];
    const float* D_skip    = (const float*)d_in[18];
    const float* out_proj_w= (const float*)d_in[19];
    float* out = (float*)d_out;

    // Workspace regions (floats): R0..R4. Lifetimes disjoint where aliased.
    float* ws = (float*)d_ws;
    float* R0 = ws;                    //  6291456
    float* R1 = ws + 6291456;          //  6291456
    float* R2 = ws + 12582912;         // 12582912
    float* R3 = ws + 25165824;         // 12582912
    float* R4 = ws + 37748736;         // 12582912

    // GSC-phase aliases (conv partials/outputs bf16)
    ushort_t* P0    = (ushort_t*)R0;                 // partial z=0
    ushort_t* P1    = P0 + PSTRIDE;                  // partial z=1
    ushort_t* C34   = (ushort_t*)R3;                 // c3/c4 outputs bf16
    ushort_t* Wb1   = (ushort_t*)R2;                 // 3981312 bf16
    ushort_t* Xp    = (ushort_t*)(R2 + 2097152);     // 8957952 bf16
    ushort_t* w3b   = (ushort_t*)(R2 + 6576128);     // 147456 bf16
    ushort_t* w4b   = (ushort_t*)(R2 + 6649856);     // 147456 bf16
    ushort_t* Wb2   = (ushort_t*)(R2 + 6723584);     // 3981312 bf16
    float*    SA    = R4;                            // stats A
    float*    SB    = R4 + 4096;                     // stats B
    ushort_t* ipwb  = (ushort_t*)(R4 + 6291456);
    ushort_t* opwb  = (ushort_t*)(R4 + 6586368);
    ushort_t* xpwb  = (ushort_t*)(R4 + 6733824);
    // Mamba-phase aliases
    ushort_t* tnb   = (ushort_t*)R0;                 // 16384*384 bf16
    float*    DBL   = R0 + 3145728;                  // 16384*56 fp32
    float*    HOUT  = R1;
    float*    SDT   = R1 + 3145728;
    ushort_t* XIN   = (ushort_t*)R2;
    ushort_t* Zb    = (ushort_t*)R3;
    ushort_t* Ub    = (ushort_t*)R4;
    ushort_t* DTb   = (ushort_t*)R2;

    const size_t XP_BYTES = (size_t)4 * 18 * 18 * 18 * CDIM * 2;

    // ---- upfront: zero pad borders, convert all weights, pad x ----
    hipMemsetAsync(Xp, 0, XP_BYTES, stream);
    prep_weights_kernel<<<2346, 256, 0, stream>>>(
        w1, w2, w3, w4, in_proj_w, out_proj_w, x_proj_w,
        Wb1, Wb2, w3b, w4b, ipwb, opwb, xpwb);
    pad_kernel<<<1024, 384, 0, stream>>>(x, Xp);
    // ---- c1 (3x3x3 z-split) + c3 (1x1) fused; 512-thread 128x256 blocks ----
    conv_kernel<1><<<576, 512, 0, stream>>>(Xp, Wb1, w3b, P0, C34);
    inorm_stats_combo_kernel<<<3072, 256, 0, stream>>>(P0, P1, SA, C34, SB);
    pad_fuse2_kernel<<<1024, 384, 0, stream>>>(P0, P1, SA, Xp);             // x1a
    // ---- c2 ----
    conv_kernel<0><<<384, 512, 0, stream>>>(Xp, Wb2, nullptr, P0, nullptr);
    inorm_stats_combo_kernel<<<1536, 256, 0, stream>>>(P0, P1, SA, nullptr, nullptr);
    pad_fuse3_kernel<<<1024, 384, 0, stream>>>(P0, P1, SA, C34, SB, Xp);    // S
    // ---- c4 (1x1) ----
    conv_kernel<2><<<192, 512, 0, stream>>>(Xp, nullptr, w4b, nullptr, C34);
    inorm_stats_kernel<<<1536, 256, 0, stream>>>(C34, SA);
    // ---- fused relu(IN(c4)) + x residual + LayerNorm -> tn bf16 [b][l][c]
    layernorm_kernel<<<512, 256, 0, stream>>>(C34, SA, x, ln_g, ln_b, tnb);
    // ---- in_proj (bf16 MFMA, gl_lds+prefetch): tn x W^T -> XIN | Zb (bf16)
    gemm_gl_kernel<1><<<1536, 256, 0, stream>>>(
        tnb, ipwb, XIN, Zb, 16384, 1536, CDIM, 0, 12);
    // ---- causal depthwise conv + SiLU -> Ub (bf16)
    dwconv_silu_kernel<<<dim3(3, 1024, 4), 256, 0, stream>>>(XIN, conv1d_w, conv1d_b, Ub);
    // ---- x_proj (bf16 MFMA, N=56 masked): u x W^T -> DBL (fp32)
    gemm_gl_kernel<0><<<128, 256, 0, stream>>>(
        Ub, xpwb, DBL, nullptr, 16384, 56, DINC, 56, 1);
    // ---- dt_proj (fp32 VALU, K=24) + bias + softplus -> DTb (bf16)
    gemm_dtproj_kernel<<<dim3(12, 128), 256, 0, stream>>>(
        DBL, dt_proj_w, DTb, dt_proj_b, 16384, DINC, 24, 56, 24, DINC);
    // ---- chunked parallel selective scan (y bf16 over DTb)
    scan_phase1_kernel<<<dim3(3, NCHUNK, 4), 256, 0, stream>>>(
        DTb, Ub, DBL, A_log, HOUT, SDT);
    scan_phase2_kernel<<<192, 256, 0, stream>>>(HOUT, SDT, A_log);
    scan_phase3_kernel<<<dim3(3, NCHUNK, 4), 256, 0, stream>>>(
        DTb, Ub, DBL, Zb, A_log, D_skip, HOUT);
    // ---- out_proj (bf16 MFMA) -> d_out transposed fp32
    gemm_gl_kernel<2><<<384, 256, 0, stream>>>(
        DTb, opwb, out, nullptr, 16384, CDIM, DINC, 0, 3);
}